// Round 1
// baseline (701.930 us; speedup 1.0000x reference)
//
#include <hip/hip_runtime.h>
#include <hip/hip_bf16.h>

// ---------------------------------------------------------------------------
// GraphAutoEncoder: 4x GCNConv + mean-pool + repeat, all f32.
// Strategy:
//   - Build incoming-edge CSR once per call (count / rsqrt / scan / fill).
//   - Self-loop handled analytically: out[i] += dis[i]^2 * h[i].
//   - Aggregate on the narrow side of each layer (16 / 32 / z-LDS / 16 wide).
//   - Fused agg+GEMM kernels with LDS phase-split for coalesced stores.
// ---------------------------------------------------------------------------

__global__ void count_kernel(const int* __restrict__ dst, int* __restrict__ cnt, int E) {
    int e = blockIdx.x * blockDim.x + threadIdx.x;
    if (e < E) atomicAdd(&cnt[dst[e]], 1);
}

__global__ void dis_kernel(const int* __restrict__ cnt, float* __restrict__ dis, int n) {
    int i = blockIdx.x * blockDim.x + threadIdx.x;
    if (i < n) dis[i] = rsqrtf((float)cnt[i] + 1.0f);   // +1 = self-loop
}

// Single-block exclusive scan over n counts -> off[0..n], cur = copy of off.
__global__ __launch_bounds__(1024)
void scan_kernel(const int* __restrict__ cnt, int* __restrict__ off,
                 int* __restrict__ cur, int n) {
    __shared__ int sums[1024];
    int t = threadIdx.x;
    int chunk = (n + 1023) >> 10;
    int start = t * chunk;
    int end = min(start + chunk, n);
    int s = 0;
    for (int i = start; i < end; ++i) s += cnt[i];
    sums[t] = s;
    __syncthreads();
    for (int d = 1; d < 1024; d <<= 1) {
        int v = (t >= d) ? sums[t - d] : 0;
        __syncthreads();
        sums[t] += v;
        __syncthreads();
    }
    int run = (t == 0) ? 0 : sums[t - 1];
    for (int i = start; i < end; ++i) {
        off[i] = run; cur[i] = run; run += cnt[i];
    }
    if (start < n && end == n) off[n] = run;
}

__global__ void fill_kernel(const int* __restrict__ src, const int* __restrict__ dst,
                            const float* __restrict__ dis, int* __restrict__ cur,
                            int* __restrict__ col, float* __restrict__ wgt, int E) {
    int e = blockIdx.x * blockDim.x + threadIdx.x;
    if (e < E) {
        int s = src[e], d = dst[e];
        float w = dis[s] * dis[d];
        int p = atomicAdd(&cur[d], 1);
        col[p] = s;
        wgt[p] = w;
    }
}

// Layer 1: agg x (16-wide) then GEMM 16->64 + b1 + relu. Phase-split via LDS.
__global__ __launch_bounds__(256)
void l1_kernel(const float* __restrict__ x, const float* __restrict__ dis,
               const int* __restrict__ off, const int* __restrict__ col,
               const float* __restrict__ wgt,
               const float* __restrict__ W1, const float* __restrict__ b1,
               float* __restrict__ h1, int n) {
    __shared__ float accs[256][17];
    __shared__ float Wl[16 * 64];
    __shared__ float bl[64];
    int t = threadIdx.x;
    for (int i = t; i < 16 * 64; i += 256) Wl[i] = W1[i];
    if (t < 64) bl[t] = b1[t];

    int node = blockIdx.x * 256 + t;
    float acc[16];
#pragma unroll
    for (int k = 0; k < 16; ++k) acc[k] = 0.f;
    if (node < n) {
        float di = dis[node], d2 = di * di;
        const float4* xr = (const float4*)(x + (size_t)node * 16);
#pragma unroll
        for (int q = 0; q < 4; ++q) {
            float4 v = xr[q];
            acc[4 * q]     = d2 * v.x; acc[4 * q + 1] = d2 * v.y;
            acc[4 * q + 2] = d2 * v.z; acc[4 * q + 3] = d2 * v.w;
        }
        int e0 = off[node], e1 = off[node + 1];
        for (int e = e0; e < e1; ++e) {
            int s = col[e]; float w = wgt[e];
            const float4* xs = (const float4*)(x + (size_t)s * 16);
#pragma unroll
            for (int q = 0; q < 4; ++q) {
                float4 v = xs[q];
                acc[4 * q]     += w * v.x; acc[4 * q + 1] += w * v.y;
                acc[4 * q + 2] += w * v.z; acc[4 * q + 3] += w * v.w;
            }
        }
    }
#pragma unroll
    for (int k = 0; k < 16; ++k) accs[t][k] = acc[k];
    __syncthreads();

    int base = blockIdx.x * 256;
    int j = t & 63;
    for (int nb = (t >> 6); nb < 256; nb += 4) {
        int nd = base + nb;
        if (nd >= n) break;
        float s = bl[j];
#pragma unroll
        for (int k = 0; k < 16; ++k) s += accs[nb][k] * Wl[k * 64 + j];
        h1[(size_t)nd * 64 + j] = fmaxf(s, 0.f);
    }
}

// Dense transform: out[n,KO] = in[n,KI] @ W[KI,KO]  (no bias)
template <int KI, int KO>
__global__ __launch_bounds__(256)
void transform_kernel(const float* __restrict__ in, const float* __restrict__ W,
                      float* __restrict__ out, int n) {
    constexpr int NB = 256 / KO;
    __shared__ float Wl[KI * KO];
    __shared__ float tile[NB * KI];
    int t = threadIdx.x;
    for (int i = t; i < KI * KO; i += 256) Wl[i] = W[i];
    size_t base = (size_t)blockIdx.x * NB;
    for (int i = t; i < NB * KI; i += 256) {
        size_t nd = base + (size_t)(i / KI);
        tile[i] = (nd < (size_t)n) ? in[base * KI + i] : 0.f;
    }
    __syncthreads();
    int j = t % KO, nb = t / KO;
    size_t nd = base + nb;
    if (nd < (size_t)n) {
        float s = 0.f;
#pragma unroll
        for (int k = 0; k < KI; ++k) s += tile[nb * KI + k] * Wl[k * KO + j];
        out[nd * KO + j] = s;
    }
}

// Aggregate WD-wide features through CSR, add bias, write out.
template <int WD>
__global__ __launch_bounds__(256)
void agg_kernel(const float* __restrict__ h, const float* __restrict__ dis,
                const int* __restrict__ off, const int* __restrict__ col,
                const float* __restrict__ wgt, const float* __restrict__ b,
                float* __restrict__ out, int n) {
    int node = blockIdx.x * 256 + threadIdx.x;
    if (node >= n) return;
    float acc[WD];
    float di = dis[node], d2 = di * di;
    const float4* hr = (const float4*)(h + (size_t)node * WD);
#pragma unroll
    for (int q = 0; q < WD / 4; ++q) {
        float4 v = hr[q];
        acc[4 * q]     = d2 * v.x; acc[4 * q + 1] = d2 * v.y;
        acc[4 * q + 2] = d2 * v.z; acc[4 * q + 3] = d2 * v.w;
    }
    int e0 = off[node], e1 = off[node + 1];
    for (int e = e0; e < e1; ++e) {
        int s = col[e]; float w = wgt[e];
        const float4* hs = (const float4*)(h + (size_t)s * WD);
#pragma unroll
        for (int q = 0; q < WD / 4; ++q) {
            float4 v = hs[q];
            acc[4 * q]     += w * v.x; acc[4 * q + 1] += w * v.y;
            acc[4 * q + 2] += w * v.z; acc[4 * q + 3] += w * v.w;
        }
    }
    float4* orow = (float4*)(out + (size_t)node * WD);
#pragma unroll
    for (int q = 0; q < WD / 4; ++q) {
        float4 v;
        v.x = acc[4 * q]     + b[4 * q];
        v.y = acc[4 * q + 1] + b[4 * q + 1];
        v.z = acc[4 * q + 2] + b[4 * q + 2];
        v.w = acc[4 * q + 3] + b[4 * q + 3];
        orow[q] = v;
    }
}

// Mean-pool h2[n,32] per graph (equal sizes npg) -> Z[G,32]
__global__ __launch_bounds__(256)
void pool_kernel(const float* __restrict__ h2, const int* __restrict__ npg_p,
                 float* __restrict__ Z, int n) {
    int npg = npg_p[0];
    int G = n / npg;
    if (G > 4096) G = 4096;
    __shared__ float red[256];
    for (int g = blockIdx.x; g < G; g += gridDim.x) {
        int j = threadIdx.x & 31;
        int r0 = threadIdx.x >> 5;
        float acc = 0.f;
        for (int r = r0; r < npg; r += 8)
            acc += h2[((size_t)g * npg + r) * 32 + j];
        red[threadIdx.x] = acc;
        __syncthreads();
        if (threadIdx.x < 32) {
            float s = 0.f;
#pragma unroll
            for (int q = 0; q < 8; ++q) s += red[q * 32 + threadIdx.x];
            Z[g * 32 + threadIdx.x] = s / (float)npg;
        }
        __syncthreads();
    }
}

// Layer 3: aggregate per-graph z (LDS table) 32-wide, GEMM 32->64 + b3 + relu.
constexpr int ZCAP = 128;
__global__ __launch_bounds__(256)
void l3_kernel(const float* __restrict__ Z, const int* __restrict__ batch,
               const float* __restrict__ dis, const int* __restrict__ off,
               const int* __restrict__ col, const float* __restrict__ wgt,
               const int* __restrict__ npg_p,
               const float* __restrict__ W3, const float* __restrict__ b3,
               float* __restrict__ dOut, int n) {
    __shared__ float Zl[ZCAP * 33];
    __shared__ float accs[256][33];
    __shared__ float Wl[32 * 64];
    __shared__ float bl[64];
    int t = threadIdx.x;
    int npg = npg_p[0];
    int G = n / npg;
    bool lds_z = (G <= ZCAP);
    if (lds_z) {
        for (int i = t; i < G * 32; i += 256)
            Zl[(i / 32) * 33 + (i % 32)] = Z[i];
    }
    for (int i = t; i < 32 * 64; i += 256) Wl[i] = W3[i];
    if (t < 64) bl[t] = b3[t];
    __syncthreads();

    int node = blockIdx.x * 256 + t;
    float acc[32];
#pragma unroll
    for (int k = 0; k < 32; ++k) acc[k] = 0.f;
    if (node < n) {
        float di = dis[node], d2 = di * di;
        int gi = batch[node];
        if (lds_z) {
#pragma unroll
            for (int k = 0; k < 32; ++k) acc[k] = d2 * Zl[gi * 33 + k];
        } else {
#pragma unroll
            for (int k = 0; k < 32; ++k) acc[k] = d2 * Z[gi * 32 + k];
        }
        int e0 = off[node], e1 = off[node + 1];
        for (int e = e0; e < e1; ++e) {
            int s = col[e]; float w = wgt[e];
            int gs = batch[s];
            if (lds_z) {
#pragma unroll
                for (int k = 0; k < 32; ++k) acc[k] += w * Zl[gs * 33 + k];
            } else {
#pragma unroll
                for (int k = 0; k < 32; ++k) acc[k] += w * Z[gs * 32 + k];
            }
        }
    }
#pragma unroll
    for (int k = 0; k < 32; ++k) accs[t][k] = acc[k];
    __syncthreads();

    int base = blockIdx.x * 256;
    int j = t & 63;
    for (int nb = (t >> 6); nb < 256; nb += 4) {
        int nd = base + nb;
        if (nd >= n) break;
        float s = bl[j];
#pragma unroll
        for (int k = 0; k < 32; ++k) s += accs[nb][k] * Wl[k * 64 + j];
        dOut[(size_t)nd * 64 + j] = fmaxf(s, 0.f);
    }
}

extern "C" void kernel_launch(void* const* d_in, const int* in_sizes, int n_in,
                              void* d_out, int out_size, void* d_ws, size_t ws_size,
                              hipStream_t stream) {
    const float* x     = (const float*)d_in[0];
    const int*   ei    = (const int*)d_in[1];
    const int*   batch = (const int*)d_in[2];
    const int*   npg   = (const int*)d_in[3];
    const float* W1 = (const float*)d_in[4];
    const float* b1 = (const float*)d_in[5];
    const float* W2 = (const float*)d_in[6];
    const float* b2 = (const float*)d_in[7];
    const float* W3 = (const float*)d_in[8];
    const float* b3 = (const float*)d_in[9];
    const float* W4 = (const float*)d_in[10];
    const float* b4 = (const float*)d_in[11];
    float* out = (float*)d_out;

    int n = in_sizes[0] / 16;
    int E = in_sizes[1] / 2;
    const int* srcp = ei;
    const int* dstp = ei + E;

    char* w = (char*)d_ws;
    auto alloc = [&](size_t bytes) {
        char* p = w;
        w += (bytes + 255) & ~(size_t)255;
        return p;
    };
    int*   cnt = (int*)alloc((size_t)n * 4);
    float* dis = (float*)alloc((size_t)n * 4);
    int*   off = (int*)alloc(((size_t)n + 1) * 4);
    int*   cur = (int*)alloc((size_t)n * 4);
    int*   col = (int*)alloc((size_t)E * 4);
    float* wgt = (float*)alloc((size_t)E * 4);
    float* A   = (float*)alloc((size_t)n * 64 * 4);  // h1, later d
    float* B   = (float*)alloc((size_t)n * 32 * 4);  // t2, later t4
    float* C   = (float*)alloc((size_t)n * 32 * 4);  // h2
    float* Z   = (float*)alloc((size_t)4096 * 32 * 4);

    int nb256 = (n + 255) / 256;
    int eb256 = (E + 255) / 256;

    hipMemsetAsync(cnt, 0, (size_t)n * 4, stream);
    count_kernel<<<eb256, 256, 0, stream>>>(dstp, cnt, E);
    dis_kernel<<<nb256, 256, 0, stream>>>(cnt, dis, n);
    scan_kernel<<<1, 1024, 0, stream>>>(cnt, off, cur, n);
    fill_kernel<<<eb256, 256, 0, stream>>>(srcp, dstp, dis, cur, col, wgt, E);

    // encode
    l1_kernel<<<nb256, 256, 0, stream>>>(x, dis, off, col, wgt, W1, b1, A, n);
    transform_kernel<64, 32><<<(n + 7) / 8, 256, 0, stream>>>(A, W2, B, n);
    agg_kernel<32><<<nb256, 256, 0, stream>>>(B, dis, off, col, wgt, b2, C, n);
    pool_kernel<<<256, 256, 0, stream>>>(C, npg, Z, n);

    // decode
    l3_kernel<<<nb256, 256, 0, stream>>>(Z, batch, dis, off, col, wgt, npg, W3, b3, A, n);
    transform_kernel<64, 16><<<(n + 15) / 16, 256, 0, stream>>>(A, W4, B, n);
    agg_kernel<16><<<nb256, 256, 0, stream>>>(B, dis, off, col, wgt, b4, out, n);
}

// Round 2
// 481.750 us; speedup vs baseline: 1.4570x; 1.4570x over previous
//
#include <hip/hip_runtime.h>
#include <hip/hip_bf16.h>

// ---------------------------------------------------------------------------
// GraphAutoEncoder: 4x GCNConv + mean-pool + repeat, all f32.
// Strategy:
//   - Build incoming-edge CSR once per call (count / rsqrt / 3-level scan / fill).
//   - Self-loop handled analytically: out[i] += dis[i]^2 * h[i].
//   - Aggregate on the narrow side of each layer (16 / 32 / z-LDS / 16 wide).
//   - Fused agg+GEMM kernels with LDS phase-split for coalesced stores.
// R1: replaced single-block scan (231 us, 1 CU) with 3-level hierarchical scan.
// ---------------------------------------------------------------------------

__global__ void count_kernel(const int* __restrict__ dst, int* __restrict__ cnt, int E) {
    int e = blockIdx.x * blockDim.x + threadIdx.x;
    if (e < E) atomicAdd(&cnt[dst[e]], 1);
}

__global__ void dis_kernel(const int* __restrict__ cnt, float* __restrict__ dis, int n) {
    int i = blockIdx.x * blockDim.x + threadIdx.x;
    if (i < n) dis[i] = rsqrtf((float)cnt[i] + 1.0f);   // +1 = self-loop
}

// ---- hierarchical exclusive scan over cnt[0..n) -> off[0..n], cur copy ----
constexpr int SCAN_ITEMS = 4;
constexpr int SCAN_BLK   = 256;
constexpr int SCAN_CHUNK = SCAN_BLK * SCAN_ITEMS;   // 1024 elements / block

__global__ __launch_bounds__(256)
void bsum_kernel(const int* __restrict__ cnt, int* __restrict__ bsum, int n) {
    int base = blockIdx.x * SCAN_CHUNK + threadIdx.x * SCAN_ITEMS;
    int s = 0;
#pragma unroll
    for (int i = 0; i < SCAN_ITEMS; ++i) {
        int idx = base + i;
        if (idx < n) s += cnt[idx];
    }
#pragma unroll
    for (int d = 32; d > 0; d >>= 1) s += __shfl_down(s, d);
    __shared__ int red[SCAN_BLK / 64];
    int lane = threadIdx.x & 63, wv = threadIdx.x >> 6;
    if (lane == 0) red[wv] = s;
    __syncthreads();
    if (threadIdx.x == 0) {
        int t = 0;
#pragma unroll
        for (int q = 0; q < SCAN_BLK / 64; ++q) t += red[q];
        bsum[blockIdx.x] = t;
    }
}

// one small block: exclusive scan of nb block sums (nb <= 256*chunk, tiny)
__global__ __launch_bounds__(256)
void bscan_kernel(int* __restrict__ bsum, int nb) {
    __shared__ int sums[256];
    int t = threadIdx.x;
    int chunk = (nb + 255) >> 8;
    int start = t * chunk, end = min(start + chunk, nb);
    int s = 0;
    for (int i = start; i < end; ++i) s += bsum[i];
    sums[t] = s;
    __syncthreads();
    for (int d = 1; d < 256; d <<= 1) {
        int v = (t >= d) ? sums[t - d] : 0;
        __syncthreads();
        sums[t] += v;
        __syncthreads();
    }
    int run = (t == 0) ? 0 : sums[t - 1];
    for (int i = start; i < end; ++i) {
        int c = bsum[i];
        bsum[i] = run;      // becomes exclusive block offset
        run += c;
    }
}

__global__ __launch_bounds__(256)
void bfill_kernel(const int* __restrict__ cnt, const int* __restrict__ bsum,
                  int* __restrict__ off, int* __restrict__ cur, int n) {
    __shared__ int tsum[SCAN_BLK];
    int t = threadIdx.x;
    int base = blockIdx.x * SCAN_CHUNK + t * SCAN_ITEMS;
    int v[SCAN_ITEMS];
    int s = 0;
#pragma unroll
    for (int i = 0; i < SCAN_ITEMS; ++i) {
        int idx = base + i;
        v[i] = (idx < n) ? cnt[idx] : 0;
        s += v[i];
    }
    tsum[t] = s;
    __syncthreads();
    for (int d = 1; d < SCAN_BLK; d <<= 1) {
        int x = (t >= d) ? tsum[t - d] : 0;
        __syncthreads();
        tsum[t] += x;
        __syncthreads();
    }
    int run = bsum[blockIdx.x] + ((t == 0) ? 0 : tsum[t - 1]);
#pragma unroll
    for (int i = 0; i < SCAN_ITEMS; ++i) {
        int idx = base + i;
        if (idx < n) {
            off[idx] = run; cur[idx] = run; run += v[i];
            if (idx == n - 1) off[n] = run;
        }
    }
}

__global__ void fill_kernel(const int* __restrict__ src, const int* __restrict__ dst,
                            const float* __restrict__ dis, int* __restrict__ cur,
                            int* __restrict__ col, float* __restrict__ wgt, int E) {
    int e = blockIdx.x * blockDim.x + threadIdx.x;
    if (e < E) {
        int s = src[e], d = dst[e];
        float w = dis[s] * dis[d];
        int p = atomicAdd(&cur[d], 1);
        col[p] = s;
        wgt[p] = w;
    }
}

// Layer 1: agg x (16-wide) then GEMM 16->64 + b1 + relu. Phase-split via LDS.
__global__ __launch_bounds__(256)
void l1_kernel(const float* __restrict__ x, const float* __restrict__ dis,
               const int* __restrict__ off, const int* __restrict__ col,
               const float* __restrict__ wgt,
               const float* __restrict__ W1, const float* __restrict__ b1,
               float* __restrict__ h1, int n) {
    __shared__ float accs[256][17];
    __shared__ float Wl[16 * 64];
    __shared__ float bl[64];
    int t = threadIdx.x;
    for (int i = t; i < 16 * 64; i += 256) Wl[i] = W1[i];
    if (t < 64) bl[t] = b1[t];

    int node = blockIdx.x * 256 + t;
    float acc[16];
#pragma unroll
    for (int k = 0; k < 16; ++k) acc[k] = 0.f;
    if (node < n) {
        float di = dis[node], d2 = di * di;
        const float4* xr = (const float4*)(x + (size_t)node * 16);
#pragma unroll
        for (int q = 0; q < 4; ++q) {
            float4 v = xr[q];
            acc[4 * q]     = d2 * v.x; acc[4 * q + 1] = d2 * v.y;
            acc[4 * q + 2] = d2 * v.z; acc[4 * q + 3] = d2 * v.w;
        }
        int e0 = off[node], e1 = off[node + 1];
        for (int e = e0; e < e1; ++e) {
            int s = col[e]; float w = wgt[e];
            const float4* xs = (const float4*)(x + (size_t)s * 16);
#pragma unroll
            for (int q = 0; q < 4; ++q) {
                float4 v = xs[q];
                acc[4 * q]     += w * v.x; acc[4 * q + 1] += w * v.y;
                acc[4 * q + 2] += w * v.z; acc[4 * q + 3] += w * v.w;
            }
        }
    }
#pragma unroll
    for (int k = 0; k < 16; ++k) accs[t][k] = acc[k];
    __syncthreads();

    int base = blockIdx.x * 256;
    int j = t & 63;
    for (int nb = (t >> 6); nb < 256; nb += 4) {
        int nd = base + nb;
        if (nd >= n) break;
        float s = bl[j];
#pragma unroll
        for (int k = 0; k < 16; ++k) s += accs[nb][k] * Wl[k * 64 + j];
        h1[(size_t)nd * 64 + j] = fmaxf(s, 0.f);
    }
}

// Dense transform: out[n,KO] = in[n,KI] @ W[KI,KO]  (no bias)
template <int KI, int KO>
__global__ __launch_bounds__(256)
void transform_kernel(const float* __restrict__ in, const float* __restrict__ W,
                      float* __restrict__ out, int n) {
    constexpr int NB = 256 / KO;
    __shared__ float Wl[KI * KO];
    __shared__ float tile[NB * KI];
    int t = threadIdx.x;
    for (int i = t; i < KI * KO; i += 256) Wl[i] = W[i];
    size_t base = (size_t)blockIdx.x * NB;
    for (int i = t; i < NB * KI; i += 256) {
        size_t nd = base + (size_t)(i / KI);
        tile[i] = (nd < (size_t)n) ? in[base * KI + i] : 0.f;
    }
    __syncthreads();
    int j = t % KO, nb = t / KO;
    size_t nd = base + nb;
    if (nd < (size_t)n) {
        float s = 0.f;
#pragma unroll
        for (int k = 0; k < KI; ++k) s += tile[nb * KI + k] * Wl[k * KO + j];
        out[nd * KO + j] = s;
    }
}

// Aggregate WD-wide features through CSR, add bias, write out.
template <int WD>
__global__ __launch_bounds__(256)
void agg_kernel(const float* __restrict__ h, const float* __restrict__ dis,
                const int* __restrict__ off, const int* __restrict__ col,
                const float* __restrict__ wgt, const float* __restrict__ b,
                float* __restrict__ out, int n) {
    int node = blockIdx.x * 256 + threadIdx.x;
    if (node >= n) return;
    float acc[WD];
    float di = dis[node], d2 = di * di;
    const float4* hr = (const float4*)(h + (size_t)node * WD);
#pragma unroll
    for (int q = 0; q < WD / 4; ++q) {
        float4 v = hr[q];
        acc[4 * q]     = d2 * v.x; acc[4 * q + 1] = d2 * v.y;
        acc[4 * q + 2] = d2 * v.z; acc[4 * q + 3] = d2 * v.w;
    }
    int e0 = off[node], e1 = off[node + 1];
    for (int e = e0; e < e1; ++e) {
        int s = col[e]; float w = wgt[e];
        const float4* hs = (const float4*)(h + (size_t)s * WD);
#pragma unroll
        for (int q = 0; q < WD / 4; ++q) {
            float4 v = hs[q];
            acc[4 * q]     += w * v.x; acc[4 * q + 1] += w * v.y;
            acc[4 * q + 2] += w * v.z; acc[4 * q + 3] += w * v.w;
        }
    }
    float4* orow = (float4*)(out + (size_t)node * WD);
#pragma unroll
    for (int q = 0; q < WD / 4; ++q) {
        float4 v;
        v.x = acc[4 * q]     + b[4 * q];
        v.y = acc[4 * q + 1] + b[4 * q + 1];
        v.z = acc[4 * q + 2] + b[4 * q + 2];
        v.w = acc[4 * q + 3] + b[4 * q + 3];
        orow[q] = v;
    }
}

// Mean-pool h2[n,32] per graph (equal sizes npg) -> Z[G,32]
__global__ __launch_bounds__(256)
void pool_kernel(const float* __restrict__ h2, const int* __restrict__ npg_p,
                 float* __restrict__ Z, int n) {
    int npg = npg_p[0];
    int G = n / npg;
    if (G > 4096) G = 4096;
    __shared__ float red[256];
    for (int g = blockIdx.x; g < G; g += gridDim.x) {
        int j = threadIdx.x & 31;
        int r0 = threadIdx.x >> 5;
        float acc = 0.f;
        for (int r = r0; r < npg; r += 8)
            acc += h2[((size_t)g * npg + r) * 32 + j];
        red[threadIdx.x] = acc;
        __syncthreads();
        if (threadIdx.x < 32) {
            float s = 0.f;
#pragma unroll
            for (int q = 0; q < 8; ++q) s += red[q * 32 + threadIdx.x];
            Z[g * 32 + threadIdx.x] = s / (float)npg;
        }
        __syncthreads();
    }
}

// Layer 3: aggregate per-graph z (LDS table) 32-wide, GEMM 32->64 + b3 + relu.
constexpr int ZCAP = 128;
__global__ __launch_bounds__(256)
void l3_kernel(const float* __restrict__ Z, const int* __restrict__ batch,
               const float* __restrict__ dis, const int* __restrict__ off,
               const int* __restrict__ col, const float* __restrict__ wgt,
               const int* __restrict__ npg_p,
               const float* __restrict__ W3, const float* __restrict__ b3,
               float* __restrict__ dOut, int n) {
    __shared__ float Zl[ZCAP * 33];
    __shared__ float accs[256][33];
    __shared__ float Wl[32 * 64];
    __shared__ float bl[64];
    int t = threadIdx.x;
    int npg = npg_p[0];
    int G = n / npg;
    bool lds_z = (G <= ZCAP);
    if (lds_z) {
        for (int i = t; i < G * 32; i += 256)
            Zl[(i / 32) * 33 + (i % 32)] = Z[i];
    }
    for (int i = t; i < 32 * 64; i += 256) Wl[i] = W3[i];
    if (t < 64) bl[t] = b3[t];
    __syncthreads();

    int node = blockIdx.x * 256 + t;
    float acc[32];
#pragma unroll
    for (int k = 0; k < 32; ++k) acc[k] = 0.f;
    if (node < n) {
        float di = dis[node], d2 = di * di;
        int gi = batch[node];
        if (lds_z) {
#pragma unroll
            for (int k = 0; k < 32; ++k) acc[k] = d2 * Zl[gi * 33 + k];
        } else {
#pragma unroll
            for (int k = 0; k < 32; ++k) acc[k] = d2 * Z[gi * 32 + k];
        }
        int e0 = off[node], e1 = off[node + 1];
        for (int e = e0; e < e1; ++e) {
            int s = col[e]; float w = wgt[e];
            int gs = batch[s];
            if (lds_z) {
#pragma unroll
                for (int k = 0; k < 32; ++k) acc[k] += w * Zl[gs * 33 + k];
            } else {
#pragma unroll
                for (int k = 0; k < 32; ++k) acc[k] += w * Z[gs * 32 + k];
            }
        }
    }
#pragma unroll
    for (int k = 0; k < 32; ++k) accs[t][k] = acc[k];
    __syncthreads();

    int base = blockIdx.x * 256;
    int j = t & 63;
    for (int nb = (t >> 6); nb < 256; nb += 4) {
        int nd = base + nb;
        if (nd >= n) break;
        float s = bl[j];
#pragma unroll
        for (int k = 0; k < 32; ++k) s += accs[nb][k] * Wl[k * 64 + j];
        dOut[(size_t)nd * 64 + j] = fmaxf(s, 0.f);
    }
}

extern "C" void kernel_launch(void* const* d_in, const int* in_sizes, int n_in,
                              void* d_out, int out_size, void* d_ws, size_t ws_size,
                              hipStream_t stream) {
    const float* x     = (const float*)d_in[0];
    const int*   ei    = (const int*)d_in[1];
    const int*   batch = (const int*)d_in[2];
    const int*   npg   = (const int*)d_in[3];
    const float* W1 = (const float*)d_in[4];
    const float* b1 = (const float*)d_in[5];
    const float* W2 = (const float*)d_in[6];
    const float* b2 = (const float*)d_in[7];
    const float* W3 = (const float*)d_in[8];
    const float* b3 = (const float*)d_in[9];
    const float* W4 = (const float*)d_in[10];
    const float* b4 = (const float*)d_in[11];
    float* out = (float*)d_out;

    int n = in_sizes[0] / 16;
    int E = in_sizes[1] / 2;
    const int* srcp = ei;
    const int* dstp = ei + E;

    char* w = (char*)d_ws;
    auto alloc = [&](size_t bytes) {
        char* p = w;
        w += (bytes + 255) & ~(size_t)255;
        return p;
    };
    int*   cnt  = (int*)alloc((size_t)n * 4);
    float* dis  = (float*)alloc((size_t)n * 4);
    int*   off  = (int*)alloc(((size_t)n + 1) * 4);
    int*   cur  = (int*)alloc((size_t)n * 4);
    int*   col  = (int*)alloc((size_t)E * 4);
    float* wgt  = (float*)alloc((size_t)E * 4);
    float* A    = (float*)alloc((size_t)n * 64 * 4);  // h1, later d
    float* B    = (float*)alloc((size_t)n * 32 * 4);  // t2, later t4
    float* C    = (float*)alloc((size_t)n * 32 * 4);  // h2
    float* Z    = (float*)alloc((size_t)4096 * 32 * 4);
    int*   bsum = (int*)alloc((size_t)4096 * 4);

    int nb256 = (n + 255) / 256;
    int eb256 = (E + 255) / 256;
    int nscan = (n + SCAN_CHUNK - 1) / SCAN_CHUNK;

    hipMemsetAsync(cnt, 0, (size_t)n * 4, stream);
    count_kernel<<<eb256, 256, 0, stream>>>(dstp, cnt, E);
    dis_kernel<<<nb256, 256, 0, stream>>>(cnt, dis, n);
    bsum_kernel<<<nscan, 256, 0, stream>>>(cnt, bsum, n);
    bscan_kernel<<<1, 256, 0, stream>>>(bsum, nscan);
    bfill_kernel<<<nscan, 256, 0, stream>>>(cnt, bsum, off, cur, n);
    fill_kernel<<<eb256, 256, 0, stream>>>(srcp, dstp, dis, cur, col, wgt, E);

    // encode
    l1_kernel<<<nb256, 256, 0, stream>>>(x, dis, off, col, wgt, W1, b1, A, n);
    transform_kernel<64, 32><<<(n + 7) / 8, 256, 0, stream>>>(A, W2, B, n);
    agg_kernel<32><<<nb256, 256, 0, stream>>>(B, dis, off, col, wgt, b2, C, n);
    pool_kernel<<<256, 256, 0, stream>>>(C, npg, Z, n);

    // decode
    l3_kernel<<<nb256, 256, 0, stream>>>(Z, batch, dis, off, col, wgt, npg, W3, b3, A, n);
    transform_kernel<64, 16><<<(n + 15) / 16, 256, 0, stream>>>(A, W4, B, n);
    agg_kernel<16><<<nb256, 256, 0, stream>>>(B, dis, off, col, wgt, b4, out, n);
}

// Round 3
// 409.489 us; speedup vs baseline: 1.7142x; 1.1765x over previous
//
#include <hip/hip_runtime.h>
#include <hip/hip_bf16.h>

// ---------------------------------------------------------------------------
// GraphAutoEncoder: 4x GCNConv + mean-pool + repeat, all f32.
// Strategy:
//   - Build incoming-edge CSR once per call (count / rsqrt / 3-level scan / fill).
//   - CSR payload interleaved as int2{col, wgt} -> ONE scattered 8B write/edge.
//   - Self-loop handled analytically: out[i] += dis[i]^2 * h[i].
//   - Aggregate on the narrow side of each layer (16 / 32 / z-LDS / 16 wide).
//   - Vector-per-node gathers: WD/4 lanes per node, one float4 gather per lane
//     per edge -> 4-8x more outstanding loads than thread-per-node.
// R1: 3-level hierarchical scan (was 231 us single-block).
// R2: int2 CSR payload (fill write traffic ~2x down), vector-per-node gathers.
// ---------------------------------------------------------------------------

__global__ void count_kernel(const int* __restrict__ dst, int* __restrict__ cnt, int E) {
    int e = blockIdx.x * blockDim.x + threadIdx.x;
    if (e < E) atomicAdd(&cnt[dst[e]], 1);
}

__global__ void dis_kernel(const int* __restrict__ cnt, float* __restrict__ dis, int n) {
    int i = blockIdx.x * blockDim.x + threadIdx.x;
    if (i < n) dis[i] = rsqrtf((float)cnt[i] + 1.0f);   // +1 = self-loop
}

// ---- hierarchical exclusive scan over cnt[0..n) -> off[0..n], cur copy ----
constexpr int SCAN_ITEMS = 4;
constexpr int SCAN_BLK   = 256;
constexpr int SCAN_CHUNK = SCAN_BLK * SCAN_ITEMS;   // 1024 elements / block

__global__ __launch_bounds__(256)
void bsum_kernel(const int* __restrict__ cnt, int* __restrict__ bsum, int n) {
    int base = blockIdx.x * SCAN_CHUNK + threadIdx.x * SCAN_ITEMS;
    int s = 0;
#pragma unroll
    for (int i = 0; i < SCAN_ITEMS; ++i) {
        int idx = base + i;
        if (idx < n) s += cnt[idx];
    }
#pragma unroll
    for (int d = 32; d > 0; d >>= 1) s += __shfl_down(s, d);
    __shared__ int red[SCAN_BLK / 64];
    int lane = threadIdx.x & 63, wv = threadIdx.x >> 6;
    if (lane == 0) red[wv] = s;
    __syncthreads();
    if (threadIdx.x == 0) {
        int t = 0;
#pragma unroll
        for (int q = 0; q < SCAN_BLK / 64; ++q) t += red[q];
        bsum[blockIdx.x] = t;
    }
}

__global__ __launch_bounds__(256)
void bscan_kernel(int* __restrict__ bsum, int nb) {
    __shared__ int sums[256];
    int t = threadIdx.x;
    int chunk = (nb + 255) >> 8;
    int start = t * chunk, end = min(start + chunk, nb);
    int s = 0;
    for (int i = start; i < end; ++i) s += bsum[i];
    sums[t] = s;
    __syncthreads();
    for (int d = 1; d < 256; d <<= 1) {
        int v = (t >= d) ? sums[t - d] : 0;
        __syncthreads();
        sums[t] += v;
        __syncthreads();
    }
    int run = (t == 0) ? 0 : sums[t - 1];
    for (int i = start; i < end; ++i) {
        int c = bsum[i];
        bsum[i] = run;      // becomes exclusive block offset
        run += c;
    }
}

__global__ __launch_bounds__(256)
void bfill_kernel(const int* __restrict__ cnt, const int* __restrict__ bsum,
                  int* __restrict__ off, int* __restrict__ cur, int n) {
    __shared__ int tsum[SCAN_BLK];
    int t = threadIdx.x;
    int base = blockIdx.x * SCAN_CHUNK + t * SCAN_ITEMS;
    int v[SCAN_ITEMS];
    int s = 0;
#pragma unroll
    for (int i = 0; i < SCAN_ITEMS; ++i) {
        int idx = base + i;
        v[i] = (idx < n) ? cnt[idx] : 0;
        s += v[i];
    }
    tsum[t] = s;
    __syncthreads();
    for (int d = 1; d < SCAN_BLK; d <<= 1) {
        int x = (t >= d) ? tsum[t - d] : 0;
        __syncthreads();
        tsum[t] += x;
        __syncthreads();
    }
    int run = bsum[blockIdx.x] + ((t == 0) ? 0 : tsum[t - 1]);
#pragma unroll
    for (int i = 0; i < SCAN_ITEMS; ++i) {
        int idx = base + i;
        if (idx < n) {
            off[idx] = run; cur[idx] = run; run += v[i];
            if (idx == n - 1) off[n] = run;
        }
    }
}

// Fill CSR payload: ONE interleaved 8B write per edge.
__global__ void fill_kernel(const int* __restrict__ src, const int* __restrict__ dst,
                            const float* __restrict__ dis, int* __restrict__ cur,
                            int2* __restrict__ ew, int E) {
    int e = blockIdx.x * blockDim.x + threadIdx.x;
    if (e < E) {
        int s = src[e], d = dst[e];
        float w = dis[s] * dis[d];
        int p = atomicAdd(&cur[d], 1);
        ew[p] = make_int2(s, __float_as_int(w));
    }
}

// Layer 1: agg x (16-wide, 4 lanes/node) then GEMM 16->64 + b1 + relu.
__global__ __launch_bounds__(256)
void l1_kernel(const float* __restrict__ x, const float* __restrict__ dis,
               const int* __restrict__ off, const int2* __restrict__ ew,
               const float* __restrict__ W1, const float* __restrict__ b1,
               float* __restrict__ h1, int n) {
    __shared__ float accs[64][17];
    __shared__ float Wl[16 * 64];
    __shared__ float bl[64];
    int t = threadIdx.x;
    for (int i = t; i < 16 * 64; i += 256) Wl[i] = W1[i];
    if (t < 64) bl[t] = b1[t];

    int q = t & 3, ln = t >> 2;
    int node = blockIdx.x * 64 + ln;
    const float4* xp = (const float4*)x;
    float4 acc = make_float4(0.f, 0.f, 0.f, 0.f);
    if (node < n) {
        float di = dis[node], d2 = di * di;
        float4 v = xp[(size_t)node * 4 + q];
        acc.x = d2 * v.x; acc.y = d2 * v.y; acc.z = d2 * v.z; acc.w = d2 * v.w;
        int e0 = off[node], e1 = off[node + 1];
        int e = e0;
        for (; e + 1 < e1; e += 2) {
            int2 a0 = ew[e], a1 = ew[e + 1];
            float4 v0 = xp[(size_t)a0.x * 4 + q];
            float4 v1 = xp[(size_t)a1.x * 4 + q];
            float w0 = __int_as_float(a0.y), w1 = __int_as_float(a1.y);
            acc.x += w0 * v0.x; acc.y += w0 * v0.y; acc.z += w0 * v0.z; acc.w += w0 * v0.w;
            acc.x += w1 * v1.x; acc.y += w1 * v1.y; acc.z += w1 * v1.z; acc.w += w1 * v1.w;
        }
        if (e < e1) {
            int2 a0 = ew[e];
            float4 v0 = xp[(size_t)a0.x * 4 + q];
            float w0 = __int_as_float(a0.y);
            acc.x += w0 * v0.x; acc.y += w0 * v0.y; acc.z += w0 * v0.z; acc.w += w0 * v0.w;
        }
    }
    accs[ln][q * 4 + 0] = acc.x; accs[ln][q * 4 + 1] = acc.y;
    accs[ln][q * 4 + 2] = acc.z; accs[ln][q * 4 + 3] = acc.w;
    __syncthreads();

    int base = blockIdx.x * 64;
    int j = t & 63;
    for (int nb = (t >> 6); nb < 64; nb += 4) {
        int nd = base + nb;
        if (nd >= n) break;
        float s = bl[j];
#pragma unroll
        for (int k = 0; k < 16; ++k) s += accs[nb][k] * Wl[k * 64 + j];
        h1[(size_t)nd * 64 + j] = fmaxf(s, 0.f);
    }
}

// Dense transform: out[n,KO] = in[n,KI] @ W[KI,KO]  (no bias)
template <int KI, int KO>
__global__ __launch_bounds__(256)
void transform_kernel(const float* __restrict__ in, const float* __restrict__ W,
                      float* __restrict__ out, int n) {
    constexpr int NB = 256 / KO;
    __shared__ float Wl[KI * KO];
    __shared__ float tile[NB * KI];
    int t = threadIdx.x;
    for (int i = t; i < KI * KO; i += 256) Wl[i] = W[i];
    size_t base = (size_t)blockIdx.x * NB;
    for (int i = t; i < NB * KI; i += 256) {
        size_t nd = base + (size_t)(i / KI);
        tile[i] = (nd < (size_t)n) ? in[base * KI + i] : 0.f;
    }
    __syncthreads();
    int j = t % KO, nb = t / KO;
    size_t nd = base + nb;
    if (nd < (size_t)n) {
        float s = 0.f;
#pragma unroll
        for (int k = 0; k < KI; ++k) s += tile[nb * KI + k] * Wl[k * KO + j];
        out[nd * KO + j] = s;
    }
}

// Aggregate WD-wide features through CSR; WD/4 lanes per node, one float4 each.
template <int WD>
__global__ __launch_bounds__(256)
void agg_kernel(const float* __restrict__ h, const float* __restrict__ dis,
                const int* __restrict__ off, const int2* __restrict__ ew,
                const float* __restrict__ b, float* __restrict__ out, int n) {
    constexpr int TPN = WD / 4;
    constexpr int NPB = 256 / TPN;
    int t = threadIdx.x;
    int q = t % TPN, ln = t / TPN;
    int node = blockIdx.x * NPB + ln;
    if (node >= n) return;
    const float4* hp = (const float4*)h;
    float di = dis[node], d2 = di * di;
    float4 v = hp[(size_t)node * TPN + q];
    float4 acc;
    acc.x = d2 * v.x; acc.y = d2 * v.y; acc.z = d2 * v.z; acc.w = d2 * v.w;
    int e0 = off[node], e1 = off[node + 1];
    int e = e0;
    for (; e + 1 < e1; e += 2) {
        int2 a0 = ew[e], a1 = ew[e + 1];
        float4 v0 = hp[(size_t)a0.x * TPN + q];
        float4 v1 = hp[(size_t)a1.x * TPN + q];
        float w0 = __int_as_float(a0.y), w1 = __int_as_float(a1.y);
        acc.x += w0 * v0.x; acc.y += w0 * v0.y; acc.z += w0 * v0.z; acc.w += w0 * v0.w;
        acc.x += w1 * v1.x; acc.y += w1 * v1.y; acc.z += w1 * v1.z; acc.w += w1 * v1.w;
    }
    if (e < e1) {
        int2 a0 = ew[e];
        float4 v0 = hp[(size_t)a0.x * TPN + q];
        float w0 = __int_as_float(a0.y);
        acc.x += w0 * v0.x; acc.y += w0 * v0.y; acc.z += w0 * v0.z; acc.w += w0 * v0.w;
    }
    float4 bb = ((const float4*)b)[q];
    float4 o;
    o.x = acc.x + bb.x; o.y = acc.y + bb.y; o.z = acc.z + bb.z; o.w = acc.w + bb.w;
    ((float4*)out)[(size_t)node * TPN + q] = o;
}

// Mean-pool h2[n,32] per graph (equal sizes npg) -> Z[G,32]
__global__ __launch_bounds__(256)
void pool_kernel(const float* __restrict__ h2, const int* __restrict__ npg_p,
                 float* __restrict__ Z, int n) {
    int npg = npg_p[0];
    int G = n / npg;
    if (G > 4096) G = 4096;
    __shared__ float red[256];
    for (int g = blockIdx.x; g < G; g += gridDim.x) {
        int j = threadIdx.x & 31;
        int r0 = threadIdx.x >> 5;
        float acc = 0.f;
        for (int r = r0; r < npg; r += 8)
            acc += h2[((size_t)g * npg + r) * 32 + j];
        red[threadIdx.x] = acc;
        __syncthreads();
        if (threadIdx.x < 32) {
            float s = 0.f;
#pragma unroll
            for (int q = 0; q < 8; ++q) s += red[q * 32 + threadIdx.x];
            Z[g * 32 + threadIdx.x] = s / (float)npg;
        }
        __syncthreads();
    }
}

// Layer 3: aggregate per-graph z (LDS table, 8 lanes/node), GEMM 32->64 + b3 + relu.
constexpr int ZCAP = 128;
__global__ __launch_bounds__(256)
void l3_kernel(const float* __restrict__ Z, const int* __restrict__ batch,
               const float* __restrict__ dis, const int* __restrict__ off,
               const int2* __restrict__ ew, const int* __restrict__ npg_p,
               const float* __restrict__ W3, const float* __restrict__ b3,
               float* __restrict__ dOut, int n) {
    __shared__ float Zl[ZCAP * 33];
    __shared__ float accs[32][33];
    __shared__ float Wl[32 * 64];
    __shared__ float bl[64];
    int t = threadIdx.x;
    int npg = npg_p[0];
    int G = n / npg;
    bool lds_z = (G <= ZCAP);
    if (lds_z) {
        for (int i = t; i < G * 32; i += 256)
            Zl[(i / 32) * 33 + (i % 32)] = Z[i];
    }
    for (int i = t; i < 32 * 64; i += 256) Wl[i] = W3[i];
    if (t < 64) bl[t] = b3[t];
    __syncthreads();

    int q = t & 7, ln = t >> 3;          // 8 lanes/node, 32 nodes/block
    int node = blockIdx.x * 32 + ln;
    float acc[4] = {0.f, 0.f, 0.f, 0.f};
    if (node < n) {
        float di = dis[node], d2 = di * di;
        int gi = batch[node];
        const float* zg = lds_z ? &Zl[gi * 33] : &Z[gi * 32];
        int zs = lds_z ? 33 : 32;
#pragma unroll
        for (int i = 0; i < 4; ++i) acc[i] = d2 * zg[q * 4 + i];
        int e0 = off[node], e1 = off[node + 1];
        int e = e0;
        for (; e + 1 < e1; e += 2) {
            int2 a0 = ew[e], a1 = ew[e + 1];
            int g0 = batch[a0.x], g1 = batch[a1.x];
            float w0 = __int_as_float(a0.y), w1 = __int_as_float(a1.y);
            const float* z0 = lds_z ? &Zl[g0 * 33] : &Z[g0 * 32];
            const float* z1 = lds_z ? &Zl[g1 * 33] : &Z[g1 * 32];
#pragma unroll
            for (int i = 0; i < 4; ++i) acc[i] += w0 * z0[q * 4 + i];
#pragma unroll
            for (int i = 0; i < 4; ++i) acc[i] += w1 * z1[q * 4 + i];
        }
        if (e < e1) {
            int2 a0 = ew[e];
            int g0 = batch[a0.x];
            float w0 = __int_as_float(a0.y);
            const float* z0 = lds_z ? &Zl[g0 * 33] : &Z[g0 * 32];
#pragma unroll
            for (int i = 0; i < 4; ++i) acc[i] += w0 * z0[q * 4 + i];
        }
        (void)zs;
    }
#pragma unroll
    for (int i = 0; i < 4; ++i) accs[ln][q * 4 + i] = acc[i];
    __syncthreads();

    int base = blockIdx.x * 32;
    int j = t & 63;
    for (int nb = (t >> 6); nb < 32; nb += 4) {
        int nd = base + nb;
        if (nd >= n) break;
        float s = bl[j];
#pragma unroll
        for (int k = 0; k < 32; ++k) s += accs[nb][k] * Wl[k * 64 + j];
        dOut[(size_t)nd * 64 + j] = fmaxf(s, 0.f);
    }
}

extern "C" void kernel_launch(void* const* d_in, const int* in_sizes, int n_in,
                              void* d_out, int out_size, void* d_ws, size_t ws_size,
                              hipStream_t stream) {
    const float* x     = (const float*)d_in[0];
    const int*   ei    = (const int*)d_in[1];
    const int*   batch = (const int*)d_in[2];
    const int*   npg   = (const int*)d_in[3];
    const float* W1 = (const float*)d_in[4];
    const float* b1 = (const float*)d_in[5];
    const float* W2 = (const float*)d_in[6];
    const float* b2 = (const float*)d_in[7];
    const float* W3 = (const float*)d_in[8];
    const float* b3 = (const float*)d_in[9];
    const float* W4 = (const float*)d_in[10];
    const float* b4 = (const float*)d_in[11];
    float* out = (float*)d_out;

    int n = in_sizes[0] / 16;
    int E = in_sizes[1] / 2;
    const int* srcp = ei;
    const int* dstp = ei + E;

    char* w = (char*)d_ws;
    auto alloc = [&](size_t bytes) {
        char* p = w;
        w += (bytes + 255) & ~(size_t)255;
        return p;
    };
    int*   cnt  = (int*)alloc((size_t)n * 4);
    float* dis  = (float*)alloc((size_t)n * 4);
    int*   off  = (int*)alloc(((size_t)n + 1) * 4);
    int*   cur  = (int*)alloc((size_t)n * 4);
    int2*  ew   = (int2*)alloc((size_t)E * 8);
    float* A    = (float*)alloc((size_t)n * 64 * 4);  // h1, later d
    float* B    = (float*)alloc((size_t)n * 32 * 4);  // t2, later t4
    float* C    = (float*)alloc((size_t)n * 32 * 4);  // h2
    float* Z    = (float*)alloc((size_t)4096 * 32 * 4);
    int*   bsum = (int*)alloc((size_t)4096 * 4);

    int nb256 = (n + 255) / 256;
    int eb256 = (E + 255) / 256;
    int nscan = (n + SCAN_CHUNK - 1) / SCAN_CHUNK;

    hipMemsetAsync(cnt, 0, (size_t)n * 4, stream);
    count_kernel<<<eb256, 256, 0, stream>>>(dstp, cnt, E);
    dis_kernel<<<nb256, 256, 0, stream>>>(cnt, dis, n);
    bsum_kernel<<<nscan, 256, 0, stream>>>(cnt, bsum, n);
    bscan_kernel<<<1, 256, 0, stream>>>(bsum, nscan);
    bfill_kernel<<<nscan, 256, 0, stream>>>(cnt, bsum, off, cur, n);
    fill_kernel<<<eb256, 256, 0, stream>>>(srcp, dstp, dis, cur, ew, E);

    // encode
    l1_kernel<<<(n + 63) / 64, 256, 0, stream>>>(x, dis, off, ew, W1, b1, A, n);
    transform_kernel<64, 32><<<(n + 7) / 8, 256, 0, stream>>>(A, W2, B, n);
    agg_kernel<32><<<(n + 31) / 32, 256, 0, stream>>>(B, dis, off, ew, b2, C, n);
    pool_kernel<<<256, 256, 0, stream>>>(C, npg, Z, n);

    // decode
    l3_kernel<<<(n + 31) / 32, 256, 0, stream>>>(Z, batch, dis, off, ew, npg, W3, b3, A, n);
    transform_kernel<64, 16><<<(n + 15) / 16, 256, 0, stream>>>(A, W4, B, n);
    agg_kernel<16><<<(n + 63) / 64, 256, 0, stream>>>(B, dis, off, ew, b4, out, n);
}

// Round 4
// 376.789 us; speedup vs baseline: 1.8629x; 1.0868x over previous
//
#include <hip/hip_runtime.h>
#include <hip/hip_bf16.h>

// ---------------------------------------------------------------------------
// GraphAutoEncoder: 4x GCNConv + mean-pool + repeat, all f32.
// Strategy:
//   - Build incoming-edge CSR once per call: count / 3-level scan / LDS-binned
//     bucket sort (coalesced) / per-bucket LDS-scan scatter (L2-local writes).
//   - CSR payload interleaved as int2{col, wgt}.
//   - Self-loop handled analytically: out[i] += dis[i]^2 * h[i].
//   - Aggregate on the narrow side of each layer (16 / 32 / z-LDS / 16 wide).
//   - Vector-per-node gathers: WD/4 lanes per node, one float4 gather per lane.
// R1: 3-level hierarchical scan (was 231 us single-block).
// R2: int2 CSR payload, vector-per-node gathers.
// R3: binned CSR fill — old fill_kernel scattered 8B writes dirtied 101 MB of
//     lines (64B/edge); now bucket-local scatter keeps writes in L2 (~20 MB).
// ---------------------------------------------------------------------------

constexpr int BSZ_LOG = 9;                 // bucket = 512 dst nodes
constexpr int BSZ     = 1 << BSZ_LOG;
constexpr int NBMAX   = 256;               // max buckets (n <= 128K)
constexpr int ECHUNK  = 8192;              // edges per binfill block

__global__ void count_kernel(const int* __restrict__ dst, int* __restrict__ cnt, int E) {
    int e = blockIdx.x * blockDim.x + threadIdx.x;
    if (e < E) atomicAdd(&cnt[dst[e]], 1);
}

__global__ void dis_kernel(const int* __restrict__ cnt, float* __restrict__ dis, int n) {
    int i = blockIdx.x * blockDim.x + threadIdx.x;
    if (i < n) dis[i] = rsqrtf((float)cnt[i] + 1.0f);   // +1 = self-loop
}

// ---- hierarchical exclusive scan over cnt[0..n) -> off[0..n] ----
constexpr int SCAN_ITEMS = 4;
constexpr int SCAN_BLK   = 256;
constexpr int SCAN_CHUNK = SCAN_BLK * SCAN_ITEMS;   // 1024 elements / block

__global__ __launch_bounds__(256)
void bsum_kernel(const int* __restrict__ cnt, int* __restrict__ bsum, int n) {
    int base = blockIdx.x * SCAN_CHUNK + threadIdx.x * SCAN_ITEMS;
    int s = 0;
#pragma unroll
    for (int i = 0; i < SCAN_ITEMS; ++i) {
        int idx = base + i;
        if (idx < n) s += cnt[idx];
    }
#pragma unroll
    for (int d = 32; d > 0; d >>= 1) s += __shfl_down(s, d);
    __shared__ int red[SCAN_BLK / 64];
    int lane = threadIdx.x & 63, wv = threadIdx.x >> 6;
    if (lane == 0) red[wv] = s;
    __syncthreads();
    if (threadIdx.x == 0) {
        int t = 0;
#pragma unroll
        for (int q = 0; q < SCAN_BLK / 64; ++q) t += red[q];
        bsum[blockIdx.x] = t;
    }
}

__global__ __launch_bounds__(256)
void bscan_kernel(int* __restrict__ bsum, int nb) {
    __shared__ int sums[256];
    int t = threadIdx.x;
    int chunk = (nb + 255) >> 8;
    int start = t * chunk, end = min(start + chunk, nb);
    int s = 0;
    for (int i = start; i < end; ++i) s += bsum[i];
    sums[t] = s;
    __syncthreads();
    for (int d = 1; d < 256; d <<= 1) {
        int v = (t >= d) ? sums[t - d] : 0;
        __syncthreads();
        sums[t] += v;
        __syncthreads();
    }
    int run = (t == 0) ? 0 : sums[t - 1];
    for (int i = start; i < end; ++i) {
        int c = bsum[i];
        bsum[i] = run;
        run += c;
    }
}

__global__ __launch_bounds__(256)
void bfill_kernel(const int* __restrict__ cnt, const int* __restrict__ bsum,
                  int* __restrict__ off, int n) {
    __shared__ int tsum[SCAN_BLK];
    int t = threadIdx.x;
    int base = blockIdx.x * SCAN_CHUNK + t * SCAN_ITEMS;
    int v[SCAN_ITEMS];
    int s = 0;
#pragma unroll
    for (int i = 0; i < SCAN_ITEMS; ++i) {
        int idx = base + i;
        v[i] = (idx < n) ? cnt[idx] : 0;
        s += v[i];
    }
    tsum[t] = s;
    __syncthreads();
    for (int d = 1; d < SCAN_BLK; d <<= 1) {
        int x = (t >= d) ? tsum[t - d] : 0;
        __syncthreads();
        tsum[t] += x;
        __syncthreads();
    }
    int run = bsum[blockIdx.x] + ((t == 0) ? 0 : tsum[t - 1]);
#pragma unroll
    for (int i = 0; i < SCAN_ITEMS; ++i) {
        int idx = base + i;
        if (idx < n) {
            off[idx] = run; run += v[i];
            if (idx == n - 1) off[n] = run;
        }
    }
}

// bstart[b] = off[min(b*BSZ, n)]; bcur = copy (binfill reservation cursors)
__global__ void bucket_init_kernel(const int* __restrict__ off, int* __restrict__ bstart,
                                   int* __restrict__ bcur, int n, int nbuck) {
    int b = blockIdx.x * blockDim.x + threadIdx.x;
    if (b <= nbuck) {
        int idx = b << BSZ_LOG;
        if (idx > n) idx = n;
        int v = off[idx];
        bstart[b] = v;
        if (b < nbuck) bcur[b] = v;
    }
}

// Pass 1: LDS-binned bucket sort. code = (dst_local << 20) | src  (src < 2^20).
__global__ __launch_bounds__(256)
void binfill_kernel(const int* __restrict__ src, const int* __restrict__ dst,
                    int* __restrict__ bcur, int* __restrict__ binned, int E) {
    __shared__ int hist[NBMAX], hexcl[NBMAX], gbase[NBMAX], hpos[NBMAX], tmp[NBMAX];
    __shared__ int sorted[ECHUNK];
    __shared__ unsigned char bsorted[ECHUNK];
    int t = threadIdx.x;
    hist[t] = 0; hpos[t] = 0;
    __syncthreads();
    int e0 = blockIdx.x * ECHUNK;
    int cnt = min(ECHUNK, E - e0);
    // A: histogram buckets
    for (int i = t; i < cnt; i += 256)
        atomicAdd(&hist[dst[e0 + i] >> BSZ_LOG], 1);
    __syncthreads();
    // B: exclusive scan + global reservation
    tmp[t] = hist[t];
    __syncthreads();
    for (int d = 1; d < 256; d <<= 1) {
        int v = (t >= d) ? tmp[t - d] : 0;
        __syncthreads();
        tmp[t] += v;
        __syncthreads();
    }
    hexcl[t] = (t == 0) ? 0 : tmp[t - 1];
    int h = hist[t];
    gbase[t] = (h > 0) ? atomicAdd(&bcur[t], h) : 0;
    __syncthreads();
    // C: re-read edges (L2-warm), place sorted-by-bucket in LDS
    for (int i = t; i < cnt; i += 256) {
        int s = src[e0 + i], d = dst[e0 + i];
        int b = d >> BSZ_LOG;
        int code = ((d & (BSZ - 1)) << 20) | s;
        int sp = hexcl[b] + atomicAdd(&hpos[b], 1);
        sorted[sp] = code;
        bsorted[sp] = (unsigned char)b;
    }
    __syncthreads();
    // D: coalesced write-out in per-bucket runs
    for (int i = t; i < cnt; i += 256) {
        int b = bsorted[i];
        binned[gbase[b] + (i - hexcl[b])] = sorted[i];
    }
}

// Pass 2: one block per bucket; LDS node-hist + scan -> exact CSR positions.
// No global atomics; writes land in the bucket's ~64KB window (L2-local).
__global__ __launch_bounds__(256)
void bucket_csr_kernel(const int* __restrict__ binned, const int* __restrict__ bstart,
                       const float* __restrict__ dis, int2* __restrict__ ew, int n) {
    __shared__ int lstart[BSZ];
    __shared__ int lpos[BSZ];
    __shared__ float ldis[BSZ];
    __shared__ int partial[256];
    int b = blockIdx.x, t = threadIdx.x;
    int nb0 = b << BSZ_LOG;
    int nn = min(BSZ, n - nb0);
    int e0 = bstart[b], m = bstart[b + 1] - e0;
    for (int i = t; i < BSZ; i += 256) {
        lstart[i] = 0; lpos[i] = 0;
        ldis[i] = (i < nn) ? dis[nb0 + i] : 0.f;
    }
    __syncthreads();
    // A: node histogram
    for (int i = t; i < m; i += 256)
        atomicAdd(&lstart[binned[e0 + i] >> 20], 1);
    __syncthreads();
    // scan 512 with 256 threads (2 per thread)
    int a0 = lstart[2 * t], a1 = lstart[2 * t + 1];
    partial[t] = a0 + a1;
    __syncthreads();
    for (int d = 1; d < 256; d <<= 1) {
        int v = (t >= d) ? partial[t - d] : 0;
        __syncthreads();
        partial[t] += v;
        __syncthreads();
    }
    int base = (t == 0) ? 0 : partial[t - 1];
    lstart[2 * t] = base;
    lstart[2 * t + 1] = base + a0;
    __syncthreads();
    // B: scatter to exact positions
    for (int i = t; i < m; i += 256) {
        int code = binned[e0 + i];
        int dl = code >> 20, s = code & 0xFFFFF;
        float w = dis[s] * ldis[dl];
        int p = e0 + lstart[dl] + atomicAdd(&lpos[dl], 1);
        ew[p] = make_int2(s, __float_as_int(w));
    }
}

// Layer 1: agg x (16-wide, 4 lanes/node) then GEMM 16->64 + b1 + relu.
__global__ __launch_bounds__(256)
void l1_kernel(const float* __restrict__ x, const float* __restrict__ dis,
               const int* __restrict__ off, const int2* __restrict__ ew,
               const float* __restrict__ W1, const float* __restrict__ b1,
               float* __restrict__ h1, int n) {
    __shared__ float accs[64][17];
    __shared__ float Wl[16 * 64];
    __shared__ float bl[64];
    int t = threadIdx.x;
    for (int i = t; i < 16 * 64; i += 256) Wl[i] = W1[i];
    if (t < 64) bl[t] = b1[t];

    int q = t & 3, ln = t >> 2;
    int node = blockIdx.x * 64 + ln;
    const float4* xp = (const float4*)x;
    float4 acc = make_float4(0.f, 0.f, 0.f, 0.f);
    if (node < n) {
        float di = dis[node], d2 = di * di;
        float4 v = xp[(size_t)node * 4 + q];
        acc.x = d2 * v.x; acc.y = d2 * v.y; acc.z = d2 * v.z; acc.w = d2 * v.w;
        int e0 = off[node], e1 = off[node + 1];
        int e = e0;
        for (; e + 1 < e1; e += 2) {
            int2 a0 = ew[e], a1 = ew[e + 1];
            float4 v0 = xp[(size_t)a0.x * 4 + q];
            float4 v1 = xp[(size_t)a1.x * 4 + q];
            float w0 = __int_as_float(a0.y), w1 = __int_as_float(a1.y);
            acc.x += w0 * v0.x; acc.y += w0 * v0.y; acc.z += w0 * v0.z; acc.w += w0 * v0.w;
            acc.x += w1 * v1.x; acc.y += w1 * v1.y; acc.z += w1 * v1.z; acc.w += w1 * v1.w;
        }
        if (e < e1) {
            int2 a0 = ew[e];
            float4 v0 = xp[(size_t)a0.x * 4 + q];
            float w0 = __int_as_float(a0.y);
            acc.x += w0 * v0.x; acc.y += w0 * v0.y; acc.z += w0 * v0.z; acc.w += w0 * v0.w;
        }
    }
    accs[ln][q * 4 + 0] = acc.x; accs[ln][q * 4 + 1] = acc.y;
    accs[ln][q * 4 + 2] = acc.z; accs[ln][q * 4 + 3] = acc.w;
    __syncthreads();

    int base = blockIdx.x * 64;
    int j = t & 63;
    for (int nb = (t >> 6); nb < 64; nb += 4) {
        int nd = base + nb;
        if (nd >= n) break;
        float s = bl[j];
#pragma unroll
        for (int k = 0; k < 16; ++k) s += accs[nb][k] * Wl[k * 64 + j];
        h1[(size_t)nd * 64 + j] = fmaxf(s, 0.f);
    }
}

// Dense transform: out[n,KO] = in[n,KI] @ W[KI,KO]  (no bias)
template <int KI, int KO>
__global__ __launch_bounds__(256)
void transform_kernel(const float* __restrict__ in, const float* __restrict__ W,
                      float* __restrict__ out, int n) {
    constexpr int NB = 256 / KO;
    __shared__ float Wl[KI * KO];
    __shared__ float tile[NB * KI];
    int t = threadIdx.x;
    for (int i = t; i < KI * KO; i += 256) Wl[i] = W[i];
    size_t base = (size_t)blockIdx.x * NB;
    for (int i = t; i < NB * KI; i += 256) {
        size_t nd = base + (size_t)(i / KI);
        tile[i] = (nd < (size_t)n) ? in[base * KI + i] : 0.f;
    }
    __syncthreads();
    int j = t % KO, nb = t / KO;
    size_t nd = base + nb;
    if (nd < (size_t)n) {
        float s = 0.f;
#pragma unroll
        for (int k = 0; k < KI; ++k) s += tile[nb * KI + k] * Wl[k * KO + j];
        out[nd * KO + j] = s;
    }
}

// Aggregate WD-wide features through CSR; WD/4 lanes per node, one float4 each.
template <int WD>
__global__ __launch_bounds__(256)
void agg_kernel(const float* __restrict__ h, const float* __restrict__ dis,
                const int* __restrict__ off, const int2* __restrict__ ew,
                const float* __restrict__ b, float* __restrict__ out, int n) {
    constexpr int TPN = WD / 4;
    constexpr int NPB = 256 / TPN;
    int t = threadIdx.x;
    int q = t % TPN, ln = t / TPN;
    int node = blockIdx.x * NPB + ln;
    if (node >= n) return;
    const float4* hp = (const float4*)h;
    float di = dis[node], d2 = di * di;
    float4 v = hp[(size_t)node * TPN + q];
    float4 acc;
    acc.x = d2 * v.x; acc.y = d2 * v.y; acc.z = d2 * v.z; acc.w = d2 * v.w;
    int e0 = off[node], e1 = off[node + 1];
    int e = e0;
    for (; e + 1 < e1; e += 2) {
        int2 a0 = ew[e], a1 = ew[e + 1];
        float4 v0 = hp[(size_t)a0.x * TPN + q];
        float4 v1 = hp[(size_t)a1.x * TPN + q];
        float w0 = __int_as_float(a0.y), w1 = __int_as_float(a1.y);
        acc.x += w0 * v0.x; acc.y += w0 * v0.y; acc.z += w0 * v0.z; acc.w += w0 * v0.w;
        acc.x += w1 * v1.x; acc.y += w1 * v1.y; acc.z += w1 * v1.z; acc.w += w1 * v1.w;
    }
    if (e < e1) {
        int2 a0 = ew[e];
        float4 v0 = hp[(size_t)a0.x * TPN + q];
        float w0 = __int_as_float(a0.y);
        acc.x += w0 * v0.x; acc.y += w0 * v0.y; acc.z += w0 * v0.z; acc.w += w0 * v0.w;
    }
    float4 bb = ((const float4*)b)[q];
    float4 o;
    o.x = acc.x + bb.x; o.y = acc.y + bb.y; o.z = acc.z + bb.z; o.w = acc.w + bb.w;
    ((float4*)out)[(size_t)node * TPN + q] = o;
}

// Mean-pool h2[n,32] per graph (equal sizes npg) -> Z[G,32]
__global__ __launch_bounds__(256)
void pool_kernel(const float* __restrict__ h2, const int* __restrict__ npg_p,
                 float* __restrict__ Z, int n) {
    int npg = npg_p[0];
    int G = n / npg;
    if (G > 4096) G = 4096;
    __shared__ float red[256];
    for (int g = blockIdx.x; g < G; g += gridDim.x) {
        int j = threadIdx.x & 31;
        int r0 = threadIdx.x >> 5;
        float acc = 0.f;
        for (int r = r0; r < npg; r += 8)
            acc += h2[((size_t)g * npg + r) * 32 + j];
        red[threadIdx.x] = acc;
        __syncthreads();
        if (threadIdx.x < 32) {
            float s = 0.f;
#pragma unroll
            for (int q = 0; q < 8; ++q) s += red[q * 32 + threadIdx.x];
            Z[g * 32 + threadIdx.x] = s / (float)npg;
        }
        __syncthreads();
    }
}

// Layer 3: aggregate per-graph z (LDS table, 8 lanes/node), GEMM 32->64 + b3 + relu.
constexpr int ZCAP = 128;
__global__ __launch_bounds__(256)
void l3_kernel(const float* __restrict__ Z, const int* __restrict__ batch,
               const float* __restrict__ dis, const int* __restrict__ off,
               const int2* __restrict__ ew, const int* __restrict__ npg_p,
               const float* __restrict__ W3, const float* __restrict__ b3,
               float* __restrict__ dOut, int n) {
    __shared__ float Zl[ZCAP * 33];
    __shared__ float accs[32][33];
    __shared__ float Wl[32 * 64];
    __shared__ float bl[64];
    int t = threadIdx.x;
    int npg = npg_p[0];
    int G = n / npg;
    bool lds_z = (G <= ZCAP);
    if (lds_z) {
        for (int i = t; i < G * 32; i += 256)
            Zl[(i / 32) * 33 + (i % 32)] = Z[i];
    }
    for (int i = t; i < 32 * 64; i += 256) Wl[i] = W3[i];
    if (t < 64) bl[t] = b3[t];
    __syncthreads();

    int q = t & 7, ln = t >> 3;          // 8 lanes/node, 32 nodes/block
    int node = blockIdx.x * 32 + ln;
    float acc[4] = {0.f, 0.f, 0.f, 0.f};
    if (node < n) {
        float di = dis[node], d2 = di * di;
        int gi = batch[node];
        const float* zg = lds_z ? &Zl[gi * 33] : &Z[gi * 32];
#pragma unroll
        for (int i = 0; i < 4; ++i) acc[i] = d2 * zg[q * 4 + i];
        int e0 = off[node], e1 = off[node + 1];
        int e = e0;
        for (; e + 1 < e1; e += 2) {
            int2 a0 = ew[e], a1 = ew[e + 1];
            int g0 = batch[a0.x], g1 = batch[a1.x];
            float w0 = __int_as_float(a0.y), w1 = __int_as_float(a1.y);
            const float* z0 = lds_z ? &Zl[g0 * 33] : &Z[g0 * 32];
            const float* z1 = lds_z ? &Zl[g1 * 33] : &Z[g1 * 32];
#pragma unroll
            for (int i = 0; i < 4; ++i) acc[i] += w0 * z0[q * 4 + i];
#pragma unroll
            for (int i = 0; i < 4; ++i) acc[i] += w1 * z1[q * 4 + i];
        }
        if (e < e1) {
            int2 a0 = ew[e];
            int g0 = batch[a0.x];
            float w0 = __int_as_float(a0.y);
            const float* z0 = lds_z ? &Zl[g0 * 33] : &Z[g0 * 32];
#pragma unroll
            for (int i = 0; i < 4; ++i) acc[i] += w0 * z0[q * 4 + i];
        }
    }
#pragma unroll
    for (int i = 0; i < 4; ++i) accs[ln][q * 4 + i] = acc[i];
    __syncthreads();

    int base = blockIdx.x * 32;
    int j = t & 63;
    for (int nb = (t >> 6); nb < 32; nb += 4) {
        int nd = base + nb;
        if (nd >= n) break;
        float s = bl[j];
#pragma unroll
        for (int k = 0; k < 32; ++k) s += accs[nb][k] * Wl[k * 64 + j];
        dOut[(size_t)nd * 64 + j] = fmaxf(s, 0.f);
    }
}

extern "C" void kernel_launch(void* const* d_in, const int* in_sizes, int n_in,
                              void* d_out, int out_size, void* d_ws, size_t ws_size,
                              hipStream_t stream) {
    const float* x     = (const float*)d_in[0];
    const int*   ei    = (const int*)d_in[1];
    const int*   batch = (const int*)d_in[2];
    const int*   npg   = (const int*)d_in[3];
    const float* W1 = (const float*)d_in[4];
    const float* b1 = (const float*)d_in[5];
    const float* W2 = (const float*)d_in[6];
    const float* b2 = (const float*)d_in[7];
    const float* W3 = (const float*)d_in[8];
    const float* b3 = (const float*)d_in[9];
    const float* W4 = (const float*)d_in[10];
    const float* b4 = (const float*)d_in[11];
    float* out = (float*)d_out;

    int n = in_sizes[0] / 16;
    int E = in_sizes[1] / 2;
    const int* srcp = ei;
    const int* dstp = ei + E;

    char* w = (char*)d_ws;
    auto alloc = [&](size_t bytes) {
        char* p = w;
        w += (bytes + 255) & ~(size_t)255;
        return p;
    };
    int*   cnt    = (int*)alloc((size_t)n * 4);
    float* dis    = (float*)alloc((size_t)n * 4);
    int*   off    = (int*)alloc(((size_t)n + 1) * 4);
    int*   binned = (int*)alloc((size_t)E * 4);
    int2*  ew     = (int2*)alloc((size_t)E * 8);
    float* A      = (float*)alloc((size_t)n * 64 * 4);  // h1, later d
    float* B      = (float*)alloc((size_t)n * 32 * 4);  // t2, later t4
    float* C      = (float*)alloc((size_t)n * 32 * 4);  // h2
    float* Z      = (float*)alloc((size_t)4096 * 32 * 4);
    int*   bsum   = (int*)alloc((size_t)4096 * 4);
    int*   bstart = (int*)alloc((size_t)(NBMAX + 1) * 4);
    int*   bcur   = (int*)alloc((size_t)NBMAX * 4);

    int nb256 = (n + 255) / 256;
    int eb256 = (E + 255) / 256;
    int nscan = (n + SCAN_CHUNK - 1) / SCAN_CHUNK;
    int nbuck = (n + BSZ - 1) / BSZ;
    int nbin  = (E + ECHUNK - 1) / ECHUNK;

    hipMemsetAsync(cnt, 0, (size_t)n * 4, stream);
    count_kernel<<<eb256, 256, 0, stream>>>(dstp, cnt, E);
    dis_kernel<<<nb256, 256, 0, stream>>>(cnt, dis, n);
    bsum_kernel<<<nscan, 256, 0, stream>>>(cnt, bsum, n);
    bscan_kernel<<<1, 256, 0, stream>>>(bsum, nscan);
    bfill_kernel<<<nscan, 256, 0, stream>>>(cnt, bsum, off, n);
    bucket_init_kernel<<<1, 256, 0, stream>>>(off, bstart, bcur, n, nbuck);
    binfill_kernel<<<nbin, 256, 0, stream>>>(srcp, dstp, bcur, binned, E);
    bucket_csr_kernel<<<nbuck, 256, 0, stream>>>(binned, bstart, dis, ew, n);

    // encode
    l1_kernel<<<(n + 63) / 64, 256, 0, stream>>>(x, dis, off, ew, W1, b1, A, n);
    transform_kernel<64, 32><<<(n + 7) / 8, 256, 0, stream>>>(A, W2, B, n);
    agg_kernel<32><<<(n + 31) / 32, 256, 0, stream>>>(B, dis, off, ew, b2, C, n);
    pool_kernel<<<256, 256, 0, stream>>>(C, npg, Z, n);

    // decode
    l3_kernel<<<(n + 31) / 32, 256, 0, stream>>>(Z, batch, dis, off, ew, npg, W3, b3, A, n);
    transform_kernel<64, 16><<<(n + 15) / 16, 256, 0, stream>>>(A, W4, B, n);
    agg_kernel<16><<<(n + 63) / 64, 256, 0, stream>>>(B, dis, off, ew, b4, out, n);
}

// Round 5
// 371.671 us; speedup vs baseline: 1.8886x; 1.0138x over previous
//
#include <hip/hip_runtime.h>
#include <hip/hip_bf16.h>

// ---------------------------------------------------------------------------
// GraphAutoEncoder: 4x GCNConv + mean-pool + repeat, all f32.
// Strategy:
//   - Build incoming-edge CSR once per call: count / 3-level scan / LDS-binned
//     bucket sort (coalesced) / per-bucket LDS-scan scatter (L2-local writes).
//   - CSR payload interleaved as int2{col, wgt}.
//   - Self-loop handled analytically: out[i] += dis[i]^2 * h[i].
//   - Aggregate on the narrow side of each layer (16 / 32 / ZW3-LDS / 16 wide).
//   - Vector-per-node gathers: lanes per node, one float4 gather per lane.
// R1: 3-level hierarchical scan (was 231 us single-block).
// R2: int2 CSR payload, vector-per-node gathers.
// R3: binned CSR fill (write-combining; was 101 MB of dirtied lines).
// R4: l3 rewritten as dec1: ZW3 = Z@W3 precomputed (100x64, LDS) so the edge
//     loop reads ONE broadcast int2 and g(src) = src/npg arithmetically —
//     removes the dependent batch[] gather and the whole GEMM phase.
// ---------------------------------------------------------------------------

constexpr int BSZ_LOG = 9;                 // bucket = 512 dst nodes
constexpr int BSZ     = 1 << BSZ_LOG;
constexpr int NBMAX   = 256;               // max buckets (n <= 128K)
constexpr int ECHUNK  = 8192;              // edges per binfill block

__global__ void count_kernel(const int* __restrict__ dst, int* __restrict__ cnt, int E) {
    int e = blockIdx.x * blockDim.x + threadIdx.x;
    if (e < E) atomicAdd(&cnt[dst[e]], 1);
}

__global__ void dis_kernel(const int* __restrict__ cnt, float* __restrict__ dis, int n) {
    int i = blockIdx.x * blockDim.x + threadIdx.x;
    if (i < n) dis[i] = rsqrtf((float)cnt[i] + 1.0f);   // +1 = self-loop
}

// ---- hierarchical exclusive scan over cnt[0..n) -> off[0..n] ----
constexpr int SCAN_ITEMS = 4;
constexpr int SCAN_BLK   = 256;
constexpr int SCAN_CHUNK = SCAN_BLK * SCAN_ITEMS;   // 1024 elements / block

__global__ __launch_bounds__(256)
void bsum_kernel(const int* __restrict__ cnt, int* __restrict__ bsum, int n) {
    int base = blockIdx.x * SCAN_CHUNK + threadIdx.x * SCAN_ITEMS;
    int s = 0;
#pragma unroll
    for (int i = 0; i < SCAN_ITEMS; ++i) {
        int idx = base + i;
        if (idx < n) s += cnt[idx];
    }
#pragma unroll
    for (int d = 32; d > 0; d >>= 1) s += __shfl_down(s, d);
    __shared__ int red[SCAN_BLK / 64];
    int lane = threadIdx.x & 63, wv = threadIdx.x >> 6;
    if (lane == 0) red[wv] = s;
    __syncthreads();
    if (threadIdx.x == 0) {
        int t = 0;
#pragma unroll
        for (int q = 0; q < SCAN_BLK / 64; ++q) t += red[q];
        bsum[blockIdx.x] = t;
    }
}

__global__ __launch_bounds__(256)
void bscan_kernel(int* __restrict__ bsum, int nb) {
    __shared__ int sums[256];
    int t = threadIdx.x;
    int chunk = (nb + 255) >> 8;
    int start = t * chunk, end = min(start + chunk, nb);
    int s = 0;
    for (int i = start; i < end; ++i) s += bsum[i];
    sums[t] = s;
    __syncthreads();
    for (int d = 1; d < 256; d <<= 1) {
        int v = (t >= d) ? sums[t - d] : 0;
        __syncthreads();
        sums[t] += v;
        __syncthreads();
    }
    int run = (t == 0) ? 0 : sums[t - 1];
    for (int i = start; i < end; ++i) {
        int c = bsum[i];
        bsum[i] = run;
        run += c;
    }
}

__global__ __launch_bounds__(256)
void bfill_kernel(const int* __restrict__ cnt, const int* __restrict__ bsum,
                  int* __restrict__ off, int n) {
    __shared__ int tsum[SCAN_BLK];
    int t = threadIdx.x;
    int base = blockIdx.x * SCAN_CHUNK + t * SCAN_ITEMS;
    int v[SCAN_ITEMS];
    int s = 0;
#pragma unroll
    for (int i = 0; i < SCAN_ITEMS; ++i) {
        int idx = base + i;
        v[i] = (idx < n) ? cnt[idx] : 0;
        s += v[i];
    }
    tsum[t] = s;
    __syncthreads();
    for (int d = 1; d < SCAN_BLK; d <<= 1) {
        int x = (t >= d) ? tsum[t - d] : 0;
        __syncthreads();
        tsum[t] += x;
        __syncthreads();
    }
    int run = bsum[blockIdx.x] + ((t == 0) ? 0 : tsum[t - 1]);
#pragma unroll
    for (int i = 0; i < SCAN_ITEMS; ++i) {
        int idx = base + i;
        if (idx < n) {
            off[idx] = run; run += v[i];
            if (idx == n - 1) off[n] = run;
        }
    }
}

// bstart[b] = off[min(b*BSZ, n)]; bcur = copy (binfill reservation cursors)
__global__ void bucket_init_kernel(const int* __restrict__ off, int* __restrict__ bstart,
                                   int* __restrict__ bcur, int n, int nbuck) {
    int b = blockIdx.x * blockDim.x + threadIdx.x;
    if (b <= nbuck) {
        int idx = b << BSZ_LOG;
        if (idx > n) idx = n;
        int v = off[idx];
        bstart[b] = v;
        if (b < nbuck) bcur[b] = v;
    }
}

// Pass 1: LDS-binned bucket sort. code = (dst_local << 20) | src  (src < 2^20).
__global__ __launch_bounds__(256)
void binfill_kernel(const int* __restrict__ src, const int* __restrict__ dst,
                    int* __restrict__ bcur, int* __restrict__ binned, int E) {
    __shared__ int hist[NBMAX], hexcl[NBMAX], gbase[NBMAX], hpos[NBMAX], tmp[NBMAX];
    __shared__ int sorted[ECHUNK];
    __shared__ unsigned char bsorted[ECHUNK];
    int t = threadIdx.x;
    hist[t] = 0; hpos[t] = 0;
    __syncthreads();
    int e0 = blockIdx.x * ECHUNK;
    int cnt = min(ECHUNK, E - e0);
    // A: histogram buckets
    for (int i = t; i < cnt; i += 256)
        atomicAdd(&hist[dst[e0 + i] >> BSZ_LOG], 1);
    __syncthreads();
    // B: exclusive scan + global reservation
    tmp[t] = hist[t];
    __syncthreads();
    for (int d = 1; d < 256; d <<= 1) {
        int v = (t >= d) ? tmp[t - d] : 0;
        __syncthreads();
        tmp[t] += v;
        __syncthreads();
    }
    hexcl[t] = (t == 0) ? 0 : tmp[t - 1];
    int h = hist[t];
    gbase[t] = (h > 0) ? atomicAdd(&bcur[t], h) : 0;
    __syncthreads();
    // C: re-read edges (L2-warm), place sorted-by-bucket in LDS
    for (int i = t; i < cnt; i += 256) {
        int s = src[e0 + i], d = dst[e0 + i];
        int b = d >> BSZ_LOG;
        int code = ((d & (BSZ - 1)) << 20) | s;
        int sp = hexcl[b] + atomicAdd(&hpos[b], 1);
        sorted[sp] = code;
        bsorted[sp] = (unsigned char)b;
    }
    __syncthreads();
    // D: coalesced write-out in per-bucket runs
    for (int i = t; i < cnt; i += 256) {
        int b = bsorted[i];
        binned[gbase[b] + (i - hexcl[b])] = sorted[i];
    }
}

// Pass 2: one block per bucket; LDS node-hist + scan -> exact CSR positions.
__global__ __launch_bounds__(256)
void bucket_csr_kernel(const int* __restrict__ binned, const int* __restrict__ bstart,
                       const float* __restrict__ dis, int2* __restrict__ ew, int n) {
    __shared__ int lstart[BSZ];
    __shared__ int lpos[BSZ];
    __shared__ float ldis[BSZ];
    __shared__ int partial[256];
    int b = blockIdx.x, t = threadIdx.x;
    int nb0 = b << BSZ_LOG;
    int nn = min(BSZ, n - nb0);
    int e0 = bstart[b], m = bstart[b + 1] - e0;
    for (int i = t; i < BSZ; i += 256) {
        lstart[i] = 0; lpos[i] = 0;
        ldis[i] = (i < nn) ? dis[nb0 + i] : 0.f;
    }
    __syncthreads();
    // A: node histogram
    for (int i = t; i < m; i += 256)
        atomicAdd(&lstart[binned[e0 + i] >> 20], 1);
    __syncthreads();
    // scan 512 with 256 threads (2 per thread)
    int a0 = lstart[2 * t], a1 = lstart[2 * t + 1];
    partial[t] = a0 + a1;
    __syncthreads();
    for (int d = 1; d < 256; d <<= 1) {
        int v = (t >= d) ? partial[t - d] : 0;
        __syncthreads();
        partial[t] += v;
        __syncthreads();
    }
    int base = (t == 0) ? 0 : partial[t - 1];
    lstart[2 * t] = base;
    lstart[2 * t + 1] = base + a0;
    __syncthreads();
    // B: scatter to exact positions
    for (int i = t; i < m; i += 256) {
        int code = binned[e0 + i];
        int dl = code >> 20, s = code & 0xFFFFF;
        float w = dis[s] * ldis[dl];
        int p = e0 + lstart[dl] + atomicAdd(&lpos[dl], 1);
        ew[p] = make_int2(s, __float_as_int(w));
    }
}

// Layer 1: agg x (16-wide, 4 lanes/node) then GEMM 16->64 + b1 + relu.
__global__ __launch_bounds__(256)
void l1_kernel(const float* __restrict__ x, const float* __restrict__ dis,
               const int* __restrict__ off, const int2* __restrict__ ew,
               const float* __restrict__ W1, const float* __restrict__ b1,
               float* __restrict__ h1, int n) {
    __shared__ float accs[64][17];
    __shared__ float Wl[16 * 64];
    __shared__ float bl[64];
    int t = threadIdx.x;
    for (int i = t; i < 16 * 64; i += 256) Wl[i] = W1[i];
    if (t < 64) bl[t] = b1[t];

    int q = t & 3, ln = t >> 2;
    int node = blockIdx.x * 64 + ln;
    const float4* xp = (const float4*)x;
    float4 acc = make_float4(0.f, 0.f, 0.f, 0.f);
    if (node < n) {
        float di = dis[node], d2 = di * di;
        float4 v = xp[(size_t)node * 4 + q];
        acc.x = d2 * v.x; acc.y = d2 * v.y; acc.z = d2 * v.z; acc.w = d2 * v.w;
        int e0 = off[node], e1 = off[node + 1];
        int e = e0;
        for (; e + 1 < e1; e += 2) {
            int2 a0 = ew[e], a1 = ew[e + 1];
            float4 v0 = xp[(size_t)a0.x * 4 + q];
            float4 v1 = xp[(size_t)a1.x * 4 + q];
            float w0 = __int_as_float(a0.y), w1 = __int_as_float(a1.y);
            acc.x += w0 * v0.x; acc.y += w0 * v0.y; acc.z += w0 * v0.z; acc.w += w0 * v0.w;
            acc.x += w1 * v1.x; acc.y += w1 * v1.y; acc.z += w1 * v1.z; acc.w += w1 * v1.w;
        }
        if (e < e1) {
            int2 a0 = ew[e];
            float4 v0 = xp[(size_t)a0.x * 4 + q];
            float w0 = __int_as_float(a0.y);
            acc.x += w0 * v0.x; acc.y += w0 * v0.y; acc.z += w0 * v0.z; acc.w += w0 * v0.w;
        }
    }
    accs[ln][q * 4 + 0] = acc.x; accs[ln][q * 4 + 1] = acc.y;
    accs[ln][q * 4 + 2] = acc.z; accs[ln][q * 4 + 3] = acc.w;
    __syncthreads();

    int base = blockIdx.x * 64;
    int j = t & 63;
    for (int nb = (t >> 6); nb < 64; nb += 4) {
        int nd = base + nb;
        if (nd >= n) break;
        float s = bl[j];
#pragma unroll
        for (int k = 0; k < 16; ++k) s += accs[nb][k] * Wl[k * 64 + j];
        h1[(size_t)nd * 64 + j] = fmaxf(s, 0.f);
    }
}

// Dense transform: out[n,KO] = in[n,KI] @ W[KI,KO]  (no bias)
template <int KI, int KO>
__global__ __launch_bounds__(256)
void transform_kernel(const float* __restrict__ in, const float* __restrict__ W,
                      float* __restrict__ out, int n) {
    constexpr int NB = 256 / KO;
    __shared__ float Wl[KI * KO];
    __shared__ float tile[NB * KI];
    int t = threadIdx.x;
    for (int i = t; i < KI * KO; i += 256) Wl[i] = W[i];
    size_t base = (size_t)blockIdx.x * NB;
    for (int i = t; i < NB * KI; i += 256) {
        size_t nd = base + (size_t)(i / KI);
        tile[i] = (nd < (size_t)n) ? in[base * KI + i] : 0.f;
    }
    __syncthreads();
    int j = t % KO, nb = t / KO;
    size_t nd = base + nb;
    if (nd < (size_t)n) {
        float s = 0.f;
#pragma unroll
        for (int k = 0; k < KI; ++k) s += tile[nb * KI + k] * Wl[k * KO + j];
        out[nd * KO + j] = s;
    }
}

// Aggregate WD-wide features through CSR; WD/4 lanes per node, one float4 each.
template <int WD>
__global__ __launch_bounds__(256)
void agg_kernel(const float* __restrict__ h, const float* __restrict__ dis,
                const int* __restrict__ off, const int2* __restrict__ ew,
                const float* __restrict__ b, float* __restrict__ out, int n) {
    constexpr int TPN = WD / 4;
    constexpr int NPB = 256 / TPN;
    int t = threadIdx.x;
    int q = t % TPN, ln = t / TPN;
    int node = blockIdx.x * NPB + ln;
    if (node >= n) return;
    const float4* hp = (const float4*)h;
    float di = dis[node], d2 = di * di;
    float4 v = hp[(size_t)node * TPN + q];
    float4 acc;
    acc.x = d2 * v.x; acc.y = d2 * v.y; acc.z = d2 * v.z; acc.w = d2 * v.w;
    int e0 = off[node], e1 = off[node + 1];
    int e = e0;
    for (; e + 1 < e1; e += 2) {
        int2 a0 = ew[e], a1 = ew[e + 1];
        float4 v0 = hp[(size_t)a0.x * TPN + q];
        float4 v1 = hp[(size_t)a1.x * TPN + q];
        float w0 = __int_as_float(a0.y), w1 = __int_as_float(a1.y);
        acc.x += w0 * v0.x; acc.y += w0 * v0.y; acc.z += w0 * v0.z; acc.w += w0 * v0.w;
        acc.x += w1 * v1.x; acc.y += w1 * v1.y; acc.z += w1 * v1.z; acc.w += w1 * v1.w;
    }
    if (e < e1) {
        int2 a0 = ew[e];
        float4 v0 = hp[(size_t)a0.x * TPN + q];
        float w0 = __int_as_float(a0.y);
        acc.x += w0 * v0.x; acc.y += w0 * v0.y; acc.z += w0 * v0.z; acc.w += w0 * v0.w;
    }
    float4 bb = ((const float4*)b)[q];
    float4 o;
    o.x = acc.x + bb.x; o.y = acc.y + bb.y; o.z = acc.z + bb.z; o.w = acc.w + bb.w;
    ((float4*)out)[(size_t)node * TPN + q] = o;
}

// Mean-pool h2[n,32] per graph (equal sizes npg) -> Z[G,32]
__global__ __launch_bounds__(256)
void pool_kernel(const float* __restrict__ h2, const int* __restrict__ npg_p,
                 float* __restrict__ Z, int n) {
    int npg = npg_p[0];
    int G = n / npg;
    if (G > 4096) G = 4096;
    __shared__ float red[256];
    for (int g = blockIdx.x; g < G; g += gridDim.x) {
        int j = threadIdx.x & 31;
        int r0 = threadIdx.x >> 5;
        float acc = 0.f;
        for (int r = r0; r < npg; r += 8)
            acc += h2[((size_t)g * npg + r) * 32 + j];
        red[threadIdx.x] = acc;
        __syncthreads();
        if (threadIdx.x < 32) {
            float s = 0.f;
#pragma unroll
            for (int q = 0; q < 8; ++q) s += red[q * 32 + threadIdx.x];
            Z[g * 32 + threadIdx.x] = s / (float)npg;
        }
        __syncthreads();
    }
}

// ZW3[g][64] = Z[g][32] @ W3[32][64]  (tiny; b3 added later, once per node)
__global__ __launch_bounds__(256)
void zw3_kernel(const float* __restrict__ Z, const float* __restrict__ W3,
                const int* __restrict__ npg_p, float* __restrict__ ZW, int n) {
    __shared__ float Wl[32 * 64];
    int t = threadIdx.x;
    for (int i = t; i < 32 * 64; i += 256) Wl[i] = W3[i];
    __syncthreads();
    int npg = npg_p[0];
    int G = n / npg;
    int j = t & 63, gq = t >> 6;               // 4 graphs per block-iter
    for (int g = blockIdx.x * 4 + gq; g < G; g += gridDim.x * 4) {
        float s = 0.f;
#pragma unroll
        for (int k = 0; k < 32; ++k) s += Z[g * 32 + k] * Wl[k * 64 + j];
        ZW[g * 64 + j] = s;
    }
}

// Decoder layer 1 fused: d[i] = relu( sum_e w_e * ZW3[g(src_e)] + d2*ZW3[g(i)] + b3 )
// g(v) = v / npg arithmetically (batch is repeat(arange(G), npg) by construction).
// 16 lanes/node, one float4 of the 64-wide row per lane; ZW3 in LDS (padded).
constexpr int ZCAP  = 128;
constexpr int ZPAD4 = 17;   // float4 stride per graph (odd -> bank-spread)

__device__ __forceinline__ int gdiv(int v, int npg, float inv) {
    int g = __float2int_rz((float)v * inv);
    int r = v - g * npg;
    if (r < 0) --g; else if (r >= npg) ++g;
    return g;
}

__global__ __launch_bounds__(256)
void dec1_kernel(const float* __restrict__ ZW, const float* __restrict__ dis,
                 const int* __restrict__ off, const int2* __restrict__ ew,
                 const int* __restrict__ npg_p, const float* __restrict__ b3,
                 float* __restrict__ dOut, int n) {
    __shared__ float ZWl[ZCAP * ZPAD4 * 4];
    __shared__ float bl[64];
    int t = threadIdx.x;
    int npg = npg_p[0];
    int G = n / npg;
    bool ldsz = (G <= ZCAP);
    if (ldsz) {
        for (int i = t; i < G * 64; i += 256)
            ZWl[(i >> 6) * (ZPAD4 * 4) + (i & 63)] = ZW[i];
    }
    if (t < 64) bl[t] = b3[t];
    __syncthreads();

    float inv = 1.0f / (float)npg;
    int q = t & 15, ln = t >> 4;          // 16 lanes/node, 16 nodes/block
    int node = blockIdx.x * 16 + ln;
    if (node >= n) return;
    const float4* zt = ldsz ? (const float4*)ZWl : (const float4*)ZW;
    int zs = ldsz ? ZPAD4 : 16;

    float di = dis[node], d2 = di * di;
    int gi = gdiv(node, npg, inv);
    float4 v = zt[gi * zs + q];
    float4 acc;
    acc.x = d2 * v.x; acc.y = d2 * v.y; acc.z = d2 * v.z; acc.w = d2 * v.w;
    int e0 = off[node], e1 = off[node + 1];
    int e = e0;
    for (; e + 1 < e1; e += 2) {
        int2 a0 = ew[e], a1 = ew[e + 1];
        int g0 = gdiv(a0.x, npg, inv), g1 = gdiv(a1.x, npg, inv);
        float w0 = __int_as_float(a0.y), w1 = __int_as_float(a1.y);
        float4 v0 = zt[g0 * zs + q];
        float4 v1 = zt[g1 * zs + q];
        acc.x += w0 * v0.x; acc.y += w0 * v0.y; acc.z += w0 * v0.z; acc.w += w0 * v0.w;
        acc.x += w1 * v1.x; acc.y += w1 * v1.y; acc.z += w1 * v1.z; acc.w += w1 * v1.w;
    }
    if (e < e1) {
        int2 a0 = ew[e];
        int g0 = gdiv(a0.x, npg, inv);
        float w0 = __int_as_float(a0.y);
        float4 v0 = zt[g0 * zs + q];
        acc.x += w0 * v0.x; acc.y += w0 * v0.y; acc.z += w0 * v0.z; acc.w += w0 * v0.w;
    }
    float4 bb = ((const float4*)bl)[q];
    float4 o;
    o.x = fmaxf(acc.x + bb.x, 0.f); o.y = fmaxf(acc.y + bb.y, 0.f);
    o.z = fmaxf(acc.z + bb.z, 0.f); o.w = fmaxf(acc.w + bb.w, 0.f);
    ((float4*)dOut)[(size_t)node * 16 + q] = o;
}

extern "C" void kernel_launch(void* const* d_in, const int* in_sizes, int n_in,
                              void* d_out, int out_size, void* d_ws, size_t ws_size,
                              hipStream_t stream) {
    const float* x     = (const float*)d_in[0];
    const int*   ei    = (const int*)d_in[1];
    const int*   npg   = (const int*)d_in[3];
    const float* W1 = (const float*)d_in[4];
    const float* b1 = (const float*)d_in[5];
    const float* W2 = (const float*)d_in[6];
    const float* b2 = (const float*)d_in[7];
    const float* W3 = (const float*)d_in[8];
    const float* b3 = (const float*)d_in[9];
    const float* W4 = (const float*)d_in[10];
    const float* b4 = (const float*)d_in[11];
    float* out = (float*)d_out;

    int n = in_sizes[0] / 16;
    int E = in_sizes[1] / 2;
    const int* srcp = ei;
    const int* dstp = ei + E;

    char* w = (char*)d_ws;
    auto alloc = [&](size_t bytes) {
        char* p = w;
        w += (bytes + 255) & ~(size_t)255;
        return p;
    };
    int*   cnt    = (int*)alloc((size_t)n * 4);
    float* dis    = (float*)alloc((size_t)n * 4);
    int*   off    = (int*)alloc(((size_t)n + 1) * 4);
    int*   binned = (int*)alloc((size_t)E * 4);
    int2*  ew     = (int2*)alloc((size_t)E * 8);
    float* A      = (float*)alloc((size_t)n * 64 * 4);  // h1, later d
    float* B      = (float*)alloc((size_t)n * 32 * 4);  // t2, later t4
    float* C      = (float*)alloc((size_t)n * 32 * 4);  // h2
    float* Z      = (float*)alloc((size_t)4096 * 32 * 4);
    float* ZWb    = (float*)alloc((size_t)4096 * 64 * 4);
    int*   bsum   = (int*)alloc((size_t)4096 * 4);
    int*   bstart = (int*)alloc((size_t)(NBMAX + 1) * 4);
    int*   bcur   = (int*)alloc((size_t)NBMAX * 4);

    int nb256 = (n + 255) / 256;
    int eb256 = (E + 255) / 256;
    int nscan = (n + SCAN_CHUNK - 1) / SCAN_CHUNK;
    int nbuck = (n + BSZ - 1) / BSZ;
    int nbin  = (E + ECHUNK - 1) / ECHUNK;

    hipMemsetAsync(cnt, 0, (size_t)n * 4, stream);
    count_kernel<<<eb256, 256, 0, stream>>>(dstp, cnt, E);
    dis_kernel<<<nb256, 256, 0, stream>>>(cnt, dis, n);
    bsum_kernel<<<nscan, 256, 0, stream>>>(cnt, bsum, n);
    bscan_kernel<<<1, 256, 0, stream>>>(bsum, nscan);
    bfill_kernel<<<nscan, 256, 0, stream>>>(cnt, bsum, off, n);
    bucket_init_kernel<<<1, 256, 0, stream>>>(off, bstart, bcur, n, nbuck);
    binfill_kernel<<<nbin, 256, 0, stream>>>(srcp, dstp, bcur, binned, E);
    bucket_csr_kernel<<<nbuck, 256, 0, stream>>>(binned, bstart, dis, ew, n);

    // encode
    l1_kernel<<<(n + 63) / 64, 256, 0, stream>>>(x, dis, off, ew, W1, b1, A, n);
    transform_kernel<64, 32><<<(n + 7) / 8, 256, 0, stream>>>(A, W2, B, n);
    agg_kernel<32><<<(n + 31) / 32, 256, 0, stream>>>(B, dis, off, ew, b2, C, n);
    pool_kernel<<<256, 256, 0, stream>>>(C, npg, Z, n);

    // decode
    zw3_kernel<<<32, 256, 0, stream>>>(Z, W3, npg, ZWb, n);
    dec1_kernel<<<(n + 15) / 16, 256, 0, stream>>>(ZWb, dis, off, ew, npg, b3, A, n);
    transform_kernel<64, 16><<<(n + 15) / 16, 256, 0, stream>>>(A, W4, B, n);
    agg_kernel<16><<<(n + 63) / 64, 256, 0, stream>>>(B, dis, off, ew, b4, out, n);
}

// Round 6
// 304.814 us; speedup vs baseline: 2.3028x; 1.2193x over previous
//
#include <hip/hip_runtime.h>
#include <hip/hip_bf16.h>

// ---------------------------------------------------------------------------
// GraphAutoEncoder: 4x GCNConv + mean-pool + repeat, all f32.
// Strategy:
//   - CSR build WITHOUT a count pass: LDS-binned bucket staging (fixed CAP),
//     per-bucket LDS histogram+scan gives node offsets AND degrees (dis).
//   - CSR payload interleaved as int2{col, wgt}.
//   - Self-loop handled analytically: out[i] += dis[i]^2 * h[i].
//   - Aggregate on the narrow side of each layer (16 / 32 / ZW3-LDS / 16 wide).
//   - Vector-per-node gathers: lanes per node, one float4 gather per lane.
// R1: 3-level hierarchical scan (was 231 us single-block).
// R2: int2 CSR payload, vector-per-node gathers.
// R3: binned CSR fill (write-combining; was 101 MB of dirtied lines).
// R4: dec1 fused with ZW3=Z@W3 table; g(src)=src/npg arithmetically.
// R5: count_kernel (65 us, 50 MB atomic writebacks) ELIMINATED — degrees come
//     from the bucket histograms; staging uses fixed-capacity bucket regions.
// ---------------------------------------------------------------------------

constexpr int BSZ_LOG = 9;                 // bucket = 512 dst nodes
constexpr int BSZ     = 1 << BSZ_LOG;
constexpr int NBMAX   = 256;               // max buckets (n <= 128K)
constexpr int ECHUNK  = 8192;              // edges per binfill block
constexpr int BCAP    = 12288;             // staging capacity per bucket

// Pass 1: LDS-binned bucket staging. code = (dst_local << 20) | src (src < 2^20).
// Reserves space with ONE atomic per (block,bucket) pair; bcnt starts at 0.
__global__ __launch_bounds__(256)
void binfill_kernel(const int* __restrict__ src, const int* __restrict__ dst,
                    int* __restrict__ bcnt, int* __restrict__ binned, int E) {
    __shared__ int hist[NBMAX], hexcl[NBMAX], gbase[NBMAX], hpos[NBMAX], tmp[NBMAX];
    __shared__ int sorted[ECHUNK];
    __shared__ unsigned char bsorted[ECHUNK];
    int t = threadIdx.x;
    hist[t] = 0; hpos[t] = 0;
    __syncthreads();
    int e0 = blockIdx.x * ECHUNK;
    int cnt = min(ECHUNK, E - e0);
    // A: histogram buckets
    for (int i = t; i < cnt; i += 256)
        atomicAdd(&hist[dst[e0 + i] >> BSZ_LOG], 1);
    __syncthreads();
    // B: exclusive scan + per-bucket space reservation
    tmp[t] = hist[t];
    __syncthreads();
    for (int d = 1; d < 256; d <<= 1) {
        int v = (t >= d) ? tmp[t - d] : 0;
        __syncthreads();
        tmp[t] += v;
        __syncthreads();
    }
    hexcl[t] = (t == 0) ? 0 : tmp[t - 1];
    int h = hist[t];
    gbase[t] = (h > 0) ? atomicAdd(&bcnt[t], h) : 0;
    __syncthreads();
    // C: re-read edges (L2-warm), place sorted-by-bucket in LDS
    for (int i = t; i < cnt; i += 256) {
        int s = src[e0 + i], d = dst[e0 + i];
        int b = d >> BSZ_LOG;
        int code = ((d & (BSZ - 1)) << 20) | s;
        int sp = hexcl[b] + atomicAdd(&hpos[b], 1);
        sorted[sp] = code;
        bsorted[sp] = (unsigned char)b;
    }
    __syncthreads();
    // D: coalesced write-out in per-bucket runs into the bucket's CAP region
    for (int i = t; i < cnt; i += 256) {
        int b = bsorted[i];
        binned[(size_t)b * BCAP + gbase[b] + (i - hexcl[b])] = sorted[i];
    }
}

// Exclusive scan of per-bucket totals -> bstart[0..nbuck]; off[n] = E.
__global__ __launch_bounds__(256)
void bstart_scan_kernel(const int* __restrict__ bcnt, int* __restrict__ bstart,
                        int* __restrict__ off, int n, int nbuck, int E) {
    __shared__ int sums[256];
    int t = threadIdx.x;
    int v = (t < nbuck) ? bcnt[t] : 0;
    sums[t] = v;
    __syncthreads();
    for (int d = 1; d < 256; d <<= 1) {
        int s = (t >= d) ? sums[t - d] : 0;
        __syncthreads();
        sums[t] += s;
        __syncthreads();
    }
    if (t <= nbuck) bstart[t] = (t == 0) ? 0 : sums[t - 1];
    if (t == 0) off[n] = E;
}

// Per bucket: LDS node histogram + scan -> coalesced off[] and dis[] writes.
__global__ __launch_bounds__(256)
void csr_off_kernel(const int* __restrict__ binned, const int* __restrict__ bcnt,
                    const int* __restrict__ bstart, int* __restrict__ off,
                    float* __restrict__ dis, int n) {
    __shared__ int hist[BSZ];
    __shared__ int lstart[BSZ];
    __shared__ int partial[256];
    int b = blockIdx.x, t = threadIdx.x;
    int nb0 = b << BSZ_LOG;
    int nn = min(BSZ, n - nb0);
    int m = bcnt[b];
    const int* bp = binned + (size_t)b * BCAP;
    for (int i = t; i < BSZ; i += 256) hist[i] = 0;
    __syncthreads();
    for (int i = t; i < m; i += 256)
        atomicAdd(&hist[bp[i] >> 20], 1);
    __syncthreads();
    int a0 = hist[2 * t], a1 = hist[2 * t + 1];
    partial[t] = a0 + a1;
    __syncthreads();
    for (int d = 1; d < 256; d <<= 1) {
        int v = (t >= d) ? partial[t - d] : 0;
        __syncthreads();
        partial[t] += v;
        __syncthreads();
    }
    int base = (t == 0) ? 0 : partial[t - 1];
    lstart[2 * t] = base;
    lstart[2 * t + 1] = base + a0;
    __syncthreads();
    int bs = bstart[b];
    for (int i = t; i < nn; i += 256) {
        off[nb0 + i] = bs + lstart[i];
        dis[nb0 + i] = rsqrtf((float)hist[i] + 1.0f);   // +1 = self-loop
    }
}

// Per bucket: scatter {src, w} to exact CSR positions (L2-local window).
__global__ __launch_bounds__(256)
void bucket_scatter_kernel(const int* __restrict__ binned, const int* __restrict__ bcnt,
                           const int* __restrict__ bstart, const float* __restrict__ dis,
                           int2* __restrict__ ew, int n) {
    __shared__ int lstart[BSZ];
    __shared__ int lpos[BSZ];
    __shared__ float ldis[BSZ];
    __shared__ int partial[256];
    int b = blockIdx.x, t = threadIdx.x;
    int nb0 = b << BSZ_LOG;
    int nn = min(BSZ, n - nb0);
    int m = bcnt[b];
    const int* bp = binned + (size_t)b * BCAP;
    for (int i = t; i < BSZ; i += 256) {
        lstart[i] = 0; lpos[i] = 0;
        ldis[i] = (i < nn) ? dis[nb0 + i] : 0.f;
    }
    __syncthreads();
    for (int i = t; i < m; i += 256)
        atomicAdd(&lstart[bp[i] >> 20], 1);
    __syncthreads();
    int a0 = lstart[2 * t], a1 = lstart[2 * t + 1];
    partial[t] = a0 + a1;
    __syncthreads();
    for (int d = 1; d < 256; d <<= 1) {
        int v = (t >= d) ? partial[t - d] : 0;
        __syncthreads();
        partial[t] += v;
        __syncthreads();
    }
    int base = (t == 0) ? 0 : partial[t - 1];
    lstart[2 * t] = base;
    lstart[2 * t + 1] = base + a0;
    __syncthreads();
    int e0 = bstart[b];
    for (int i = t; i < m; i += 256) {
        int code = bp[i];
        int dl = code >> 20, s = code & 0xFFFFF;
        float w = dis[s] * ldis[dl];
        int p = e0 + lstart[dl] + atomicAdd(&lpos[dl], 1);
        ew[p] = make_int2(s, __float_as_int(w));
    }
}

// Layer 1: agg x (16-wide, 4 lanes/node) then GEMM 16->64 + b1 + relu.
__global__ __launch_bounds__(256)
void l1_kernel(const float* __restrict__ x, const float* __restrict__ dis,
               const int* __restrict__ off, const int2* __restrict__ ew,
               const float* __restrict__ W1, const float* __restrict__ b1,
               float* __restrict__ h1, int n) {
    __shared__ float accs[64][17];
    __shared__ float Wl[16 * 64];
    __shared__ float bl[64];
    int t = threadIdx.x;
    for (int i = t; i < 16 * 64; i += 256) Wl[i] = W1[i];
    if (t < 64) bl[t] = b1[t];

    int q = t & 3, ln = t >> 2;
    int node = blockIdx.x * 64 + ln;
    const float4* xp = (const float4*)x;
    float4 acc = make_float4(0.f, 0.f, 0.f, 0.f);
    if (node < n) {
        float di = dis[node], d2 = di * di;
        float4 v = xp[(size_t)node * 4 + q];
        acc.x = d2 * v.x; acc.y = d2 * v.y; acc.z = d2 * v.z; acc.w = d2 * v.w;
        int e0 = off[node], e1 = off[node + 1];
        int e = e0;
        for (; e + 1 < e1; e += 2) {
            int2 a0 = ew[e], a1 = ew[e + 1];
            float4 v0 = xp[(size_t)a0.x * 4 + q];
            float4 v1 = xp[(size_t)a1.x * 4 + q];
            float w0 = __int_as_float(a0.y), w1 = __int_as_float(a1.y);
            acc.x += w0 * v0.x; acc.y += w0 * v0.y; acc.z += w0 * v0.z; acc.w += w0 * v0.w;
            acc.x += w1 * v1.x; acc.y += w1 * v1.y; acc.z += w1 * v1.z; acc.w += w1 * v1.w;
        }
        if (e < e1) {
            int2 a0 = ew[e];
            float4 v0 = xp[(size_t)a0.x * 4 + q];
            float w0 = __int_as_float(a0.y);
            acc.x += w0 * v0.x; acc.y += w0 * v0.y; acc.z += w0 * v0.z; acc.w += w0 * v0.w;
        }
    }
    accs[ln][q * 4 + 0] = acc.x; accs[ln][q * 4 + 1] = acc.y;
    accs[ln][q * 4 + 2] = acc.z; accs[ln][q * 4 + 3] = acc.w;
    __syncthreads();

    int base = blockIdx.x * 64;
    int j = t & 63;
    for (int nb = (t >> 6); nb < 64; nb += 4) {
        int nd = base + nb;
        if (nd >= n) break;
        float s = bl[j];
#pragma unroll
        for (int k = 0; k < 16; ++k) s += accs[nb][k] * Wl[k * 64 + j];
        h1[(size_t)nd * 64 + j] = fmaxf(s, 0.f);
    }
}

// Dense transform: out[n,KO] = in[n,KI] @ W[KI,KO]  (no bias)
template <int KI, int KO>
__global__ __launch_bounds__(256)
void transform_kernel(const float* __restrict__ in, const float* __restrict__ W,
                      float* __restrict__ out, int n) {
    constexpr int NB = 256 / KO;
    __shared__ float Wl[KI * KO];
    __shared__ float tile[NB * KI];
    int t = threadIdx.x;
    for (int i = t; i < KI * KO; i += 256) Wl[i] = W[i];
    size_t base = (size_t)blockIdx.x * NB;
    for (int i = t; i < NB * KI; i += 256) {
        size_t nd = base + (size_t)(i / KI);
        tile[i] = (nd < (size_t)n) ? in[base * KI + i] : 0.f;
    }
    __syncthreads();
    int j = t % KO, nb = t / KO;
    size_t nd = base + nb;
    if (nd < (size_t)n) {
        float s = 0.f;
#pragma unroll
        for (int k = 0; k < KI; ++k) s += tile[nb * KI + k] * Wl[k * KO + j];
        out[nd * KO + j] = s;
    }
}

// Aggregate WD-wide features through CSR; WD/4 lanes per node, one float4 each.
template <int WD>
__global__ __launch_bounds__(256)
void agg_kernel(const float* __restrict__ h, const float* __restrict__ dis,
                const int* __restrict__ off, const int2* __restrict__ ew,
                const float* __restrict__ b, float* __restrict__ out, int n) {
    constexpr int TPN = WD / 4;
    constexpr int NPB = 256 / TPN;
    int t = threadIdx.x;
    int q = t % TPN, ln = t / TPN;
    int node = blockIdx.x * NPB + ln;
    if (node >= n) return;
    const float4* hp = (const float4*)h;
    float di = dis[node], d2 = di * di;
    float4 v = hp[(size_t)node * TPN + q];
    float4 acc;
    acc.x = d2 * v.x; acc.y = d2 * v.y; acc.z = d2 * v.z; acc.w = d2 * v.w;
    int e0 = off[node], e1 = off[node + 1];
    int e = e0;
    for (; e + 1 < e1; e += 2) {
        int2 a0 = ew[e], a1 = ew[e + 1];
        float4 v0 = hp[(size_t)a0.x * TPN + q];
        float4 v1 = hp[(size_t)a1.x * TPN + q];
        float w0 = __int_as_float(a0.y), w1 = __int_as_float(a1.y);
        acc.x += w0 * v0.x; acc.y += w0 * v0.y; acc.z += w0 * v0.z; acc.w += w0 * v0.w;
        acc.x += w1 * v1.x; acc.y += w1 * v1.y; acc.z += w1 * v1.z; acc.w += w1 * v1.w;
    }
    if (e < e1) {
        int2 a0 = ew[e];
        float4 v0 = hp[(size_t)a0.x * TPN + q];
        float w0 = __int_as_float(a0.y);
        acc.x += w0 * v0.x; acc.y += w0 * v0.y; acc.z += w0 * v0.z; acc.w += w0 * v0.w;
    }
    float4 bb = ((const float4*)b)[q];
    float4 o;
    o.x = acc.x + bb.x; o.y = acc.y + bb.y; o.z = acc.z + bb.z; o.w = acc.w + bb.w;
    ((float4*)out)[(size_t)node * TPN + q] = o;
}

// Mean-pool h2[n,32] per graph (equal sizes npg) -> Z[G,32]
__global__ __launch_bounds__(256)
void pool_kernel(const float* __restrict__ h2, const int* __restrict__ npg_p,
                 float* __restrict__ Z, int n) {
    int npg = npg_p[0];
    int G = n / npg;
    if (G > 4096) G = 4096;
    __shared__ float red[256];
    for (int g = blockIdx.x; g < G; g += gridDim.x) {
        int j = threadIdx.x & 31;
        int r0 = threadIdx.x >> 5;
        float acc = 0.f;
        for (int r = r0; r < npg; r += 8)
            acc += h2[((size_t)g * npg + r) * 32 + j];
        red[threadIdx.x] = acc;
        __syncthreads();
        if (threadIdx.x < 32) {
            float s = 0.f;
#pragma unroll
            for (int q = 0; q < 8; ++q) s += red[q * 32 + threadIdx.x];
            Z[g * 32 + threadIdx.x] = s / (float)npg;
        }
        __syncthreads();
    }
}

// ZW3[g][64] = Z[g][32] @ W3[32][64]  (tiny; b3 added later, once per node)
__global__ __launch_bounds__(256)
void zw3_kernel(const float* __restrict__ Z, const float* __restrict__ W3,
                const int* __restrict__ npg_p, float* __restrict__ ZW, int n) {
    __shared__ float Wl[32 * 64];
    int t = threadIdx.x;
    for (int i = t; i < 32 * 64; i += 256) Wl[i] = W3[i];
    __syncthreads();
    int npg = npg_p[0];
    int G = n / npg;
    int j = t & 63, gq = t >> 6;               // 4 graphs per block-iter
    for (int g = blockIdx.x * 4 + gq; g < G; g += gridDim.x * 4) {
        float s = 0.f;
#pragma unroll
        for (int k = 0; k < 32; ++k) s += Z[g * 32 + k] * Wl[k * 64 + j];
        ZW[g * 64 + j] = s;
    }
}

// Decoder layer 1 fused: d[i] = relu( sum_e w_e * ZW3[g(src_e)] + d2*ZW3[g(i)] + b3 )
constexpr int ZCAP  = 128;
constexpr int ZPAD4 = 17;   // float4 stride per graph (odd -> bank-spread)

__device__ __forceinline__ int gdiv(int v, int npg, float inv) {
    int g = __float2int_rz((float)v * inv);
    int r = v - g * npg;
    if (r < 0) --g; else if (r >= npg) ++g;
    return g;
}

__global__ __launch_bounds__(256)
void dec1_kernel(const float* __restrict__ ZW, const float* __restrict__ dis,
                 const int* __restrict__ off, const int2* __restrict__ ew,
                 const int* __restrict__ npg_p, const float* __restrict__ b3,
                 float* __restrict__ dOut, int n) {
    __shared__ float ZWl[ZCAP * ZPAD4 * 4];
    __shared__ float bl[64];
    int t = threadIdx.x;
    int npg = npg_p[0];
    int G = n / npg;
    bool ldsz = (G <= ZCAP);
    if (ldsz) {
        for (int i = t; i < G * 64; i += 256)
            ZWl[(i >> 6) * (ZPAD4 * 4) + (i & 63)] = ZW[i];
    }
    if (t < 64) bl[t] = b3[t];
    __syncthreads();

    float inv = 1.0f / (float)npg;
    int q = t & 15, ln = t >> 4;          // 16 lanes/node, 16 nodes/block
    int node = blockIdx.x * 16 + ln;
    if (node >= n) return;
    const float4* zt = ldsz ? (const float4*)ZWl : (const float4*)ZW;
    int zs = ldsz ? ZPAD4 : 16;

    float di = dis[node], d2 = di * di;
    int gi = gdiv(node, npg, inv);
    float4 v = zt[gi * zs + q];
    float4 acc;
    acc.x = d2 * v.x; acc.y = d2 * v.y; acc.z = d2 * v.z; acc.w = d2 * v.w;
    int e0 = off[node], e1 = off[node + 1];
    int e = e0;
    for (; e + 1 < e1; e += 2) {
        int2 a0 = ew[e], a1 = ew[e + 1];
        int g0 = gdiv(a0.x, npg, inv), g1 = gdiv(a1.x, npg, inv);
        float w0 = __int_as_float(a0.y), w1 = __int_as_float(a1.y);
        float4 v0 = zt[g0 * zs + q];
        float4 v1 = zt[g1 * zs + q];
        acc.x += w0 * v0.x; acc.y += w0 * v0.y; acc.z += w0 * v0.z; acc.w += w0 * v0.w;
        acc.x += w1 * v1.x; acc.y += w1 * v1.y; acc.z += w1 * v1.z; acc.w += w1 * v1.w;
    }
    if (e < e1) {
        int2 a0 = ew[e];
        int g0 = gdiv(a0.x, npg, inv);
        float w0 = __int_as_float(a0.y);
        float4 v0 = zt[g0 * zs + q];
        acc.x += w0 * v0.x; acc.y += w0 * v0.y; acc.z += w0 * v0.z; acc.w += w0 * v0.w;
    }
    float4 bb = ((const float4*)bl)[q];
    float4 o;
    o.x = fmaxf(acc.x + bb.x, 0.f); o.y = fmaxf(acc.y + bb.y, 0.f);
    o.z = fmaxf(acc.z + bb.z, 0.f); o.w = fmaxf(acc.w + bb.w, 0.f);
    ((float4*)dOut)[(size_t)node * 16 + q] = o;
}

extern "C" void kernel_launch(void* const* d_in, const int* in_sizes, int n_in,
                              void* d_out, int out_size, void* d_ws, size_t ws_size,
                              hipStream_t stream) {
    const float* x     = (const float*)d_in[0];
    const int*   ei    = (const int*)d_in[1];
    const int*   npg   = (const int*)d_in[3];
    const float* W1 = (const float*)d_in[4];
    const float* b1 = (const float*)d_in[5];
    const float* W2 = (const float*)d_in[6];
    const float* b2 = (const float*)d_in[7];
    const float* W3 = (const float*)d_in[8];
    const float* b3 = (const float*)d_in[9];
    const float* W4 = (const float*)d_in[10];
    const float* b4 = (const float*)d_in[11];
    float* out = (float*)d_out;

    int n = in_sizes[0] / 16;
    int E = in_sizes[1] / 2;
    const int* srcp = ei;
    const int* dstp = ei + E;

    char* w = (char*)d_ws;
    auto alloc = [&](size_t bytes) {
        char* p = w;
        w += (bytes + 255) & ~(size_t)255;
        return p;
    };
    float* dis    = (float*)alloc((size_t)n * 4);
    int*   off    = (int*)alloc(((size_t)n + 1) * 4);
    int*   binned = (int*)alloc((size_t)NBMAX * BCAP * 4);
    int2*  ew     = (int2*)alloc((size_t)E * 8);
    float* A      = (float*)alloc((size_t)n * 64 * 4);  // h1, later d
    float* B      = (float*)alloc((size_t)n * 32 * 4);  // t2, later t4
    float* C      = (float*)alloc((size_t)n * 32 * 4);  // h2
    float* Z      = (float*)alloc((size_t)4096 * 32 * 4);
    float* ZWb    = (float*)alloc((size_t)4096 * 64 * 4);
    int*   bcnt   = (int*)alloc((size_t)NBMAX * 4);
    int*   bstart = (int*)alloc((size_t)(NBMAX + 1) * 4);

    int nbuck = (n + BSZ - 1) / BSZ;
    int nbin  = (E + ECHUNK - 1) / ECHUNK;

    // ---- CSR build (no count pass) ----
    hipMemsetAsync(bcnt, 0, (size_t)NBMAX * 4, stream);
    binfill_kernel<<<nbin, 256, 0, stream>>>(srcp, dstp, bcnt, binned, E);
    bstart_scan_kernel<<<1, 256, 0, stream>>>(bcnt, bstart, off, n, nbuck, E);
    csr_off_kernel<<<nbuck, 256, 0, stream>>>(binned, bcnt, bstart, off, dis, n);
    bucket_scatter_kernel<<<nbuck, 256, 0, stream>>>(binned, bcnt, bstart, dis, ew, n);

    // encode
    l1_kernel<<<(n + 63) / 64, 256, 0, stream>>>(x, dis, off, ew, W1, b1, A, n);
    transform_kernel<64, 32><<<(n + 7) / 8, 256, 0, stream>>>(A, W2, B, n);
    agg_kernel<32><<<(n + 31) / 32, 256, 0, stream>>>(B, dis, off, ew, b2, C, n);
    pool_kernel<<<256, 256, 0, stream>>>(C, npg, Z, n);

    // decode
    zw3_kernel<<<32, 256, 0, stream>>>(Z, W3, npg, ZWb, n);
    dec1_kernel<<<(n + 15) / 16, 256, 0, stream>>>(ZWb, dis, off, ew, npg, b3, A, n);
    transform_kernel<64, 16><<<(n + 15) / 16, 256, 0, stream>>>(A, W4, B, n);
    agg_kernel<16><<<(n + 63) / 64, 256, 0, stream>>>(B, dis, off, ew, b4, out, n);
}

// Round 7
// 288.629 us; speedup vs baseline: 2.4319x; 1.0561x over previous
//
#include <hip/hip_runtime.h>
#include <hip/hip_bf16.h>

// ---------------------------------------------------------------------------
// GraphAutoEncoder: 4x GCNConv + mean-pool + repeat, all f32.
// Strategy:
//   - CSR build WITHOUT a count pass: LDS-binned bucket staging (fixed CAP),
//     per-bucket LDS histogram+scan gives node offsets AND degrees (dis).
//   - CSR payload int2{ src | g<<20, wgt }: g(src)=src/npg precomputed once.
//   - Self-loop handled analytically: out[i] += dis[i]^2 * h[i].
//   - Aggregate on the narrow side of each layer (16 / 32 / ZW3-LDS / 16 wide).
// R1: 3-level hierarchical scan. R2: int2 payload, vector-per-node gathers.
// R3: binned CSR fill (write-combining). R4: dec1 fused with ZW3=Z@W3 table.
// R5: count pass eliminated (degrees from bucket histograms).
// R6: g(src) packed in ew.x bits[20:30] (kills per-edge gdiv = half of dec1's
//     VALU); transform<64,16> fused into dec1 (hl row -> @W4 phase in LDS).
// ---------------------------------------------------------------------------

constexpr int BSZ_LOG = 9;                 // bucket = 512 dst nodes
constexpr int BSZ     = 1 << BSZ_LOG;
constexpr int NBMAX   = 256;               // max buckets (n <= 128K)
constexpr int ECHUNK  = 8192;              // edges per binfill block
constexpr int BCAP    = 12288;             // staging capacity per bucket

__device__ __forceinline__ int gdiv(int v, int npg, float inv) {
    int g = __float2int_rz((float)v * inv);
    int r = v - g * npg;
    if (r < 0) --g; else if (r >= npg) ++g;
    return g;
}

// Pass 1: LDS-binned bucket staging. code = (dst_local << 20) | src (src < 2^20).
__global__ __launch_bounds__(256)
void binfill_kernel(const int* __restrict__ src, const int* __restrict__ dst,
                    int* __restrict__ bcnt, int* __restrict__ binned, int E) {
    __shared__ int hist[NBMAX], hexcl[NBMAX], gbase[NBMAX], hpos[NBMAX], tmp[NBMAX];
    __shared__ int sorted[ECHUNK];
    __shared__ unsigned char bsorted[ECHUNK];
    int t = threadIdx.x;
    hist[t] = 0; hpos[t] = 0;
    __syncthreads();
    int e0 = blockIdx.x * ECHUNK;
    int cnt = min(ECHUNK, E - e0);
    for (int i = t; i < cnt; i += 256)
        atomicAdd(&hist[dst[e0 + i] >> BSZ_LOG], 1);
    __syncthreads();
    tmp[t] = hist[t];
    __syncthreads();
    for (int d = 1; d < 256; d <<= 1) {
        int v = (t >= d) ? tmp[t - d] : 0;
        __syncthreads();
        tmp[t] += v;
        __syncthreads();
    }
    hexcl[t] = (t == 0) ? 0 : tmp[t - 1];
    int h = hist[t];
    gbase[t] = (h > 0) ? atomicAdd(&bcnt[t], h) : 0;
    __syncthreads();
    for (int i = t; i < cnt; i += 256) {
        int s = src[e0 + i], d = dst[e0 + i];
        int b = d >> BSZ_LOG;
        int code = ((d & (BSZ - 1)) << 20) | s;
        int sp = hexcl[b] + atomicAdd(&hpos[b], 1);
        sorted[sp] = code;
        bsorted[sp] = (unsigned char)b;
    }
    __syncthreads();
    for (int i = t; i < cnt; i += 256) {
        int b = bsorted[i];
        binned[(size_t)b * BCAP + gbase[b] + (i - hexcl[b])] = sorted[i];
    }
}

// Exclusive scan of per-bucket totals -> bstart[0..nbuck]; off[n] = E.
__global__ __launch_bounds__(256)
void bstart_scan_kernel(const int* __restrict__ bcnt, int* __restrict__ bstart,
                        int* __restrict__ off, int n, int nbuck, int E) {
    __shared__ int sums[256];
    int t = threadIdx.x;
    int v = (t < nbuck) ? bcnt[t] : 0;
    sums[t] = v;
    __syncthreads();
    for (int d = 1; d < 256; d <<= 1) {
        int s = (t >= d) ? sums[t - d] : 0;
        __syncthreads();
        sums[t] += s;
        __syncthreads();
    }
    if (t <= nbuck) bstart[t] = (t == 0) ? 0 : sums[t - 1];
    if (t == 0) off[n] = E;
}

// Per bucket: LDS node histogram + scan -> coalesced off[] and dis[] writes.
__global__ __launch_bounds__(256)
void csr_off_kernel(const int* __restrict__ binned, const int* __restrict__ bcnt,
                    const int* __restrict__ bstart, int* __restrict__ off,
                    float* __restrict__ dis, int n) {
    __shared__ int hist[BSZ];
    __shared__ int lstart[BSZ];
    __shared__ int partial[256];
    int b = blockIdx.x, t = threadIdx.x;
    int nb0 = b << BSZ_LOG;
    int nn = min(BSZ, n - nb0);
    int m = bcnt[b];
    const int* bp = binned + (size_t)b * BCAP;
    for (int i = t; i < BSZ; i += 256) hist[i] = 0;
    __syncthreads();
    for (int i = t; i < m; i += 256)
        atomicAdd(&hist[bp[i] >> 20], 1);
    __syncthreads();
    int a0 = hist[2 * t], a1 = hist[2 * t + 1];
    partial[t] = a0 + a1;
    __syncthreads();
    for (int d = 1; d < 256; d <<= 1) {
        int v = (t >= d) ? partial[t - d] : 0;
        __syncthreads();
        partial[t] += v;
        __syncthreads();
    }
    int base = (t == 0) ? 0 : partial[t - 1];
    lstart[2 * t] = base;
    lstart[2 * t + 1] = base + a0;
    __syncthreads();
    int bs = bstart[b];
    for (int i = t; i < nn; i += 256) {
        off[nb0 + i] = bs + lstart[i];
        dis[nb0 + i] = rsqrtf((float)hist[i] + 1.0f);   // +1 = self-loop
    }
}

// Per bucket: scatter {src | g<<20, w} to exact CSR positions (L2-local window).
__global__ __launch_bounds__(256)
void bucket_scatter_kernel(const int* __restrict__ binned, const int* __restrict__ bcnt,
                           const int* __restrict__ bstart, const float* __restrict__ dis,
                           const int* __restrict__ npg_p, int2* __restrict__ ew, int n) {
    __shared__ int lstart[BSZ];
    __shared__ int lpos[BSZ];
    __shared__ float ldis[BSZ];
    __shared__ int partial[256];
    int b = blockIdx.x, t = threadIdx.x;
    int nb0 = b << BSZ_LOG;
    int nn = min(BSZ, n - nb0);
    int m = bcnt[b];
    int npg = npg_p[0];
    float inv = 1.0f / (float)npg;
    const int* bp = binned + (size_t)b * BCAP;
    for (int i = t; i < BSZ; i += 256) {
        lstart[i] = 0; lpos[i] = 0;
        ldis[i] = (i < nn) ? dis[nb0 + i] : 0.f;
    }
    __syncthreads();
    for (int i = t; i < m; i += 256)
        atomicAdd(&lstart[bp[i] >> 20], 1);
    __syncthreads();
    int a0 = lstart[2 * t], a1 = lstart[2 * t + 1];
    partial[t] = a0 + a1;
    __syncthreads();
    for (int d = 1; d < 256; d <<= 1) {
        int v = (t >= d) ? partial[t - d] : 0;
        __syncthreads();
        partial[t] += v;
        __syncthreads();
    }
    int base = (t == 0) ? 0 : partial[t - 1];
    lstart[2 * t] = base;
    lstart[2 * t + 1] = base + a0;
    __syncthreads();
    int e0 = bstart[b];
    for (int i = t; i < m; i += 256) {
        int code = bp[i];
        int dl = code >> 20, s = code & 0xFFFFF;
        float w = dis[s] * ldis[dl];
        int g = gdiv(s, npg, inv);
        int p = e0 + lstart[dl] + atomicAdd(&lpos[dl], 1);
        ew[p] = make_int2(s | (g << 20), __float_as_int(w));
    }
}

// Layer 1: agg x (16-wide, 4 lanes/node) then GEMM 16->64 + b1 + relu.
__global__ __launch_bounds__(256)
void l1_kernel(const float* __restrict__ x, const float* __restrict__ dis,
               const int* __restrict__ off, const int2* __restrict__ ew,
               const float* __restrict__ W1, const float* __restrict__ b1,
               float* __restrict__ h1, int n) {
    __shared__ float accs[64][17];
    __shared__ float Wl[16 * 64];
    __shared__ float bl[64];
    int t = threadIdx.x;
    for (int i = t; i < 16 * 64; i += 256) Wl[i] = W1[i];
    if (t < 64) bl[t] = b1[t];

    int q = t & 3, ln = t >> 2;
    int node = blockIdx.x * 64 + ln;
    const float4* xp = (const float4*)x;
    float4 acc = make_float4(0.f, 0.f, 0.f, 0.f);
    if (node < n) {
        float di = dis[node], d2 = di * di;
        float4 v = xp[(size_t)node * 4 + q];
        acc.x = d2 * v.x; acc.y = d2 * v.y; acc.z = d2 * v.z; acc.w = d2 * v.w;
        int e0 = off[node], e1 = off[node + 1];
        int e = e0;
        for (; e + 1 < e1; e += 2) {
            int2 a0 = ew[e], a1 = ew[e + 1];
            float4 v0 = xp[(size_t)(a0.x & 0xFFFFF) * 4 + q];
            float4 v1 = xp[(size_t)(a1.x & 0xFFFFF) * 4 + q];
            float w0 = __int_as_float(a0.y), w1 = __int_as_float(a1.y);
            acc.x += w0 * v0.x; acc.y += w0 * v0.y; acc.z += w0 * v0.z; acc.w += w0 * v0.w;
            acc.x += w1 * v1.x; acc.y += w1 * v1.y; acc.z += w1 * v1.z; acc.w += w1 * v1.w;
        }
        if (e < e1) {
            int2 a0 = ew[e];
            float4 v0 = xp[(size_t)(a0.x & 0xFFFFF) * 4 + q];
            float w0 = __int_as_float(a0.y);
            acc.x += w0 * v0.x; acc.y += w0 * v0.y; acc.z += w0 * v0.z; acc.w += w0 * v0.w;
        }
    }
    accs[ln][q * 4 + 0] = acc.x; accs[ln][q * 4 + 1] = acc.y;
    accs[ln][q * 4 + 2] = acc.z; accs[ln][q * 4 + 3] = acc.w;
    __syncthreads();

    int base = blockIdx.x * 64;
    int j = t & 63;
    for (int nb = (t >> 6); nb < 64; nb += 4) {
        int nd = base + nb;
        if (nd >= n) break;
        float s = bl[j];
#pragma unroll
        for (int k = 0; k < 16; ++k) s += accs[nb][k] * Wl[k * 64 + j];
        h1[(size_t)nd * 64 + j] = fmaxf(s, 0.f);
    }
}

// Dense transform: out[n,KO] = in[n,KI] @ W[KI,KO]  (no bias)
template <int KI, int KO>
__global__ __launch_bounds__(256)
void transform_kernel(const float* __restrict__ in, const float* __restrict__ W,
                      float* __restrict__ out, int n) {
    constexpr int NB = 256 / KO;
    __shared__ float Wl[KI * KO];
    __shared__ float tile[NB * KI];
    int t = threadIdx.x;
    for (int i = t; i < KI * KO; i += 256) Wl[i] = W[i];
    size_t base = (size_t)blockIdx.x * NB;
    for (int i = t; i < NB * KI; i += 256) {
        size_t nd = base + (size_t)(i / KI);
        tile[i] = (nd < (size_t)n) ? in[base * KI + i] : 0.f;
    }
    __syncthreads();
    int j = t % KO, nb = t / KO;
    size_t nd = base + nb;
    if (nd < (size_t)n) {
        float s = 0.f;
#pragma unroll
        for (int k = 0; k < KI; ++k) s += tile[nb * KI + k] * Wl[k * KO + j];
        out[nd * KO + j] = s;
    }
}

// Aggregate WD-wide features through CSR; WD/4 lanes per node, one float4 each.
template <int WD>
__global__ __launch_bounds__(256)
void agg_kernel(const float* __restrict__ h, const float* __restrict__ dis,
                const int* __restrict__ off, const int2* __restrict__ ew,
                const float* __restrict__ b, float* __restrict__ out, int n) {
    constexpr int TPN = WD / 4;
    constexpr int NPB = 256 / TPN;
    int t = threadIdx.x;
    int q = t % TPN, ln = t / TPN;
    int node = blockIdx.x * NPB + ln;
    if (node >= n) return;
    const float4* hp = (const float4*)h;
    float di = dis[node], d2 = di * di;
    float4 v = hp[(size_t)node * TPN + q];
    float4 acc;
    acc.x = d2 * v.x; acc.y = d2 * v.y; acc.z = d2 * v.z; acc.w = d2 * v.w;
    int e0 = off[node], e1 = off[node + 1];
    int e = e0;
    for (; e + 1 < e1; e += 2) {
        int2 a0 = ew[e], a1 = ew[e + 1];
        float4 v0 = hp[(size_t)(a0.x & 0xFFFFF) * TPN + q];
        float4 v1 = hp[(size_t)(a1.x & 0xFFFFF) * TPN + q];
        float w0 = __int_as_float(a0.y), w1 = __int_as_float(a1.y);
        acc.x += w0 * v0.x; acc.y += w0 * v0.y; acc.z += w0 * v0.z; acc.w += w0 * v0.w;
        acc.x += w1 * v1.x; acc.y += w1 * v1.y; acc.z += w1 * v1.z; acc.w += w1 * v1.w;
    }
    if (e < e1) {
        int2 a0 = ew[e];
        float4 v0 = hp[(size_t)(a0.x & 0xFFFFF) * TPN + q];
        float w0 = __int_as_float(a0.y);
        acc.x += w0 * v0.x; acc.y += w0 * v0.y; acc.z += w0 * v0.z; acc.w += w0 * v0.w;
    }
    float4 bb = ((const float4*)b)[q];
    float4 o;
    o.x = acc.x + bb.x; o.y = acc.y + bb.y; o.z = acc.z + bb.z; o.w = acc.w + bb.w;
    ((float4*)out)[(size_t)node * TPN + q] = o;
}

// Mean-pool h2[n,32] per graph (equal sizes npg) -> Z[G,32]
__global__ __launch_bounds__(256)
void pool_kernel(const float* __restrict__ h2, const int* __restrict__ npg_p,
                 float* __restrict__ Z, int n) {
    int npg = npg_p[0];
    int G = n / npg;
    if (G > 4096) G = 4096;
    __shared__ float red[256];
    for (int g = blockIdx.x; g < G; g += gridDim.x) {
        int j = threadIdx.x & 31;
        int r0 = threadIdx.x >> 5;
        float acc = 0.f;
        for (int r = r0; r < npg; r += 8)
            acc += h2[((size_t)g * npg + r) * 32 + j];
        red[threadIdx.x] = acc;
        __syncthreads();
        if (threadIdx.x < 32) {
            float s = 0.f;
#pragma unroll
            for (int q = 0; q < 8; ++q) s += red[q * 32 + threadIdx.x];
            Z[g * 32 + threadIdx.x] = s / (float)npg;
        }
        __syncthreads();
    }
}

// ZW3[g][64] = Z[g][32] @ W3[32][64]
__global__ __launch_bounds__(256)
void zw3_kernel(const float* __restrict__ Z, const float* __restrict__ W3,
                const int* __restrict__ npg_p, float* __restrict__ ZW, int n) {
    __shared__ float Wl[32 * 64];
    int t = threadIdx.x;
    for (int i = t; i < 32 * 64; i += 256) Wl[i] = W3[i];
    __syncthreads();
    int npg = npg_p[0];
    int G = n / npg;
    int j = t & 63, gq = t >> 6;
    for (int g = blockIdx.x * 4 + gq; g < G; g += gridDim.x * 4) {
        float s = 0.f;
#pragma unroll
        for (int k = 0; k < 32; ++k) s += Z[g * 32 + k] * Wl[k * 64 + j];
        ZW[g * 64 + j] = s;
    }
}

// Decoder fused: d_row = relu(sum_e w_e*ZW3[g_e] + d2*ZW3[g_i] + b3);
// then t4[i] = d_row @ W4  (64->16) via LDS phase split. Writes t4 directly.
constexpr int ZCAP  = 104;
constexpr int ZPAD  = 68;    // float stride per graph row in LDS

__global__ __launch_bounds__(256)
void dec1w4_kernel(const float* __restrict__ ZW, const float* __restrict__ dis,
                   const int* __restrict__ off, const int2* __restrict__ ew,
                   const int* __restrict__ npg_p, const float* __restrict__ b3,
                   const float* __restrict__ W4, float* __restrict__ t4, int n) {
    __shared__ float ZWl[ZCAP * ZPAD];
    __shared__ float hl[16][ZPAD];
    __shared__ float W4l[64 * 16];
    __shared__ float bl[64];
    int t = threadIdx.x;
    int npg = npg_p[0];
    int G = n / npg;
    bool ldsz = (G <= ZCAP);
    if (ldsz) {
        for (int i = t; i < G * 64; i += 256)
            ZWl[(i >> 6) * ZPAD + (i & 63)] = ZW[i];
    }
    for (int i = t; i < 64 * 16; i += 256) W4l[i] = W4[i];
    if (t < 64) bl[t] = b3[t];
    __syncthreads();

    float inv = 1.0f / (float)npg;
    int q = t & 15, ln = t >> 4;          // 16 lanes/node, 16 nodes/block
    int node = blockIdx.x * 16 + ln;
    {
        float4 acc = make_float4(0.f, 0.f, 0.f, 0.f);
        if (node < n) {
            const float4* zl = (const float4*)ZWl;
            const float4* zg = (const float4*)ZW;
            float di = dis[node], d2 = di * di;
            int gi = gdiv(node, npg, inv);
            float4 v = ldsz ? zl[gi * (ZPAD / 4) + q] : zg[gi * 16 + q];
            acc.x = d2 * v.x; acc.y = d2 * v.y; acc.z = d2 * v.z; acc.w = d2 * v.w;
            int e0 = off[node], e1 = off[node + 1];
            int e = e0;
            for (; e + 3 < e1; e += 4) {
                int2 a0 = ew[e], a1 = ew[e + 1], a2 = ew[e + 2], a3 = ew[e + 3];
                int g0 = ((unsigned)a0.x) >> 20, g1 = ((unsigned)a1.x) >> 20;
                int g2 = ((unsigned)a2.x) >> 20, g3 = ((unsigned)a3.x) >> 20;
                float4 v0 = ldsz ? zl[g0 * (ZPAD / 4) + q] : zg[g0 * 16 + q];
                float4 v1 = ldsz ? zl[g1 * (ZPAD / 4) + q] : zg[g1 * 16 + q];
                float4 v2 = ldsz ? zl[g2 * (ZPAD / 4) + q] : zg[g2 * 16 + q];
                float4 v3 = ldsz ? zl[g3 * (ZPAD / 4) + q] : zg[g3 * 16 + q];
                float w0 = __int_as_float(a0.y), w1 = __int_as_float(a1.y);
                float w2 = __int_as_float(a2.y), w3 = __int_as_float(a3.y);
                acc.x += w0 * v0.x; acc.y += w0 * v0.y; acc.z += w0 * v0.z; acc.w += w0 * v0.w;
                acc.x += w1 * v1.x; acc.y += w1 * v1.y; acc.z += w1 * v1.z; acc.w += w1 * v1.w;
                acc.x += w2 * v2.x; acc.y += w2 * v2.y; acc.z += w2 * v2.z; acc.w += w2 * v2.w;
                acc.x += w3 * v3.x; acc.y += w3 * v3.y; acc.z += w3 * v3.z; acc.w += w3 * v3.w;
            }
            for (; e < e1; ++e) {
                int2 a0 = ew[e];
                int g0 = ((unsigned)a0.x) >> 20;
                float4 v0 = ldsz ? zl[g0 * (ZPAD / 4) + q] : zg[g0 * 16 + q];
                float w0 = __int_as_float(a0.y);
                acc.x += w0 * v0.x; acc.y += w0 * v0.y; acc.z += w0 * v0.z; acc.w += w0 * v0.w;
            }
        }
        // d row: + b3, relu, stage to LDS
        hl[ln][q * 4 + 0] = fmaxf(acc.x + bl[q * 4 + 0], 0.f);
        hl[ln][q * 4 + 1] = fmaxf(acc.y + bl[q * 4 + 1], 0.f);
        hl[ln][q * 4 + 2] = fmaxf(acc.z + bl[q * 4 + 2], 0.f);
        hl[ln][q * 4 + 3] = fmaxf(acc.w + bl[q * 4 + 3], 0.f);
    }
    __syncthreads();
    // Phase B: t4[node][k] = hl[node][:] @ W4[:,k]; one (node,k) per thread.
    int nd = blockIdx.x * 16 + ln;
    if (nd < n) {
        float s = 0.f;
#pragma unroll
        for (int j = 0; j < 64; ++j) s += hl[ln][j] * W4l[j * 16 + q];
        t4[(size_t)nd * 16 + q] = s;
    }
}

extern "C" void kernel_launch(void* const* d_in, const int* in_sizes, int n_in,
                              void* d_out, int out_size, void* d_ws, size_t ws_size,
                              hipStream_t stream) {
    const float* x     = (const float*)d_in[0];
    const int*   ei    = (const int*)d_in[1];
    const int*   npg   = (const int*)d_in[3];
    const float* W1 = (const float*)d_in[4];
    const float* b1 = (const float*)d_in[5];
    const float* W2 = (const float*)d_in[6];
    const float* b2 = (const float*)d_in[7];
    const float* W3 = (const float*)d_in[8];
    const float* b3 = (const float*)d_in[9];
    const float* W4 = (const float*)d_in[10];
    const float* b4 = (const float*)d_in[11];
    float* out = (float*)d_out;

    int n = in_sizes[0] / 16;
    int E = in_sizes[1] / 2;
    const int* srcp = ei;
    const int* dstp = ei + E;

    char* w = (char*)d_ws;
    auto alloc = [&](size_t bytes) {
        char* p = w;
        w += (bytes + 255) & ~(size_t)255;
        return p;
    };
    float* dis    = (float*)alloc((size_t)n * 4);
    int*   off    = (int*)alloc(((size_t)n + 1) * 4);
    int*   binned = (int*)alloc((size_t)NBMAX * BCAP * 4);
    int2*  ew     = (int2*)alloc((size_t)E * 8);
    float* A      = (float*)alloc((size_t)n * 64 * 4);  // h1
    float* B      = (float*)alloc((size_t)n * 32 * 4);  // t2, later t4
    float* C      = (float*)alloc((size_t)n * 32 * 4);  // h2
    float* Z      = (float*)alloc((size_t)4096 * 32 * 4);
    float* ZWb    = (float*)alloc((size_t)4096 * 64 * 4);
    int*   bcnt   = (int*)alloc((size_t)NBMAX * 4);
    int*   bstart = (int*)alloc((size_t)(NBMAX + 1) * 4);

    int nbuck = (n + BSZ - 1) / BSZ;
    int nbin  = (E + ECHUNK - 1) / ECHUNK;

    // ---- CSR build (no count pass) ----
    hipMemsetAsync(bcnt, 0, (size_t)NBMAX * 4, stream);
    binfill_kernel<<<nbin, 256, 0, stream>>>(srcp, dstp, bcnt, binned, E);
    bstart_scan_kernel<<<1, 256, 0, stream>>>(bcnt, bstart, off, n, nbuck, E);
    csr_off_kernel<<<nbuck, 256, 0, stream>>>(binned, bcnt, bstart, off, dis, n);
    bucket_scatter_kernel<<<nbuck, 256, 0, stream>>>(binned, bcnt, bstart, dis, npg, ew, n);

    // encode
    l1_kernel<<<(n + 63) / 64, 256, 0, stream>>>(x, dis, off, ew, W1, b1, A, n);
    transform_kernel<64, 32><<<(n + 7) / 8, 256, 0, stream>>>(A, W2, B, n);
    agg_kernel<32><<<(n + 31) / 32, 256, 0, stream>>>(B, dis, off, ew, b2, C, n);
    pool_kernel<<<256, 256, 0, stream>>>(C, npg, Z, n);

    // decode
    zw3_kernel<<<32, 256, 0, stream>>>(Z, W3, npg, ZWb, n);
    dec1w4_kernel<<<(n + 15) / 16, 256, 0, stream>>>(ZWb, dis, off, ew, npg, b3, W4, B, n);
    agg_kernel<16><<<(n + 63) / 64, 256, 0, stream>>>(B, dis, off, ew, b4, out, n);
}

// Round 8
// 275.016 us; speedup vs baseline: 2.5523x; 1.0495x over previous
//
#include <hip/hip_runtime.h>
#include <hip/hip_bf16.h>

// ---------------------------------------------------------------------------
// GraphAutoEncoder: 4x GCNConv + mean-pool + repeat, all f32.
// Strategy:
//   - CSR build WITHOUT a count pass: LDS-binned bucket staging (fixed CAP),
//     per-bucket LDS histogram+scan gives node offsets AND degrees (dis).
//   - CSR payload int2{ src | g<<20, wgt }: g(src)=src/npg precomputed once.
//   - Self-loop handled analytically: out[i] += dis[i]^2 * h[i].
// R1: hierarchical scan. R2: int2 payload, vector-per-node gathers.
// R3: binned CSR fill. R4: dec1 fused via ZW3 table. R5: count pass gone.
// R6: g packed in ew.x; W4 fused into dec1.
// R7: dec1 rewritten WITHOUT LDS table staging — R6 post-mortem showed the
//     25.6KB/block ZWl prologue (160MB L2->LDS over 6250 blocks) + 37KB LDS
//     occupancy cap was the real cost, not VALU. Now: gather 32-wide z rows
//     straight from global (Z=12.8KB, L1-resident), aggregate in z-space,
//     dense phase-B (@W3+b3, relu, @W4) per block. zw3_kernel deleted.
//     agg/l1 edge loops unrolled x4 for deeper MLP.
// ---------------------------------------------------------------------------

constexpr int BSZ_LOG = 9;                 // bucket = 512 dst nodes
constexpr int BSZ     = 1 << BSZ_LOG;
constexpr int NBMAX   = 256;               // max buckets (n <= 128K)
constexpr int ECHUNK  = 8192;              // edges per binfill block
constexpr int BCAP    = 12288;             // staging capacity per bucket

__device__ __forceinline__ int gdiv(int v, int npg, float inv) {
    int g = __float2int_rz((float)v * inv);
    int r = v - g * npg;
    if (r < 0) --g; else if (r >= npg) ++g;
    return g;
}

// Pass 1: LDS-binned bucket staging. code = (dst_local << 20) | src (src < 2^20).
__global__ __launch_bounds__(256)
void binfill_kernel(const int* __restrict__ src, const int* __restrict__ dst,
                    int* __restrict__ bcnt, int* __restrict__ binned, int E) {
    __shared__ int hist[NBMAX], hexcl[NBMAX], gbase[NBMAX], hpos[NBMAX], tmp[NBMAX];
    __shared__ int sorted[ECHUNK];
    __shared__ unsigned char bsorted[ECHUNK];
    int t = threadIdx.x;
    hist[t] = 0; hpos[t] = 0;
    __syncthreads();
    int e0 = blockIdx.x * ECHUNK;
    int cnt = min(ECHUNK, E - e0);
    for (int i = t; i < cnt; i += 256)
        atomicAdd(&hist[dst[e0 + i] >> BSZ_LOG], 1);
    __syncthreads();
    tmp[t] = hist[t];
    __syncthreads();
    for (int d = 1; d < 256; d <<= 1) {
        int v = (t >= d) ? tmp[t - d] : 0;
        __syncthreads();
        tmp[t] += v;
        __syncthreads();
    }
    hexcl[t] = (t == 0) ? 0 : tmp[t - 1];
    int h = hist[t];
    gbase[t] = (h > 0) ? atomicAdd(&bcnt[t], h) : 0;
    __syncthreads();
    for (int i = t; i < cnt; i += 256) {
        int s = src[e0 + i], d = dst[e0 + i];
        int b = d >> BSZ_LOG;
        int code = ((d & (BSZ - 1)) << 20) | s;
        int sp = hexcl[b] + atomicAdd(&hpos[b], 1);
        sorted[sp] = code;
        bsorted[sp] = (unsigned char)b;
    }
    __syncthreads();
    for (int i = t; i < cnt; i += 256) {
        int b = bsorted[i];
        binned[(size_t)b * BCAP + gbase[b] + (i - hexcl[b])] = sorted[i];
    }
}

// Exclusive scan of per-bucket totals -> bstart[0..nbuck]; off[n] = E.
__global__ __launch_bounds__(256)
void bstart_scan_kernel(const int* __restrict__ bcnt, int* __restrict__ bstart,
                        int* __restrict__ off, int n, int nbuck, int E) {
    __shared__ int sums[256];
    int t = threadIdx.x;
    int v = (t < nbuck) ? bcnt[t] : 0;
    sums[t] = v;
    __syncthreads();
    for (int d = 1; d < 256; d <<= 1) {
        int s = (t >= d) ? sums[t - d] : 0;
        __syncthreads();
        sums[t] += s;
        __syncthreads();
    }
    if (t <= nbuck) bstart[t] = (t == 0) ? 0 : sums[t - 1];
    if (t == 0) off[n] = E;
}

// Per bucket: LDS node histogram + scan -> coalesced off[] and dis[] writes.
__global__ __launch_bounds__(256)
void csr_off_kernel(const int* __restrict__ binned, const int* __restrict__ bcnt,
                    const int* __restrict__ bstart, int* __restrict__ off,
                    float* __restrict__ dis, int n) {
    __shared__ int hist[BSZ];
    __shared__ int lstart[BSZ];
    __shared__ int partial[256];
    int b = blockIdx.x, t = threadIdx.x;
    int nb0 = b << BSZ_LOG;
    int nn = min(BSZ, n - nb0);
    int m = bcnt[b];
    const int* bp = binned + (size_t)b * BCAP;
    for (int i = t; i < BSZ; i += 256) hist[i] = 0;
    __syncthreads();
    for (int i = t; i < m; i += 256)
        atomicAdd(&hist[bp[i] >> 20], 1);
    __syncthreads();
    int a0 = hist[2 * t], a1 = hist[2 * t + 1];
    partial[t] = a0 + a1;
    __syncthreads();
    for (int d = 1; d < 256; d <<= 1) {
        int v = (t >= d) ? partial[t - d] : 0;
        __syncthreads();
        partial[t] += v;
        __syncthreads();
    }
    int base = (t == 0) ? 0 : partial[t - 1];
    lstart[2 * t] = base;
    lstart[2 * t + 1] = base + a0;
    __syncthreads();
    int bs = bstart[b];
    for (int i = t; i < nn; i += 256) {
        off[nb0 + i] = bs + lstart[i];
        dis[nb0 + i] = rsqrtf((float)hist[i] + 1.0f);   // +1 = self-loop
    }
}

// Per bucket: scatter {src | g<<20, w} to exact CSR positions (L2-local window).
__global__ __launch_bounds__(256)
void bucket_scatter_kernel(const int* __restrict__ binned, const int* __restrict__ bcnt,
                           const int* __restrict__ bstart, const float* __restrict__ dis,
                           const int* __restrict__ npg_p, int2* __restrict__ ew, int n) {
    __shared__ int lstart[BSZ];
    __shared__ int lpos[BSZ];
    __shared__ float ldis[BSZ];
    __shared__ int partial[256];
    int b = blockIdx.x, t = threadIdx.x;
    int nb0 = b << BSZ_LOG;
    int nn = min(BSZ, n - nb0);
    int m = bcnt[b];
    int npg = npg_p[0];
    float inv = 1.0f / (float)npg;
    const int* bp = binned + (size_t)b * BCAP;
    for (int i = t; i < BSZ; i += 256) {
        lstart[i] = 0; lpos[i] = 0;
        ldis[i] = (i < nn) ? dis[nb0 + i] : 0.f;
    }
    __syncthreads();
    for (int i = t; i < m; i += 256)
        atomicAdd(&lstart[bp[i] >> 20], 1);
    __syncthreads();
    int a0 = lstart[2 * t], a1 = lstart[2 * t + 1];
    partial[t] = a0 + a1;
    __syncthreads();
    for (int d = 1; d < 256; d <<= 1) {
        int v = (t >= d) ? partial[t - d] : 0;
        __syncthreads();
        partial[t] += v;
        __syncthreads();
    }
    int base = (t == 0) ? 0 : partial[t - 1];
    lstart[2 * t] = base;
    lstart[2 * t + 1] = base + a0;
    __syncthreads();
    int e0 = bstart[b];
    for (int i = t; i < m; i += 256) {
        int code = bp[i];
        int dl = code >> 20, s = code & 0xFFFFF;
        float w = dis[s] * ldis[dl];
        int g = gdiv(s, npg, inv);
        int p = e0 + lstart[dl] + atomicAdd(&lpos[dl], 1);
        ew[p] = make_int2(s | (g << 20), __float_as_int(w));
    }
}

// Layer 1: agg x (16-wide, 4 lanes/node) then GEMM 16->64 + b1 + relu.
__global__ __launch_bounds__(256)
void l1_kernel(const float* __restrict__ x, const float* __restrict__ dis,
               const int* __restrict__ off, const int2* __restrict__ ew,
               const float* __restrict__ W1, const float* __restrict__ b1,
               float* __restrict__ h1, int n) {
    __shared__ float accs[64][17];
    __shared__ float Wl[16 * 64];
    __shared__ float bl[64];
    int t = threadIdx.x;
    for (int i = t; i < 16 * 64; i += 256) Wl[i] = W1[i];
    if (t < 64) bl[t] = b1[t];

    int q = t & 3, ln = t >> 2;
    int node = blockIdx.x * 64 + ln;
    const float4* xp = (const float4*)x;
    float4 acc = make_float4(0.f, 0.f, 0.f, 0.f);
    if (node < n) {
        float di = dis[node], d2 = di * di;
        float4 v = xp[(size_t)node * 4 + q];
        acc.x = d2 * v.x; acc.y = d2 * v.y; acc.z = d2 * v.z; acc.w = d2 * v.w;
        int e0 = off[node], e1 = off[node + 1];
        int e = e0;
        for (; e + 3 < e1; e += 4) {
            int2 a0 = ew[e], a1 = ew[e + 1], a2 = ew[e + 2], a3 = ew[e + 3];
            float4 v0 = xp[(size_t)(a0.x & 0xFFFFF) * 4 + q];
            float4 v1 = xp[(size_t)(a1.x & 0xFFFFF) * 4 + q];
            float4 v2 = xp[(size_t)(a2.x & 0xFFFFF) * 4 + q];
            float4 v3 = xp[(size_t)(a3.x & 0xFFFFF) * 4 + q];
            float w0 = __int_as_float(a0.y), w1 = __int_as_float(a1.y);
            float w2 = __int_as_float(a2.y), w3 = __int_as_float(a3.y);
            acc.x += w0 * v0.x; acc.y += w0 * v0.y; acc.z += w0 * v0.z; acc.w += w0 * v0.w;
            acc.x += w1 * v1.x; acc.y += w1 * v1.y; acc.z += w1 * v1.z; acc.w += w1 * v1.w;
            acc.x += w2 * v2.x; acc.y += w2 * v2.y; acc.z += w2 * v2.z; acc.w += w2 * v2.w;
            acc.x += w3 * v3.x; acc.y += w3 * v3.y; acc.z += w3 * v3.z; acc.w += w3 * v3.w;
        }
        for (; e < e1; ++e) {
            int2 a0 = ew[e];
            float4 v0 = xp[(size_t)(a0.x & 0xFFFFF) * 4 + q];
            float w0 = __int_as_float(a0.y);
            acc.x += w0 * v0.x; acc.y += w0 * v0.y; acc.z += w0 * v0.z; acc.w += w0 * v0.w;
        }
    }
    accs[ln][q * 4 + 0] = acc.x; accs[ln][q * 4 + 1] = acc.y;
    accs[ln][q * 4 + 2] = acc.z; accs[ln][q * 4 + 3] = acc.w;
    __syncthreads();

    int base = blockIdx.x * 64;
    int j = t & 63;
    for (int nb = (t >> 6); nb < 64; nb += 4) {
        int nd = base + nb;
        if (nd >= n) break;
        float s = bl[j];
#pragma unroll
        for (int k = 0; k < 16; ++k) s += accs[nb][k] * Wl[k * 64 + j];
        h1[(size_t)nd * 64 + j] = fmaxf(s, 0.f);
    }
}

// Dense transform: out[n,KO] = in[n,KI] @ W[KI,KO]  (no bias)
template <int KI, int KO>
__global__ __launch_bounds__(256)
void transform_kernel(const float* __restrict__ in, const float* __restrict__ W,
                      float* __restrict__ out, int n) {
    constexpr int NB = 256 / KO;
    __shared__ float Wl[KI * KO];
    __shared__ float tile[NB * KI];
    int t = threadIdx.x;
    for (int i = t; i < KI * KO; i += 256) Wl[i] = W[i];
    size_t base = (size_t)blockIdx.x * NB;
    for (int i = t; i < NB * KI; i += 256) {
        size_t nd = base + (size_t)(i / KI);
        tile[i] = (nd < (size_t)n) ? in[base * KI + i] : 0.f;
    }
    __syncthreads();
    int j = t % KO, nb = t / KO;
    size_t nd = base + nb;
    if (nd < (size_t)n) {
        float s = 0.f;
#pragma unroll
        for (int k = 0; k < KI; ++k) s += tile[nb * KI + k] * Wl[k * KO + j];
        out[nd * KO + j] = s;
    }
}

// Aggregate WD-wide features through CSR; WD/4 lanes per node, one float4 each.
template <int WD>
__global__ __launch_bounds__(256)
void agg_kernel(const float* __restrict__ h, const float* __restrict__ dis,
                const int* __restrict__ off, const int2* __restrict__ ew,
                const float* __restrict__ b, float* __restrict__ out, int n) {
    constexpr int TPN = WD / 4;
    constexpr int NPB = 256 / TPN;
    int t = threadIdx.x;
    int q = t % TPN, ln = t / TPN;
    int node = blockIdx.x * NPB + ln;
    if (node >= n) return;
    const float4* hp = (const float4*)h;
    float di = dis[node], d2 = di * di;
    float4 v = hp[(size_t)node * TPN + q];
    float4 acc;
    acc.x = d2 * v.x; acc.y = d2 * v.y; acc.z = d2 * v.z; acc.w = d2 * v.w;
    int e0 = off[node], e1 = off[node + 1];
    int e = e0;
    for (; e + 3 < e1; e += 4) {
        int2 a0 = ew[e], a1 = ew[e + 1], a2 = ew[e + 2], a3 = ew[e + 3];
        float4 v0 = hp[(size_t)(a0.x & 0xFFFFF) * TPN + q];
        float4 v1 = hp[(size_t)(a1.x & 0xFFFFF) * TPN + q];
        float4 v2 = hp[(size_t)(a2.x & 0xFFFFF) * TPN + q];
        float4 v3 = hp[(size_t)(a3.x & 0xFFFFF) * TPN + q];
        float w0 = __int_as_float(a0.y), w1 = __int_as_float(a1.y);
        float w2 = __int_as_float(a2.y), w3 = __int_as_float(a3.y);
        acc.x += w0 * v0.x; acc.y += w0 * v0.y; acc.z += w0 * v0.z; acc.w += w0 * v0.w;
        acc.x += w1 * v1.x; acc.y += w1 * v1.y; acc.z += w1 * v1.z; acc.w += w1 * v1.w;
        acc.x += w2 * v2.x; acc.y += w2 * v2.y; acc.z += w2 * v2.z; acc.w += w2 * v2.w;
        acc.x += w3 * v3.x; acc.y += w3 * v3.y; acc.z += w3 * v3.z; acc.w += w3 * v3.w;
    }
    for (; e < e1; ++e) {
        int2 a0 = ew[e];
        float4 v0 = hp[(size_t)(a0.x & 0xFFFFF) * TPN + q];
        float w0 = __int_as_float(a0.y);
        acc.x += w0 * v0.x; acc.y += w0 * v0.y; acc.z += w0 * v0.z; acc.w += w0 * v0.w;
    }
    float4 bb = ((const float4*)b)[q];
    float4 o;
    o.x = acc.x + bb.x; o.y = acc.y + bb.y; o.z = acc.z + bb.z; o.w = acc.w + bb.w;
    ((float4*)out)[(size_t)node * TPN + q] = o;
}

// Mean-pool h2[n,32] per graph (equal sizes npg) -> Z[G,32]
__global__ __launch_bounds__(256)
void pool_kernel(const float* __restrict__ h2, const int* __restrict__ npg_p,
                 float* __restrict__ Z, int n) {
    int npg = npg_p[0];
    int G = n / npg;
    if (G > 4096) G = 4096;
    __shared__ float red[256];
    for (int g = blockIdx.x; g < G; g += gridDim.x) {
        int j = threadIdx.x & 31;
        int r0 = threadIdx.x >> 5;
        float acc = 0.f;
        for (int r = r0; r < npg; r += 8)
            acc += h2[((size_t)g * npg + r) * 32 + j];
        red[threadIdx.x] = acc;
        __syncthreads();
        if (threadIdx.x < 32) {
            float s = 0.f;
#pragma unroll
            for (int q = 0; q < 8; ++q) s += red[q * 32 + threadIdx.x];
            Z[g * 32 + threadIdx.x] = s / (float)npg;
        }
        __syncthreads();
    }
}

// Decoder fused, NO table staging: aggregate 32-wide z rows straight from
// global (Z = G*32*4B, L1-resident); then per block: (@W3+b3) relu (@W4).
// 8 lanes/node, 32 nodes/block. LDS: W3l+W4l+zacc+hl ~= 24.5KB.
__global__ __launch_bounds__(256)
void dec1v2_kernel(const float* __restrict__ Z, const float* __restrict__ dis,
                   const int* __restrict__ off, const int2* __restrict__ ew,
                   const int* __restrict__ npg_p, const float* __restrict__ W3,
                   const float* __restrict__ b3, const float* __restrict__ W4,
                   float* __restrict__ t4, int n) {
    __shared__ float W3l[32 * 64];
    __shared__ float W4l[64 * 16];
    __shared__ float zacc[32 * 33];
    __shared__ float hl[32 * 65];
    int t = threadIdx.x;
    for (int i = t; i < 32 * 64; i += 256) W3l[i] = W3[i];
    for (int i = t; i < 64 * 16; i += 256) W4l[i] = W4[i];

    int npg = npg_p[0];
    float inv = 1.0f / (float)npg;
    int q = t & 7, ln = t >> 3;          // 8 lanes/node, 32 nodes/block
    int base = blockIdx.x * 32;
    int node = base + ln;
    const float4* zp = (const float4*)Z;

    float4 acc = make_float4(0.f, 0.f, 0.f, 0.f);
    if (node < n) {
        float di = dis[node], d2 = di * di;
        int gi = gdiv(node, npg, inv);
        float4 v = zp[(size_t)gi * 8 + q];
        acc.x = d2 * v.x; acc.y = d2 * v.y; acc.z = d2 * v.z; acc.w = d2 * v.w;
        int e0 = off[node], e1 = off[node + 1];
        int e = e0;
        for (; e + 3 < e1; e += 4) {
            int2 a0 = ew[e], a1 = ew[e + 1], a2 = ew[e + 2], a3 = ew[e + 3];
            int g0 = ((unsigned)a0.x) >> 20, g1 = ((unsigned)a1.x) >> 20;
            int g2 = ((unsigned)a2.x) >> 20, g3 = ((unsigned)a3.x) >> 20;
            float4 v0 = zp[(size_t)g0 * 8 + q];
            float4 v1 = zp[(size_t)g1 * 8 + q];
            float4 v2 = zp[(size_t)g2 * 8 + q];
            float4 v3 = zp[(size_t)g3 * 8 + q];
            float w0 = __int_as_float(a0.y), w1 = __int_as_float(a1.y);
            float w2 = __int_as_float(a2.y), w3 = __int_as_float(a3.y);
            acc.x += w0 * v0.x; acc.y += w0 * v0.y; acc.z += w0 * v0.z; acc.w += w0 * v0.w;
            acc.x += w1 * v1.x; acc.y += w1 * v1.y; acc.z += w1 * v1.z; acc.w += w1 * v1.w;
            acc.x += w2 * v2.x; acc.y += w2 * v2.y; acc.z += w2 * v2.z; acc.w += w2 * v2.w;
            acc.x += w3 * v3.x; acc.y += w3 * v3.y; acc.z += w3 * v3.z; acc.w += w3 * v3.w;
        }
        for (; e < e1; ++e) {
            int2 a0 = ew[e];
            int g0 = ((unsigned)a0.x) >> 20;
            float4 v0 = zp[(size_t)g0 * 8 + q];
            float w0 = __int_as_float(a0.y);
            acc.x += w0 * v0.x; acc.y += w0 * v0.y; acc.z += w0 * v0.z; acc.w += w0 * v0.w;
        }
    }
    zacc[ln * 33 + q * 4 + 0] = acc.x;
    zacc[ln * 33 + q * 4 + 1] = acc.y;
    zacc[ln * 33 + q * 4 + 2] = acc.z;
    zacc[ln * 33 + q * 4 + 3] = acc.w;
    __syncthreads();

    // Phase B1: h[ln][j] = relu(b3[j] + zacc[ln][:] . W3[:,j])
    for (int o = t; o < 32 * 64; o += 256) {
        int l2 = o >> 6, j = o & 63;
        if (base + l2 < n) {
            float s = b3[j];
#pragma unroll
            for (int k = 0; k < 32; ++k) s += zacc[l2 * 33 + k] * W3l[k * 64 + j];
            hl[l2 * 65 + j] = fmaxf(s, 0.f);
        }
    }
    __syncthreads();

    // Phase B2: t4[node][c] = hl[ln][:] . W4[:,c]
    for (int o = t; o < 32 * 16; o += 256) {
        int l2 = o >> 4, c = o & 15;
        int nd = base + l2;
        if (nd < n) {
            float s = 0.f;
#pragma unroll
            for (int j = 0; j < 64; ++j) s += hl[l2 * 65 + j] * W4l[j * 16 + c];
            t4[(size_t)nd * 16 + c] = s;
        }
    }
}

extern "C" void kernel_launch(void* const* d_in, const int* in_sizes, int n_in,
                              void* d_out, int out_size, void* d_ws, size_t ws_size,
                              hipStream_t stream) {
    const float* x     = (const float*)d_in[0];
    const int*   ei    = (const int*)d_in[1];
    const int*   npg   = (const int*)d_in[3];
    const float* W1 = (const float*)d_in[4];
    const float* b1 = (const float*)d_in[5];
    const float* W2 = (const float*)d_in[6];
    const float* b2 = (const float*)d_in[7];
    const float* W3 = (const float*)d_in[8];
    const float* b3 = (const float*)d_in[9];
    const float* W4 = (const float*)d_in[10];
    const float* b4 = (const float*)d_in[11];
    float* out = (float*)d_out;

    int n = in_sizes[0] / 16;
    int E = in_sizes[1] / 2;
    const int* srcp = ei;
    const int* dstp = ei + E;

    char* w = (char*)d_ws;
    auto alloc = [&](size_t bytes) {
        char* p = w;
        w += (bytes + 255) & ~(size_t)255;
        return p;
    };
    float* dis    = (float*)alloc((size_t)n * 4);
    int*   off    = (int*)alloc(((size_t)n + 1) * 4);
    int*   binned = (int*)alloc((size_t)NBMAX * BCAP * 4);
    int2*  ew     = (int2*)alloc((size_t)E * 8);
    float* A      = (float*)alloc((size_t)n * 64 * 4);  // h1
    float* B      = (float*)alloc((size_t)n * 32 * 4);  // t2, later t4
    float* C      = (float*)alloc((size_t)n * 32 * 4);  // h2
    float* Z      = (float*)alloc((size_t)4096 * 32 * 4);
    int*   bcnt   = (int*)alloc((size_t)NBMAX * 4);
    int*   bstart = (int*)alloc((size_t)(NBMAX + 1) * 4);

    int nbuck = (n + BSZ - 1) / BSZ;
    int nbin  = (E + ECHUNK - 1) / ECHUNK;

    // ---- CSR build (no count pass) ----
    hipMemsetAsync(bcnt, 0, (size_t)NBMAX * 4, stream);
    binfill_kernel<<<nbin, 256, 0, stream>>>(srcp, dstp, bcnt, binned, E);
    bstart_scan_kernel<<<1, 256, 0, stream>>>(bcnt, bstart, off, n, nbuck, E);
    csr_off_kernel<<<nbuck, 256, 0, stream>>>(binned, bcnt, bstart, off, dis, n);
    bucket_scatter_kernel<<<nbuck, 256, 0, stream>>>(binned, bcnt, bstart, dis, npg, ew, n);

    // encode
    l1_kernel<<<(n + 63) / 64, 256, 0, stream>>>(x, dis, off, ew, W1, b1, A, n);
    transform_kernel<64, 32><<<(n + 7) / 8, 256, 0, stream>>>(A, W2, B, n);
    agg_kernel<32><<<(n + 31) / 32, 256, 0, stream>>>(B, dis, off, ew, b2, C, n);
    pool_kernel<<<256, 256, 0, stream>>>(C, npg, Z, n);

    // decode (dec1v2 reads Z directly; zw3 deleted)
    dec1v2_kernel<<<(n + 31) / 32, 256, 0, stream>>>(Z, dis, off, ew, npg, W3, b3, W4, B, n);
    agg_kernel<16><<<(n + 63) / 64, 256, 0, stream>>>(B, dis, off, ew, b4, out, n);
}

// Round 9
// 266.392 us; speedup vs baseline: 2.6349x; 1.0324x over previous
//
#include <hip/hip_runtime.h>
#include <hip/hip_bf16.h>

// ---------------------------------------------------------------------------
// GraphAutoEncoder: 4x GCNConv + mean-pool + repeat, all f32.
// R1: hierarchical scan. R2: int2 payload, vector-per-node gathers.
// R3: binned CSR fill. R4: dec1 fused via ZW3 table. R5: count pass gone.
// R6: g packed in ew.x; W4 fused into dec1. R7: dec1 gathers z from global
//     (L1-resident), dense W3/W4 phase-B, no table staging.
// R8: edge loops in ALL gather kernels restructured: lane q of each TPN-lane
//     group loads ew[e+q] (coalesced, no 8x redundancy), edges broadcast
//     in-register via __shfl(.,k,TPN); next chunk's ew prefetched before
//     processing current -> ew L2/L3 latency hides under TPN independent
//     row gathers. (R7 post-mortem: dec1v2 was serialized on the dependent
//     ew->gather chain, 74% VALU-idle at 51% occupancy.)
// ---------------------------------------------------------------------------

constexpr int BSZ_LOG = 9;                 // bucket = 512 dst nodes
constexpr int BSZ     = 1 << BSZ_LOG;
constexpr int NBMAX   = 256;               // max buckets (n <= 128K)
constexpr int ECHUNK  = 8192;              // edges per binfill block
constexpr int BCAP    = 12288;             // staging capacity per bucket

__device__ __forceinline__ int gdiv(int v, int npg, float inv) {
    int g = __float2int_rz((float)v * inv);
    int r = v - g * npg;
    if (r < 0) --g; else if (r >= npg) ++g;
    return g;
}

// Pass 1: LDS-binned bucket staging. code = (dst_local << 20) | src (src < 2^20).
__global__ __launch_bounds__(256)
void binfill_kernel(const int* __restrict__ src, const int* __restrict__ dst,
                    int* __restrict__ bcnt, int* __restrict__ binned, int E) {
    __shared__ int hist[NBMAX], hexcl[NBMAX], gbase[NBMAX], hpos[NBMAX], tmp[NBMAX];
    __shared__ int sorted[ECHUNK];
    __shared__ unsigned char bsorted[ECHUNK];
    int t = threadIdx.x;
    hist[t] = 0; hpos[t] = 0;
    __syncthreads();
    int e0 = blockIdx.x * ECHUNK;
    int cnt = min(ECHUNK, E - e0);
    for (int i = t; i < cnt; i += 256)
        atomicAdd(&hist[dst[e0 + i] >> BSZ_LOG], 1);
    __syncthreads();
    tmp[t] = hist[t];
    __syncthreads();
    for (int d = 1; d < 256; d <<= 1) {
        int v = (t >= d) ? tmp[t - d] : 0;
        __syncthreads();
        tmp[t] += v;
        __syncthreads();
    }
    hexcl[t] = (t == 0) ? 0 : tmp[t - 1];
    int h = hist[t];
    gbase[t] = (h > 0) ? atomicAdd(&bcnt[t], h) : 0;
    __syncthreads();
    for (int i = t; i < cnt; i += 256) {
        int s = src[e0 + i], d = dst[e0 + i];
        int b = d >> BSZ_LOG;
        int code = ((d & (BSZ - 1)) << 20) | s;
        int sp = hexcl[b] + atomicAdd(&hpos[b], 1);
        sorted[sp] = code;
        bsorted[sp] = (unsigned char)b;
    }
    __syncthreads();
    for (int i = t; i < cnt; i += 256) {
        int b = bsorted[i];
        binned[(size_t)b * BCAP + gbase[b] + (i - hexcl[b])] = sorted[i];
    }
}

// Exclusive scan of per-bucket totals -> bstart[0..nbuck]; off[n] = E.
__global__ __launch_bounds__(256)
void bstart_scan_kernel(const int* __restrict__ bcnt, int* __restrict__ bstart,
                        int* __restrict__ off, int n, int nbuck, int E) {
    __shared__ int sums[256];
    int t = threadIdx.x;
    int v = (t < nbuck) ? bcnt[t] : 0;
    sums[t] = v;
    __syncthreads();
    for (int d = 1; d < 256; d <<= 1) {
        int s = (t >= d) ? sums[t - d] : 0;
        __syncthreads();
        sums[t] += s;
        __syncthreads();
    }
    if (t <= nbuck) bstart[t] = (t == 0) ? 0 : sums[t - 1];
    if (t == 0) off[n] = E;
}

// Per bucket: LDS node histogram + scan -> coalesced off[] and dis[] writes.
__global__ __launch_bounds__(256)
void csr_off_kernel(const int* __restrict__ binned, const int* __restrict__ bcnt,
                    const int* __restrict__ bstart, int* __restrict__ off,
                    float* __restrict__ dis, int n) {
    __shared__ int hist[BSZ];
    __shared__ int lstart[BSZ];
    __shared__ int partial[256];
    int b = blockIdx.x, t = threadIdx.x;
    int nb0 = b << BSZ_LOG;
    int nn = min(BSZ, n - nb0);
    int m = bcnt[b];
    const int* bp = binned + (size_t)b * BCAP;
    for (int i = t; i < BSZ; i += 256) hist[i] = 0;
    __syncthreads();
    for (int i = t; i < m; i += 256)
        atomicAdd(&hist[bp[i] >> 20], 1);
    __syncthreads();
    int a0 = hist[2 * t], a1 = hist[2 * t + 1];
    partial[t] = a0 + a1;
    __syncthreads();
    for (int d = 1; d < 256; d <<= 1) {
        int v = (t >= d) ? partial[t - d] : 0;
        __syncthreads();
        partial[t] += v;
        __syncthreads();
    }
    int base = (t == 0) ? 0 : partial[t - 1];
    lstart[2 * t] = base;
    lstart[2 * t + 1] = base + a0;
    __syncthreads();
    int bs = bstart[b];
    for (int i = t; i < nn; i += 256) {
        off[nb0 + i] = bs + lstart[i];
        dis[nb0 + i] = rsqrtf((float)hist[i] + 1.0f);   // +1 = self-loop
    }
}

// Per bucket: scatter {src | g<<20, w} to exact CSR positions (L2-local window).
__global__ __launch_bounds__(256)
void bucket_scatter_kernel(const int* __restrict__ binned, const int* __restrict__ bcnt,
                           const int* __restrict__ bstart, const float* __restrict__ dis,
                           const int* __restrict__ npg_p, int2* __restrict__ ew, int n) {
    __shared__ int lstart[BSZ];
    __shared__ int lpos[BSZ];
    __shared__ float ldis[BSZ];
    __shared__ int partial[256];
    int b = blockIdx.x, t = threadIdx.x;
    int nb0 = b << BSZ_LOG;
    int nn = min(BSZ, n - nb0);
    int m = bcnt[b];
    int npg = npg_p[0];
    float inv = 1.0f / (float)npg;
    const int* bp = binned + (size_t)b * BCAP;
    for (int i = t; i < BSZ; i += 256) {
        lstart[i] = 0; lpos[i] = 0;
        ldis[i] = (i < nn) ? dis[nb0 + i] : 0.f;
    }
    __syncthreads();
    for (int i = t; i < m; i += 256)
        atomicAdd(&lstart[bp[i] >> 20], 1);
    __syncthreads();
    int a0 = lstart[2 * t], a1 = lstart[2 * t + 1];
    partial[t] = a0 + a1;
    __syncthreads();
    for (int d = 1; d < 256; d <<= 1) {
        int v = (t >= d) ? partial[t - d] : 0;
        __syncthreads();
        partial[t] += v;
        __syncthreads();
    }
    int base = (t == 0) ? 0 : partial[t - 1];
    lstart[2 * t] = base;
    lstart[2 * t + 1] = base + a0;
    __syncthreads();
    int e0 = bstart[b];
    for (int i = t; i < m; i += 256) {
        int code = bp[i];
        int dl = code >> 20, s = code & 0xFFFFF;
        float w = dis[s] * ldis[dl];
        int g = gdiv(s, npg, inv);
        int p = e0 + lstart[dl] + atomicAdd(&lpos[dl], 1);
        ew[p] = make_int2(s | (g << 20), __float_as_int(w));
    }
}

// ---- shfl-broadcast edge-gather core (TPN lanes per node) -----------------
// hp: float4 row base; row index = (broadcast ax) & 0xFFFFF (or >>20 for z).
template <int TPN, bool USE_G>
__device__ __forceinline__ float4
edge_loop(const float4* __restrict__ hp, const int2* __restrict__ ew,
          int e0, int e1, int q, float4 acc) {
    int deg = e1 - e0;
    int nfull = deg / TPN;
    int r = deg - nfull * TPN;
    int idx = e0 + q;
    int2 a = make_int2(0, 0);
    if (idx < e1) a = ew[idx];
    for (int c = 0; c < nfull; ++c) {
        int nidx = idx + (c + 1) * TPN;
        int2 an = make_int2(0, 0);
        if (nidx < e1) an = ew[nidx];
#pragma unroll
        for (int k = 0; k < TPN; ++k) {
            int ax = __shfl(a.x, k, TPN);
            float w = __int_as_float(__shfl(a.y, k, TPN));
            int row = USE_G ? (int)(((unsigned)ax) >> 20) : (ax & 0xFFFFF);
            float4 v = hp[(size_t)row * TPN + q];
            acc.x += w * v.x; acc.y += w * v.y; acc.z += w * v.z; acc.w += w * v.w;
        }
        a = an;
    }
    for (int k = 0; k < r; ++k) {
        int ax = __shfl(a.x, k, TPN);
        float w = __int_as_float(__shfl(a.y, k, TPN));
        int row = USE_G ? (int)(((unsigned)ax) >> 20) : (ax & 0xFFFFF);
        float4 v = hp[(size_t)row * TPN + q];
        acc.x += w * v.x; acc.y += w * v.y; acc.z += w * v.z; acc.w += w * v.w;
    }
    return acc;
}

// Layer 1: agg x (16-wide, 4 lanes/node) then GEMM 16->64 + b1 + relu.
__global__ __launch_bounds__(256)
void l1_kernel(const float* __restrict__ x, const float* __restrict__ dis,
               const int* __restrict__ off, const int2* __restrict__ ew,
               const float* __restrict__ W1, const float* __restrict__ b1,
               float* __restrict__ h1, int n) {
    __shared__ float accs[64][17];
    __shared__ float Wl[16 * 64];
    __shared__ float bl[64];
    int t = threadIdx.x;
    for (int i = t; i < 16 * 64; i += 256) Wl[i] = W1[i];
    if (t < 64) bl[t] = b1[t];

    int q = t & 3, ln = t >> 2;
    int node = blockIdx.x * 64 + ln;
    const float4* xp = (const float4*)x;
    float4 acc = make_float4(0.f, 0.f, 0.f, 0.f);
    if (node < n) {
        float di = dis[node], d2 = di * di;
        float4 v = xp[(size_t)node * 4 + q];
        acc.x = d2 * v.x; acc.y = d2 * v.y; acc.z = d2 * v.z; acc.w = d2 * v.w;
        acc = edge_loop<4, false>(xp, ew, off[node], off[node + 1], q, acc);
    }
    accs[ln][q * 4 + 0] = acc.x; accs[ln][q * 4 + 1] = acc.y;
    accs[ln][q * 4 + 2] = acc.z; accs[ln][q * 4 + 3] = acc.w;
    __syncthreads();

    int base = blockIdx.x * 64;
    int j = t & 63;
    for (int nb = (t >> 6); nb < 64; nb += 4) {
        int nd = base + nb;
        if (nd >= n) break;
        float s = bl[j];
#pragma unroll
        for (int k = 0; k < 16; ++k) s += accs[nb][k] * Wl[k * 64 + j];
        h1[(size_t)nd * 64 + j] = fmaxf(s, 0.f);
    }
}

// Dense transform: out[n,KO] = in[n,KI] @ W[KI,KO]  (no bias)
template <int KI, int KO>
__global__ __launch_bounds__(256)
void transform_kernel(const float* __restrict__ in, const float* __restrict__ W,
                      float* __restrict__ out, int n) {
    constexpr int NB = 256 / KO;
    __shared__ float Wl[KI * KO];
    __shared__ float tile[NB * KI];
    int t = threadIdx.x;
    for (int i = t; i < KI * KO; i += 256) Wl[i] = W[i];
    size_t base = (size_t)blockIdx.x * NB;
    for (int i = t; i < NB * KI; i += 256) {
        size_t nd = base + (size_t)(i / KI);
        tile[i] = (nd < (size_t)n) ? in[base * KI + i] : 0.f;
    }
    __syncthreads();
    int j = t % KO, nb = t / KO;
    size_t nd = base + nb;
    if (nd < (size_t)n) {
        float s = 0.f;
#pragma unroll
        for (int k = 0; k < KI; ++k) s += tile[nb * KI + k] * Wl[k * KO + j];
        out[nd * KO + j] = s;
    }
}

// Aggregate WD-wide features through CSR; WD/4 lanes per node.
template <int WD>
__global__ __launch_bounds__(256)
void agg_kernel(const float* __restrict__ h, const float* __restrict__ dis,
                const int* __restrict__ off, const int2* __restrict__ ew,
                const float* __restrict__ b, float* __restrict__ out, int n) {
    constexpr int TPN = WD / 4;
    constexpr int NPB = 256 / TPN;
    int t = threadIdx.x;
    int q = t % TPN, ln = t / TPN;
    int node = blockIdx.x * NPB + ln;
    if (node >= n) return;
    const float4* hp = (const float4*)h;
    float di = dis[node], d2 = di * di;
    float4 v = hp[(size_t)node * TPN + q];
    float4 acc;
    acc.x = d2 * v.x; acc.y = d2 * v.y; acc.z = d2 * v.z; acc.w = d2 * v.w;
    acc = edge_loop<TPN, false>(hp, ew, off[node], off[node + 1], q, acc);
    float4 bb = ((const float4*)b)[q];
    float4 o;
    o.x = acc.x + bb.x; o.y = acc.y + bb.y; o.z = acc.z + bb.z; o.w = acc.w + bb.w;
    ((float4*)out)[(size_t)node * TPN + q] = o;
}

// Mean-pool h2[n,32] per graph (equal sizes npg) -> Z[G,32]
__global__ __launch_bounds__(256)
void pool_kernel(const float* __restrict__ h2, const int* __restrict__ npg_p,
                 float* __restrict__ Z, int n) {
    int npg = npg_p[0];
    int G = n / npg;
    if (G > 4096) G = 4096;
    __shared__ float red[256];
    for (int g = blockIdx.x; g < G; g += gridDim.x) {
        int j = threadIdx.x & 31;
        int r0 = threadIdx.x >> 5;
        float acc = 0.f;
        for (int r = r0; r < npg; r += 8)
            acc += h2[((size_t)g * npg + r) * 32 + j];
        red[threadIdx.x] = acc;
        __syncthreads();
        if (threadIdx.x < 32) {
            float s = 0.f;
#pragma unroll
            for (int q = 0; q < 8; ++q) s += red[q * 32 + threadIdx.x];
            Z[g * 32 + threadIdx.x] = s / (float)npg;
        }
        __syncthreads();
    }
}

// Decoder fused: aggregate 32-wide z rows from global (Z L1-resident, row =
// ew.x>>20 broadcast via shfl); then per block: (@W3+b3) relu (@W4) -> t4.
__global__ __launch_bounds__(256)
void dec1v2_kernel(const float* __restrict__ Z, const float* __restrict__ dis,
                   const int* __restrict__ off, const int2* __restrict__ ew,
                   const int* __restrict__ npg_p, const float* __restrict__ W3,
                   const float* __restrict__ b3, const float* __restrict__ W4,
                   float* __restrict__ t4, int n) {
    __shared__ float W3l[32 * 64];
    __shared__ float W4l[64 * 16];
    __shared__ float zacc[32 * 33];
    __shared__ float hl[32 * 65];
    int t = threadIdx.x;
    for (int i = t; i < 32 * 64; i += 256) W3l[i] = W3[i];
    for (int i = t; i < 64 * 16; i += 256) W4l[i] = W4[i];

    int npg = npg_p[0];
    float inv = 1.0f / (float)npg;
    int q = t & 7, ln = t >> 3;          // 8 lanes/node, 32 nodes/block
    int base = blockIdx.x * 32;
    int node = base + ln;
    const float4* zp = (const float4*)Z;

    float4 acc = make_float4(0.f, 0.f, 0.f, 0.f);
    if (node < n) {
        float di = dis[node], d2 = di * di;
        int gi = gdiv(node, npg, inv);
        float4 v = zp[(size_t)gi * 8 + q];
        acc.x = d2 * v.x; acc.y = d2 * v.y; acc.z = d2 * v.z; acc.w = d2 * v.w;
        acc = edge_loop<8, true>(zp, ew, off[node], off[node + 1], q, acc);
    }
    zacc[ln * 33 + q * 4 + 0] = acc.x;
    zacc[ln * 33 + q * 4 + 1] = acc.y;
    zacc[ln * 33 + q * 4 + 2] = acc.z;
    zacc[ln * 33 + q * 4 + 3] = acc.w;
    __syncthreads();

    // Phase B1: h[ln][j] = relu(b3[j] + zacc[ln][:] . W3[:,j])
    for (int o = t; o < 32 * 64; o += 256) {
        int l2 = o >> 6, j = o & 63;
        if (base + l2 < n) {
            float s = b3[j];
#pragma unroll
            for (int k = 0; k < 32; ++k) s += zacc[l2 * 33 + k] * W3l[k * 64 + j];
            hl[l2 * 65 + j] = fmaxf(s, 0.f);
        }
    }
    __syncthreads();

    // Phase B2: t4[node][c] = hl[ln][:] . W4[:,c]
    for (int o = t; o < 32 * 16; o += 256) {
        int l2 = o >> 4, c = o & 15;
        int nd = base + l2;
        if (nd < n) {
            float s = 0.f;
#pragma unroll
            for (int j = 0; j < 64; ++j) s += hl[l2 * 65 + j] * W4l[j * 16 + c];
            t4[(size_t)nd * 16 + c] = s;
        }
    }
}

extern "C" void kernel_launch(void* const* d_in, const int* in_sizes, int n_in,
                              void* d_out, int out_size, void* d_ws, size_t ws_size,
                              hipStream_t stream) {
    const float* x     = (const float*)d_in[0];
    const int*   ei    = (const int*)d_in[1];
    const int*   npg   = (const int*)d_in[3];
    const float* W1 = (const float*)d_in[4];
    const float* b1 = (const float*)d_in[5];
    const float* W2 = (const float*)d_in[6];
    const float* b2 = (const float*)d_in[7];
    const float* W3 = (const float*)d_in[8];
    const float* b3 = (const float*)d_in[9];
    const float* W4 = (const float*)d_in[10];
    const float* b4 = (const float*)d_in[11];
    float* out = (float*)d_out;

    int n = in_sizes[0] / 16;
    int E = in_sizes[1] / 2;
    const int* srcp = ei;
    const int* dstp = ei + E;

    char* w = (char*)d_ws;
    auto alloc = [&](size_t bytes) {
        char* p = w;
        w += (bytes + 255) & ~(size_t)255;
        return p;
    };
    float* dis    = (float*)alloc((size_t)n * 4);
    int*   off    = (int*)alloc(((size_t)n + 1) * 4);
    int*   binned = (int*)alloc((size_t)NBMAX * BCAP * 4);
    int2*  ew     = (int2*)alloc((size_t)E * 8);
    float* A      = (float*)alloc((size_t)n * 64 * 4);  // h1
    float* B      = (float*)alloc((size_t)n * 32 * 4);  // t2, later t4
    float* C      = (float*)alloc((size_t)n * 32 * 4);  // h2
    float* Z      = (float*)alloc((size_t)4096 * 32 * 4);
    int*   bcnt   = (int*)alloc((size_t)NBMAX * 4);
    int*   bstart = (int*)alloc((size_t)(NBMAX + 1) * 4);

    int nbuck = (n + BSZ - 1) / BSZ;
    int nbin  = (E + ECHUNK - 1) / ECHUNK;

    // ---- CSR build (no count pass) ----
    hipMemsetAsync(bcnt, 0, (size_t)NBMAX * 4, stream);
    binfill_kernel<<<nbin, 256, 0, stream>>>(srcp, dstp, bcnt, binned, E);
    bstart_scan_kernel<<<1, 256, 0, stream>>>(bcnt, bstart, off, n, nbuck, E);
    csr_off_kernel<<<nbuck, 256, 0, stream>>>(binned, bcnt, bstart, off, dis, n);
    bucket_scatter_kernel<<<nbuck, 256, 0, stream>>>(binned, bcnt, bstart, dis, npg, ew, n);

    // encode
    l1_kernel<<<(n + 63) / 64, 256, 0, stream>>>(x, dis, off, ew, W1, b1, A, n);
    transform_kernel<64, 32><<<(n + 7) / 8, 256, 0, stream>>>(A, W2, B, n);
    agg_kernel<32><<<(n + 31) / 32, 256, 0, stream>>>(B, dis, off, ew, b2, C, n);
    pool_kernel<<<256, 256, 0, stream>>>(C, npg, Z, n);

    // decode
    dec1v2_kernel<<<(n + 31) / 32, 256, 0, stream>>>(Z, dis, off, ew, npg, W3, b3, W4, B, n);
    agg_kernel<16><<<(n + 63) / 64, 256, 0, stream>>>(B, dis, off, ew, b4, out, n);
}

// Round 10
// 263.091 us; speedup vs baseline: 2.6680x; 1.0125x over previous
//
#include <hip/hip_runtime.h>
#include <hip/hip_bf16.h>

// ---------------------------------------------------------------------------
// GraphAutoEncoder: 4x GCNConv + mean-pool + repeat, all f32.
// R1: hierarchical scan. R2: int2 payload, vector-per-node gathers.
// R3: binned CSR fill. R4: dec1 fused via ZW3 table. R5: count pass gone.
// R6: g packed in ew.x; W4 fused into dec1. R7: dec1 gathers z from global.
// R8: shfl-broadcast edge loops (coalesced ew reads, no per-lane redundancy).
// R9: dec1v3 drops W3/W4 LDS staging (weights read from global, L1-hot,
//     coalesced/broadcast) -> LDS 25->12.5KB, occupancy cap 100%; W2 fused
//     into l1 phase-C (transform kernel deleted, h1 never hits global);
//     bstart_scan launch deleted (blocks self-reduce bcnt prefix).
// ---------------------------------------------------------------------------

constexpr int BSZ_LOG = 9;                 // bucket = 512 dst nodes
constexpr int BSZ     = 1 << BSZ_LOG;
constexpr int NBMAX   = 256;               // max buckets (n <= 128K)
constexpr int ECHUNK  = 8192;              // edges per binfill block
constexpr int BCAP    = 12288;             // staging capacity per bucket

__device__ __forceinline__ int gdiv(int v, int npg, float inv) {
    int g = __float2int_rz((float)v * inv);
    int r = v - g * npg;
    if (r < 0) --g; else if (r >= npg) ++g;
    return g;
}

// Pass 1: LDS-binned bucket staging. code = (dst_local << 20) | src (src < 2^20).
__global__ __launch_bounds__(256)
void binfill_kernel(const int* __restrict__ src, const int* __restrict__ dst,
                    int* __restrict__ bcnt, int* __restrict__ binned, int E) {
    __shared__ int hist[NBMAX], hexcl[NBMAX], gbase[NBMAX], hpos[NBMAX], tmp[NBMAX];
    __shared__ int sorted[ECHUNK];
    __shared__ unsigned char bsorted[ECHUNK];
    int t = threadIdx.x;
    hist[t] = 0; hpos[t] = 0;
    __syncthreads();
    int e0 = blockIdx.x * ECHUNK;
    int cnt = min(ECHUNK, E - e0);
    for (int i = t; i < cnt; i += 256)
        atomicAdd(&hist[dst[e0 + i] >> BSZ_LOG], 1);
    __syncthreads();
    tmp[t] = hist[t];
    __syncthreads();
    for (int d = 1; d < 256; d <<= 1) {
        int v = (t >= d) ? tmp[t - d] : 0;
        __syncthreads();
        tmp[t] += v;
        __syncthreads();
    }
    hexcl[t] = (t == 0) ? 0 : tmp[t - 1];
    int h = hist[t];
    gbase[t] = (h > 0) ? atomicAdd(&bcnt[t], h) : 0;
    __syncthreads();
    for (int i = t; i < cnt; i += 256) {
        int s = src[e0 + i], d = dst[e0 + i];
        int b = d >> BSZ_LOG;
        int code = ((d & (BSZ - 1)) << 20) | s;
        int sp = hexcl[b] + atomicAdd(&hpos[b], 1);
        sorted[sp] = code;
        bsorted[sp] = (unsigned char)b;
    }
    __syncthreads();
    for (int i = t; i < cnt; i += 256) {
        int b = bsorted[i];
        binned[(size_t)b * BCAP + gbase[b] + (i - hexcl[b])] = sorted[i];
    }
}

// Block-reduce sum of bcnt[0..b) -> returned in sums[0] (all threads see it).
__device__ __forceinline__ int prefix_before(const int* __restrict__ bcnt,
                                             int b, int* sums) {
    int t = threadIdx.x;
    sums[t] = (t < b) ? bcnt[t] : 0;
    __syncthreads();
    for (int d = 128; d > 0; d >>= 1) {
        if (t < d) sums[t] += sums[t + d];
        __syncthreads();
    }
    int r = sums[0];
    __syncthreads();
    return r;
}

// Per bucket: LDS node histogram + scan -> coalesced off[] and dis[] writes.
__global__ __launch_bounds__(256)
void csr_off_kernel(const int* __restrict__ binned, const int* __restrict__ bcnt,
                    int* __restrict__ off, float* __restrict__ dis, int n, int E) {
    __shared__ int hist[BSZ];
    __shared__ int lstart[BSZ];
    __shared__ int partial[256];
    int b = blockIdx.x, t = threadIdx.x;
    int nb0 = b << BSZ_LOG;
    int nn = min(BSZ, n - nb0);
    int m = bcnt[b];
    int bs = prefix_before(bcnt, b, partial);
    const int* bp = binned + (size_t)b * BCAP;
    for (int i = t; i < BSZ; i += 256) hist[i] = 0;
    __syncthreads();
    for (int i = t; i < m; i += 256)
        atomicAdd(&hist[bp[i] >> 20], 1);
    __syncthreads();
    int a0 = hist[2 * t], a1 = hist[2 * t + 1];
    partial[t] = a0 + a1;
    __syncthreads();
    for (int d = 1; d < 256; d <<= 1) {
        int v = (t >= d) ? partial[t - d] : 0;
        __syncthreads();
        partial[t] += v;
        __syncthreads();
    }
    int base = (t == 0) ? 0 : partial[t - 1];
    lstart[2 * t] = base;
    lstart[2 * t + 1] = base + a0;
    __syncthreads();
    for (int i = t; i < nn; i += 256) {
        off[nb0 + i] = bs + lstart[i];
        dis[nb0 + i] = rsqrtf((float)hist[i] + 1.0f);   // +1 = self-loop
    }
    if (b == 0 && t == 0) off[n] = E;
}

// Per bucket: scatter {src | g<<20, w} to exact CSR positions (L2-local window).
__global__ __launch_bounds__(256)
void bucket_scatter_kernel(const int* __restrict__ binned, const int* __restrict__ bcnt,
                           const float* __restrict__ dis,
                           const int* __restrict__ npg_p, int2* __restrict__ ew, int n) {
    __shared__ int lstart[BSZ];
    __shared__ int lpos[BSZ];
    __shared__ float ldis[BSZ];
    __shared__ int partial[256];
    int b = blockIdx.x, t = threadIdx.x;
    int nb0 = b << BSZ_LOG;
    int nn = min(BSZ, n - nb0);
    int m = bcnt[b];
    int e0 = prefix_before(bcnt, b, partial);
    int npg = npg_p[0];
    float inv = 1.0f / (float)npg;
    const int* bp = binned + (size_t)b * BCAP;
    for (int i = t; i < BSZ; i += 256) {
        lstart[i] = 0; lpos[i] = 0;
        ldis[i] = (i < nn) ? dis[nb0 + i] : 0.f;
    }
    __syncthreads();
    for (int i = t; i < m; i += 256)
        atomicAdd(&lstart[bp[i] >> 20], 1);
    __syncthreads();
    int a0 = lstart[2 * t], a1 = lstart[2 * t + 1];
    partial[t] = a0 + a1;
    __syncthreads();
    for (int d = 1; d < 256; d <<= 1) {
        int v = (t >= d) ? partial[t - d] : 0;
        __syncthreads();
        partial[t] += v;
        __syncthreads();
    }
    int base = (t == 0) ? 0 : partial[t - 1];
    lstart[2 * t] = base;
    lstart[2 * t + 1] = base + a0;
    __syncthreads();
    for (int i = t; i < m; i += 256) {
        int code = bp[i];
        int dl = code >> 20, s = code & 0xFFFFF;
        float w = dis[s] * ldis[dl];
        int g = gdiv(s, npg, inv);
        int p = e0 + lstart[dl] + atomicAdd(&lpos[dl], 1);
        ew[p] = make_int2(s | (g << 20), __float_as_int(w));
    }
}

// ---- shfl-broadcast edge-gather core (TPN lanes per node) -----------------
template <int TPN, bool USE_G>
__device__ __forceinline__ float4
edge_loop(const float4* __restrict__ hp, const int2* __restrict__ ew,
          int e0, int e1, int q, float4 acc) {
    int deg = e1 - e0;
    int nfull = deg / TPN;
    int r = deg - nfull * TPN;
    int idx = e0 + q;
    int2 a = make_int2(0, 0);
    if (idx < e1) a = ew[idx];
    for (int c = 0; c < nfull; ++c) {
        int nidx = idx + (c + 1) * TPN;
        int2 an = make_int2(0, 0);
        if (nidx < e1) an = ew[nidx];
#pragma unroll
        for (int k = 0; k < TPN; ++k) {
            int ax = __shfl(a.x, k, TPN);
            float w = __int_as_float(__shfl(a.y, k, TPN));
            int row = USE_G ? (int)(((unsigned)ax) >> 20) : (ax & 0xFFFFF);
            float4 v = hp[(size_t)row * TPN + q];
            acc.x += w * v.x; acc.y += w * v.y; acc.z += w * v.z; acc.w += w * v.w;
        }
        a = an;
    }
    for (int k = 0; k < r; ++k) {
        int ax = __shfl(a.x, k, TPN);
        float w = __int_as_float(__shfl(a.y, k, TPN));
        int row = USE_G ? (int)(((unsigned)ax) >> 20) : (ax & 0xFFFFF);
        float4 v = hp[(size_t)row * TPN + q];
        acc.x += w * v.x; acc.y += w * v.y; acc.z += w * v.z; acc.w += w * v.w;
    }
    return acc;
}

// Layer 1 + W2 fused: agg x (16-wide, 4 lanes/node); phase-B h1=relu(.@W1+b1)
// into LDS; phase-C t2 = h1@W2 written straight to global. h1 never leaves CU.
__global__ __launch_bounds__(256)
void l1w2_kernel(const float* __restrict__ x, const float* __restrict__ dis,
                 const int* __restrict__ off, const int2* __restrict__ ew,
                 const float* __restrict__ W1, const float* __restrict__ b1,
                 const float* __restrict__ W2, float* __restrict__ t2, int n) {
    __shared__ float accs[64][17];
    __shared__ float hl[64][65];
    __shared__ float Wl[16 * 64];
    __shared__ float bl[64];
    int t = threadIdx.x;
    for (int i = t; i < 16 * 64; i += 256) Wl[i] = W1[i];
    if (t < 64) bl[t] = b1[t];

    int q = t & 3, ln = t >> 2;
    int node = blockIdx.x * 64 + ln;
    const float4* xp = (const float4*)x;
    float4 acc = make_float4(0.f, 0.f, 0.f, 0.f);
    if (node < n) {
        float di = dis[node], d2 = di * di;
        float4 v = xp[(size_t)node * 4 + q];
        acc.x = d2 * v.x; acc.y = d2 * v.y; acc.z = d2 * v.z; acc.w = d2 * v.w;
        acc = edge_loop<4, false>(xp, ew, off[node], off[node + 1], q, acc);
    }
    accs[ln][q * 4 + 0] = acc.x; accs[ln][q * 4 + 1] = acc.y;
    accs[ln][q * 4 + 2] = acc.z; accs[ln][q * 4 + 3] = acc.w;
    __syncthreads();

    // Phase B: h1 row (64-wide) into LDS
    int j = t & 63;
    for (int nb = (t >> 6); nb < 64; nb += 4) {
        float s = bl[j];
#pragma unroll
        for (int k = 0; k < 16; ++k) s += accs[nb][k] * Wl[k * 64 + j];
        hl[nb][j] = fmaxf(s, 0.f);
    }
    __syncthreads();

    // Phase C: t2[node][c] = h1 . W2[:,c]  (W2 read from global, L1-hot)
    int base = blockIdx.x * 64;
    int c = t & 31;
    for (int nb = (t >> 5); nb < 64; nb += 8) {
        int nd = base + nb;
        if (nd >= n) break;
        float s = 0.f;
#pragma unroll
        for (int k = 0; k < 64; ++k) s += hl[nb][k] * W2[k * 32 + c];
        t2[(size_t)nd * 32 + c] = s;
    }
}

// Aggregate WD-wide features through CSR; WD/4 lanes per node.
template <int WD>
__global__ __launch_bounds__(256)
void agg_kernel(const float* __restrict__ h, const float* __restrict__ dis,
                const int* __restrict__ off, const int2* __restrict__ ew,
                const float* __restrict__ b, float* __restrict__ out, int n) {
    constexpr int TPN = WD / 4;
    constexpr int NPB = 256 / TPN;
    int t = threadIdx.x;
    int q = t % TPN, ln = t / TPN;
    int node = blockIdx.x * NPB + ln;
    if (node >= n) return;
    const float4* hp = (const float4*)h;
    float di = dis[node], d2 = di * di;
    float4 v = hp[(size_t)node * TPN + q];
    float4 acc;
    acc.x = d2 * v.x; acc.y = d2 * v.y; acc.z = d2 * v.z; acc.w = d2 * v.w;
    acc = edge_loop<TPN, false>(hp, ew, off[node], off[node + 1], q, acc);
    float4 bb = ((const float4*)b)[q];
    float4 o;
    o.x = acc.x + bb.x; o.y = acc.y + bb.y; o.z = acc.z + bb.z; o.w = acc.w + bb.w;
    ((float4*)out)[(size_t)node * TPN + q] = o;
}

// Mean-pool h2[n,32] per graph (equal sizes npg) -> Z[G,32]
__global__ __launch_bounds__(256)
void pool_kernel(const float* __restrict__ h2, const int* __restrict__ npg_p,
                 float* __restrict__ Z, int n) {
    int npg = npg_p[0];
    int G = n / npg;
    if (G > 4096) G = 4096;
    __shared__ float red[256];
    for (int g = blockIdx.x; g < G; g += gridDim.x) {
        int j = threadIdx.x & 31;
        int r0 = threadIdx.x >> 5;
        float acc = 0.f;
        for (int r = r0; r < npg; r += 8)
            acc += h2[((size_t)g * npg + r) * 32 + j];
        red[threadIdx.x] = acc;
        __syncthreads();
        if (threadIdx.x < 32) {
            float s = 0.f;
#pragma unroll
            for (int q = 0; q < 8; ++q) s += red[q * 32 + threadIdx.x];
            Z[g * 32 + threadIdx.x] = s / (float)npg;
        }
        __syncthreads();
    }
}

// Decoder fused: aggregate 32-wide z rows from global (Z L1-resident); dense
// (@W3+b3) relu (@W4) with W3/W4/b3 read from GLOBAL (L1-hot, coalesced) --
// no weight staging, LDS 12.5KB -> full occupancy.
__global__ __launch_bounds__(256)
void dec1v3_kernel(const float* __restrict__ Z, const float* __restrict__ dis,
                   const int* __restrict__ off, const int2* __restrict__ ew,
                   const int* __restrict__ npg_p, const float* __restrict__ W3,
                   const float* __restrict__ b3, const float* __restrict__ W4,
                   float* __restrict__ t4, int n) {
    __shared__ float zacc[32 * 33];
    __shared__ float hl[32 * 65];
    int t = threadIdx.x;
    int npg = npg_p[0];
    float inv = 1.0f / (float)npg;
    int q = t & 7, ln = t >> 3;          // 8 lanes/node, 32 nodes/block
    int base = blockIdx.x * 32;
    int node = base + ln;
    const float4* zp = (const float4*)Z;

    float4 acc = make_float4(0.f, 0.f, 0.f, 0.f);
    if (node < n) {
        float di = dis[node], d2 = di * di;
        int gi = gdiv(node, npg, inv);
        float4 v = zp[(size_t)gi * 8 + q];
        acc.x = d2 * v.x; acc.y = d2 * v.y; acc.z = d2 * v.z; acc.w = d2 * v.w;
        acc = edge_loop<8, true>(zp, ew, off[node], off[node + 1], q, acc);
    }
    zacc[ln * 33 + q * 4 + 0] = acc.x;
    zacc[ln * 33 + q * 4 + 1] = acc.y;
    zacc[ln * 33 + q * 4 + 2] = acc.z;
    zacc[ln * 33 + q * 4 + 3] = acc.w;
    __syncthreads();

    // Phase B1: h[ln][j] = relu(b3[j] + zacc[ln][:] . W3[:,j])
    for (int o = t; o < 32 * 64; o += 256) {
        int l2 = o >> 6, j = o & 63;
        if (base + l2 < n) {
            float s = b3[j];
#pragma unroll
            for (int k = 0; k < 32; ++k) s += zacc[l2 * 33 + k] * W3[k * 64 + j];
            hl[l2 * 65 + j] = fmaxf(s, 0.f);
        }
    }
    __syncthreads();

    // Phase B2: t4[node][c] = hl[ln][:] . W4[:,c]
    for (int o = t; o < 32 * 16; o += 256) {
        int l2 = o >> 4, c = o & 15;
        int nd = base + l2;
        if (nd < n) {
            float s = 0.f;
#pragma unroll
            for (int j = 0; j < 64; ++j) s += hl[l2 * 65 + j] * W4[j * 16 + c];
            t4[(size_t)nd * 16 + c] = s;
        }
    }
}

extern "C" void kernel_launch(void* const* d_in, const int* in_sizes, int n_in,
                              void* d_out, int out_size, void* d_ws, size_t ws_size,
                              hipStream_t stream) {
    const float* x     = (const float*)d_in[0];
    const int*   ei    = (const int*)d_in[1];
    const int*   npg   = (const int*)d_in[3];
    const float* W1 = (const float*)d_in[4];
    const float* b1 = (const float*)d_in[5];
    const float* W2 = (const float*)d_in[6];
    const float* b2 = (const float*)d_in[7];
    const float* W3 = (const float*)d_in[8];
    const float* b3 = (const float*)d_in[9];
    const float* W4 = (const float*)d_in[10];
    const float* b4 = (const float*)d_in[11];
    float* out = (float*)d_out;

    int n = in_sizes[0] / 16;
    int E = in_sizes[1] / 2;
    const int* srcp = ei;
    const int* dstp = ei + E;

    char* w = (char*)d_ws;
    auto alloc = [&](size_t bytes) {
        char* p = w;
        w += (bytes + 255) & ~(size_t)255;
        return p;
    };
    float* dis    = (float*)alloc((size_t)n * 4);
    int*   off    = (int*)alloc(((size_t)n + 1) * 4);
    int*   binned = (int*)alloc((size_t)NBMAX * BCAP * 4);
    int2*  ew     = (int2*)alloc((size_t)E * 8);
    float* B      = (float*)alloc((size_t)n * 32 * 4);  // t2, later t4
    float* C      = (float*)alloc((size_t)n * 32 * 4);  // h2
    float* Z      = (float*)alloc((size_t)4096 * 32 * 4);
    int*   bcnt   = (int*)alloc((size_t)NBMAX * 4);

    int nbuck = (n + BSZ - 1) / BSZ;
    int nbin  = (E + ECHUNK - 1) / ECHUNK;

    // ---- CSR build ----
    hipMemsetAsync(bcnt, 0, (size_t)NBMAX * 4, stream);
    binfill_kernel<<<nbin, 256, 0, stream>>>(srcp, dstp, bcnt, binned, E);
    csr_off_kernel<<<nbuck, 256, 0, stream>>>(binned, bcnt, off, dis, n, E);
    bucket_scatter_kernel<<<nbuck, 256, 0, stream>>>(binned, bcnt, dis, npg, ew, n);

    // encode
    l1w2_kernel<<<(n + 63) / 64, 256, 0, stream>>>(x, dis, off, ew, W1, b1, W2, B, n);
    agg_kernel<32><<<(n + 31) / 32, 256, 0, stream>>>(B, dis, off, ew, b2, C, n);
    pool_kernel<<<256, 256, 0, stream>>>(C, npg, Z, n);

    // decode
    dec1v3_kernel<<<(n + 31) / 32, 256, 0, stream>>>(Z, dis, off, ew, npg, W3, b3, W4, B, n);
    agg_kernel<16><<<(n + 63) / 64, 256, 0, stream>>>(B, dis, off, ew, b4, out, n);
}

// Round 11
// 236.275 us; speedup vs baseline: 2.9708x; 1.1135x over previous
//
#include <hip/hip_runtime.h>
#include <hip/hip_bf16.h>

// ---------------------------------------------------------------------------
// GraphAutoEncoder: 4x GCNConv + mean-pool + repeat, all f32.
// R1: hierarchical scan. R2: int2 payload, vector-per-node gathers.
// R3: binned CSR fill. R4: dec1 fused via ZW3 table. R5: count pass gone.
// R6: g packed in ew.x; W4 fused into dec1. R7: dec1 gathers z from global.
// R8: shfl-broadcast edge loops. R9: weights from global (L1), W2 fused in l1,
//     bstart_scan launch deleted.
// R10: pooling is linear -> h2/pool DELETED. zagg_kernel accumulates
//      z-sums per dst-bucket edge-major (bucket spans <=2 graphs; edge's
//      graph decided by CSR position vs one boundary), dual register
//      accumulators, block reduce, 64 global atomics/block. agg32's n x 32
//      write + pool's n x 32 read never happen.
// ---------------------------------------------------------------------------

constexpr int BSZ_LOG = 9;                 // bucket = 512 dst nodes
constexpr int BSZ     = 1 << BSZ_LOG;
constexpr int NBMAX   = 256;               // max buckets (n <= 128K)
constexpr int ECHUNK  = 8192;              // edges per binfill block
constexpr int BCAP    = 12288;             // staging capacity per bucket
constexpr int ZSPLIT  = 8;                 // sub-blocks per bucket in zagg

__device__ __forceinline__ int gdiv(int v, int npg, float inv) {
    int g = __float2int_rz((float)v * inv);
    int r = v - g * npg;
    if (r < 0) --g; else if (r >= npg) ++g;
    return g;
}

// Pass 1: LDS-binned bucket staging. code = (dst_local << 20) | src (src < 2^20).
__global__ __launch_bounds__(256)
void binfill_kernel(const int* __restrict__ src, const int* __restrict__ dst,
                    int* __restrict__ bcnt, int* __restrict__ binned, int E) {
    __shared__ int hist[NBMAX], hexcl[NBMAX], gbase[NBMAX], hpos[NBMAX], tmp[NBMAX];
    __shared__ int sorted[ECHUNK];
    __shared__ unsigned char bsorted[ECHUNK];
    int t = threadIdx.x;
    hist[t] = 0; hpos[t] = 0;
    __syncthreads();
    int e0 = blockIdx.x * ECHUNK;
    int cnt = min(ECHUNK, E - e0);
    for (int i = t; i < cnt; i += 256)
        atomicAdd(&hist[dst[e0 + i] >> BSZ_LOG], 1);
    __syncthreads();
    tmp[t] = hist[t];
    __syncthreads();
    for (int d = 1; d < 256; d <<= 1) {
        int v = (t >= d) ? tmp[t - d] : 0;
        __syncthreads();
        tmp[t] += v;
        __syncthreads();
    }
    hexcl[t] = (t == 0) ? 0 : tmp[t - 1];
    int h = hist[t];
    gbase[t] = (h > 0) ? atomicAdd(&bcnt[t], h) : 0;
    __syncthreads();
    for (int i = t; i < cnt; i += 256) {
        int s = src[e0 + i], d = dst[e0 + i];
        int b = d >> BSZ_LOG;
        int code = ((d & (BSZ - 1)) << 20) | s;
        int sp = hexcl[b] + atomicAdd(&hpos[b], 1);
        sorted[sp] = code;
        bsorted[sp] = (unsigned char)b;
    }
    __syncthreads();
    for (int i = t; i < cnt; i += 256) {
        int b = bsorted[i];
        binned[(size_t)b * BCAP + gbase[b] + (i - hexcl[b])] = sorted[i];
    }
}

// Block-reduce sum of bcnt[0..b) -> returned in sums[0] (all threads see it).
__device__ __forceinline__ int prefix_before(const int* __restrict__ bcnt,
                                             int b, int* sums) {
    int t = threadIdx.x;
    sums[t] = (t < b) ? bcnt[t] : 0;
    __syncthreads();
    for (int d = 128; d > 0; d >>= 1) {
        if (t < d) sums[t] += sums[t + d];
        __syncthreads();
    }
    int r = sums[0];
    __syncthreads();
    return r;
}

// Per bucket: LDS node histogram + scan -> coalesced off[] and dis[] writes.
__global__ __launch_bounds__(256)
void csr_off_kernel(const int* __restrict__ binned, const int* __restrict__ bcnt,
                    int* __restrict__ off, float* __restrict__ dis, int n, int E) {
    __shared__ int hist[BSZ];
    __shared__ int lstart[BSZ];
    __shared__ int partial[256];
    int b = blockIdx.x, t = threadIdx.x;
    int nb0 = b << BSZ_LOG;
    int nn = min(BSZ, n - nb0);
    int m = bcnt[b];
    int bs = prefix_before(bcnt, b, partial);
    const int* bp = binned + (size_t)b * BCAP;
    for (int i = t; i < BSZ; i += 256) hist[i] = 0;
    __syncthreads();
    for (int i = t; i < m; i += 256)
        atomicAdd(&hist[bp[i] >> 20], 1);
    __syncthreads();
    int a0 = hist[2 * t], a1 = hist[2 * t + 1];
    partial[t] = a0 + a1;
    __syncthreads();
    for (int d = 1; d < 256; d <<= 1) {
        int v = (t >= d) ? partial[t - d] : 0;
        __syncthreads();
        partial[t] += v;
        __syncthreads();
    }
    int base = (t == 0) ? 0 : partial[t - 1];
    lstart[2 * t] = base;
    lstart[2 * t + 1] = base + a0;
    __syncthreads();
    for (int i = t; i < nn; i += 256) {
        off[nb0 + i] = bs + lstart[i];
        dis[nb0 + i] = rsqrtf((float)hist[i] + 1.0f);   // +1 = self-loop
    }
    if (b == 0 && t == 0) off[n] = E;
}

// Per bucket: scatter {src | g<<20, w} to exact CSR positions (L2-local window).
__global__ __launch_bounds__(256)
void bucket_scatter_kernel(const int* __restrict__ binned, const int* __restrict__ bcnt,
                           const float* __restrict__ dis,
                           const int* __restrict__ npg_p, int2* __restrict__ ew, int n) {
    __shared__ int lstart[BSZ];
    __shared__ int lpos[BSZ];
    __shared__ float ldis[BSZ];
    __shared__ int partial[256];
    int b = blockIdx.x, t = threadIdx.x;
    int nb0 = b << BSZ_LOG;
    int nn = min(BSZ, n - nb0);
    int m = bcnt[b];
    int e0 = prefix_before(bcnt, b, partial);
    int npg = npg_p[0];
    float inv = 1.0f / (float)npg;
    const int* bp = binned + (size_t)b * BCAP;
    for (int i = t; i < BSZ; i += 256) {
        lstart[i] = 0; lpos[i] = 0;
        ldis[i] = (i < nn) ? dis[nb0 + i] : 0.f;
    }
    __syncthreads();
    for (int i = t; i < m; i += 256)
        atomicAdd(&lstart[bp[i] >> 20], 1);
    __syncthreads();
    int a0 = lstart[2 * t], a1 = lstart[2 * t + 1];
    partial[t] = a0 + a1;
    __syncthreads();
    for (int d = 1; d < 256; d <<= 1) {
        int v = (t >= d) ? partial[t - d] : 0;
        __syncthreads();
        partial[t] += v;
        __syncthreads();
    }
    int base = (t == 0) ? 0 : partial[t - 1];
    lstart[2 * t] = base;
    lstart[2 * t + 1] = base + a0;
    __syncthreads();
    for (int i = t; i < m; i += 256) {
        int code = bp[i];
        int dl = code >> 20, s = code & 0xFFFFF;
        float w = dis[s] * ldis[dl];
        int g = gdiv(s, npg, inv);
        int p = e0 + lstart[dl] + atomicAdd(&lpos[dl], 1);
        ew[p] = make_int2(s | (g << 20), __float_as_int(w));
    }
}

// ---- shfl-broadcast edge-gather core (TPN lanes per node) -----------------
template <int TPN, bool USE_G>
__device__ __forceinline__ float4
edge_loop(const float4* __restrict__ hp, const int2* __restrict__ ew,
          int e0, int e1, int q, float4 acc) {
    int deg = e1 - e0;
    int nfull = deg / TPN;
    int r = deg - nfull * TPN;
    int idx = e0 + q;
    int2 a = make_int2(0, 0);
    if (idx < e1) a = ew[idx];
    for (int c = 0; c < nfull; ++c) {
        int nidx = idx + (c + 1) * TPN;
        int2 an = make_int2(0, 0);
        if (nidx < e1) an = ew[nidx];
#pragma unroll
        for (int k = 0; k < TPN; ++k) {
            int ax = __shfl(a.x, k, TPN);
            float w = __int_as_float(__shfl(a.y, k, TPN));
            int row = USE_G ? (int)(((unsigned)ax) >> 20) : (ax & 0xFFFFF);
            float4 v = hp[(size_t)row * TPN + q];
            acc.x += w * v.x; acc.y += w * v.y; acc.z += w * v.z; acc.w += w * v.w;
        }
        a = an;
    }
    for (int k = 0; k < r; ++k) {
        int ax = __shfl(a.x, k, TPN);
        float w = __int_as_float(__shfl(a.y, k, TPN));
        int row = USE_G ? (int)(((unsigned)ax) >> 20) : (ax & 0xFFFFF);
        float4 v = hp[(size_t)row * TPN + q];
        acc.x += w * v.x; acc.y += w * v.y; acc.z += w * v.z; acc.w += w * v.w;
    }
    return acc;
}

// Layer 1 + W2 fused: agg x (16-wide, 4 lanes/node); phase-B h1=relu(.@W1+b1)
// into LDS; phase-C t2 = h1@W2 written straight to global.
__global__ __launch_bounds__(256)
void l1w2_kernel(const float* __restrict__ x, const float* __restrict__ dis,
                 const int* __restrict__ off, const int2* __restrict__ ew,
                 const float* __restrict__ W1, const float* __restrict__ b1,
                 const float* __restrict__ W2, float* __restrict__ t2, int n) {
    __shared__ float accs[64][17];
    __shared__ float hl[64][65];
    __shared__ float Wl[16 * 64];
    __shared__ float bl[64];
    int t = threadIdx.x;
    for (int i = t; i < 16 * 64; i += 256) Wl[i] = W1[i];
    if (t < 64) bl[t] = b1[t];

    int q = t & 3, ln = t >> 2;
    int node = blockIdx.x * 64 + ln;
    const float4* xp = (const float4*)x;
    float4 acc = make_float4(0.f, 0.f, 0.f, 0.f);
    if (node < n) {
        float di = dis[node], d2 = di * di;
        float4 v = xp[(size_t)node * 4 + q];
        acc.x = d2 * v.x; acc.y = d2 * v.y; acc.z = d2 * v.z; acc.w = d2 * v.w;
        acc = edge_loop<4, false>(xp, ew, off[node], off[node + 1], q, acc);
    }
    accs[ln][q * 4 + 0] = acc.x; accs[ln][q * 4 + 1] = acc.y;
    accs[ln][q * 4 + 2] = acc.z; accs[ln][q * 4 + 3] = acc.w;
    __syncthreads();

    // Phase B: h1 row (64-wide) into LDS
    int j = t & 63;
    for (int nb = (t >> 6); nb < 64; nb += 4) {
        float s = bl[j];
#pragma unroll
        for (int k = 0; k < 16; ++k) s += accs[nb][k] * Wl[k * 64 + j];
        hl[nb][j] = fmaxf(s, 0.f);
    }
    __syncthreads();

    // Phase C: t2[node][c] = h1 . W2[:,c]  (W2 read from global, L1-hot)
    int base = blockIdx.x * 64;
    int c = t & 31;
    for (int nb = (t >> 5); nb < 64; nb += 8) {
        int nd = base + nb;
        if (nd >= n) break;
        float s = 0.f;
#pragma unroll
        for (int k = 0; k < 64; ++k) s += hl[nb][k] * W2[k * 32 + c];
        t2[(size_t)nd * 32 + c] = s;
    }
}

// Aggregate WD-wide features through CSR; WD/4 lanes per node.
template <int WD>
__global__ __launch_bounds__(256)
void agg_kernel(const float* __restrict__ h, const float* __restrict__ dis,
                const int* __restrict__ off, const int2* __restrict__ ew,
                const float* __restrict__ b, float* __restrict__ out, int n) {
    constexpr int TPN = WD / 4;
    constexpr int NPB = 256 / TPN;
    int t = threadIdx.x;
    int q = t % TPN, ln = t / TPN;
    int node = blockIdx.x * NPB + ln;
    if (node >= n) return;
    const float4* hp = (const float4*)h;
    float di = dis[node], d2 = di * di;
    float4 v = hp[(size_t)node * TPN + q];
    float4 acc;
    acc.x = d2 * v.x; acc.y = d2 * v.y; acc.z = d2 * v.z; acc.w = d2 * v.w;
    acc = edge_loop<TPN, false>(hp, ew, off[node], off[node + 1], q, acc);
    float4 bb = ((const float4*)b)[q];
    float4 o;
    o.x = acc.x + bb.x; o.y = acc.y + bb.y; o.z = acc.z + bb.z; o.w = acc.w + bb.w;
    ((float4*)out)[(size_t)node * TPN + q] = o;
}

// zagg: per (bucket, split): accumulate z-sums edge-major. Bucket spans <= 2
// graphs (BSZ <= npg); an edge's dst-graph = (CSR pos < P) ? g0 : g0+1 where
// P = off[boundary node]. Dual register accumulators; block reduce; 64 atomics.
__global__ __launch_bounds__(256)
void zagg_kernel(const float* __restrict__ t2, const float* __restrict__ dis,
                 const int* __restrict__ off, const int2* __restrict__ ew,
                 const int* __restrict__ npg_p, float* __restrict__ zsum, int n) {
    __shared__ float4 red0[256];
    __shared__ float4 red1[256];
    int blk = blockIdx.x;
    int b = blk / ZSPLIT, s = blk % ZSPLIT;
    int t = threadIdx.x, q = t & 7, r = t >> 3;
    int npg = npg_p[0];
    int nb0 = b << BSZ_LOG;
    int nn = min(BSZ, n - nb0);
    int g0 = nb0 / npg;
    int nodeB = min((g0 + 1) * npg - nb0, nn);   // local boundary node
    int e0 = off[nb0], e1 = off[nb0 + nn];
    int P  = off[nb0 + nodeB];
    int m = e1 - e0;
    const float4* hp = (const float4*)t2;

    float4 a0 = make_float4(0.f, 0.f, 0.f, 0.f);
    float4 a1 = make_float4(0.f, 0.f, 0.f, 0.f);
    int i0 = (int)((long long)m * s / ZSPLIT);
    int i1 = (int)((long long)m * (s + 1) / ZSPLIT);
    for (int i = i0 + r; i < i1; i += 32) {
        int e = e0 + i;
        int2 aa = ew[e];
        float w = __int_as_float(aa.y);
        int src = aa.x & 0xFFFFF;
        float4 v = hp[(size_t)src * 8 + q];
        if (e < P) {
            a0.x += w * v.x; a0.y += w * v.y; a0.z += w * v.z; a0.w += w * v.w;
        } else {
            a1.x += w * v.x; a1.y += w * v.y; a1.z += w * v.z; a1.w += w * v.w;
        }
    }
    // self-loops: z[g] += dis[i]^2 * t2[i]
    int j0 = nn * s / ZSPLIT, j1 = nn * (s + 1) / ZSPLIT;
    for (int i = j0 + r; i < j1; i += 32) {
        int node = nb0 + i;
        float di = dis[node], d2 = di * di;
        float4 v = hp[(size_t)node * 8 + q];
        if (i < nodeB) {
            a0.x += d2 * v.x; a0.y += d2 * v.y; a0.z += d2 * v.z; a0.w += d2 * v.w;
        } else {
            a1.x += d2 * v.x; a1.y += d2 * v.y; a1.z += d2 * v.z; a1.w += d2 * v.w;
        }
    }
    red0[t] = a0; red1[t] = a1;
    __syncthreads();
    for (int d = 128; d >= 8; d >>= 1) {
        if (t < d) {
            float4 u = red0[t], v = red0[t + d];
            u.x += v.x; u.y += v.y; u.z += v.z; u.w += v.w;
            red0[t] = u;
            u = red1[t]; v = red1[t + d];
            u.x += v.x; u.y += v.y; u.z += v.z; u.w += v.w;
            red1[t] = u;
        }
        __syncthreads();
    }
    if (t < 8) {
        float4 v = red0[t];
        atomicAdd(&zsum[g0 * 32 + t * 4 + 0], v.x);
        atomicAdd(&zsum[g0 * 32 + t * 4 + 1], v.y);
        atomicAdd(&zsum[g0 * 32 + t * 4 + 2], v.z);
        atomicAdd(&zsum[g0 * 32 + t * 4 + 3], v.w);
    } else if (t < 16 && nodeB < nn) {
        float4 v = red1[t - 8];
        atomicAdd(&zsum[(g0 + 1) * 32 + (t - 8) * 4 + 0], v.x);
        atomicAdd(&zsum[(g0 + 1) * 32 + (t - 8) * 4 + 1], v.y);
        atomicAdd(&zsum[(g0 + 1) * 32 + (t - 8) * 4 + 2], v.z);
        atomicAdd(&zsum[(g0 + 1) * 32 + (t - 8) * 4 + 3], v.w);
    }
}

// z[g][c] = zsum[g][c]/npg + b2[c]
__global__ __launch_bounds__(256)
void zred_kernel(const float* __restrict__ zsum, const float* __restrict__ b2,
                 const int* __restrict__ npg_p, float* __restrict__ Z, int n) {
    int npg = npg_p[0];
    int G = n / npg;
    float inv = 1.0f / (float)npg;
    for (int i = blockIdx.x * 256 + threadIdx.x; i < G * 32; i += gridDim.x * 256)
        Z[i] = zsum[i] * inv + b2[i & 31];
}

// Decoder fused: aggregate 32-wide z rows from global (Z L1-resident); dense
// (@W3+b3) relu (@W4) with weights from global.
__global__ __launch_bounds__(256)
void dec1v3_kernel(const float* __restrict__ Z, const float* __restrict__ dis,
                   const int* __restrict__ off, const int2* __restrict__ ew,
                   const int* __restrict__ npg_p, const float* __restrict__ W3,
                   const float* __restrict__ b3, const float* __restrict__ W4,
                   float* __restrict__ t4, int n) {
    __shared__ float zacc[32 * 33];
    __shared__ float hl[32 * 65];
    int t = threadIdx.x;
    int npg = npg_p[0];
    float inv = 1.0f / (float)npg;
    int q = t & 7, ln = t >> 3;          // 8 lanes/node, 32 nodes/block
    int base = blockIdx.x * 32;
    int node = base + ln;
    const float4* zp = (const float4*)Z;

    float4 acc = make_float4(0.f, 0.f, 0.f, 0.f);
    if (node < n) {
        float di = dis[node], d2 = di * di;
        int gi = gdiv(node, npg, inv);
        float4 v = zp[(size_t)gi * 8 + q];
        acc.x = d2 * v.x; acc.y = d2 * v.y; acc.z = d2 * v.z; acc.w = d2 * v.w;
        acc = edge_loop<8, true>(zp, ew, off[node], off[node + 1], q, acc);
    }
    zacc[ln * 33 + q * 4 + 0] = acc.x;
    zacc[ln * 33 + q * 4 + 1] = acc.y;
    zacc[ln * 33 + q * 4 + 2] = acc.z;
    zacc[ln * 33 + q * 4 + 3] = acc.w;
    __syncthreads();

    for (int o = t; o < 32 * 64; o += 256) {
        int l2 = o >> 6, j = o & 63;
        if (base + l2 < n) {
            float s = b3[j];
#pragma unroll
            for (int k = 0; k < 32; ++k) s += zacc[l2 * 33 + k] * W3[k * 64 + j];
            hl[l2 * 65 + j] = fmaxf(s, 0.f);
        }
    }
    __syncthreads();

    for (int o = t; o < 32 * 16; o += 256) {
        int l2 = o >> 4, c = o & 15;
        int nd = base + l2;
        if (nd < n) {
            float s = 0.f;
#pragma unroll
            for (int j = 0; j < 64; ++j) s += hl[l2 * 65 + j] * W4[j * 16 + c];
            t4[(size_t)nd * 16 + c] = s;
        }
    }
}

extern "C" void kernel_launch(void* const* d_in, const int* in_sizes, int n_in,
                              void* d_out, int out_size, void* d_ws, size_t ws_size,
                              hipStream_t stream) {
    const float* x     = (const float*)d_in[0];
    const int*   ei    = (const int*)d_in[1];
    const int*   npg   = (const int*)d_in[3];
    const float* W1 = (const float*)d_in[4];
    const float* b1 = (const float*)d_in[5];
    const float* W2 = (const float*)d_in[6];
    const float* b2 = (const float*)d_in[7];
    const float* W3 = (const float*)d_in[8];
    const float* b3 = (const float*)d_in[9];
    const float* W4 = (const float*)d_in[10];
    const float* b4 = (const float*)d_in[11];
    float* out = (float*)d_out;

    int n = in_sizes[0] / 16;
    int E = in_sizes[1] / 2;
    const int* srcp = ei;
    const int* dstp = ei + E;

    char* w = (char*)d_ws;
    auto alloc = [&](size_t bytes) {
        char* p = w;
        w += (bytes + 255) & ~(size_t)255;
        return p;
    };
    float* dis    = (float*)alloc((size_t)n * 4);
    int*   off    = (int*)alloc(((size_t)n + 1) * 4);
    int*   binned = (int*)alloc((size_t)NBMAX * BCAP * 4);
    int2*  ew     = (int2*)alloc((size_t)E * 8);
    float* B      = (float*)alloc((size_t)n * 32 * 4);  // t2, later t4
    float* Z      = (float*)alloc((size_t)4096 * 32 * 4);
    float* zsum   = (float*)alloc((size_t)4096 * 32 * 4);
    int*   bcnt   = (int*)alloc((size_t)NBMAX * 4);

    int nbuck = (n + BSZ - 1) / BSZ;
    int nbin  = (E + ECHUNK - 1) / ECHUNK;

    // ---- CSR build ----
    hipMemsetAsync(bcnt, 0, (size_t)NBMAX * 4, stream);
    hipMemsetAsync(zsum, 0, (size_t)4096 * 32 * 4, stream);
    binfill_kernel<<<nbin, 256, 0, stream>>>(srcp, dstp, bcnt, binned, E);
    csr_off_kernel<<<nbuck, 256, 0, stream>>>(binned, bcnt, off, dis, n, E);
    bucket_scatter_kernel<<<nbuck, 256, 0, stream>>>(binned, bcnt, dis, npg, ew, n);

    // encode
    l1w2_kernel<<<(n + 63) / 64, 256, 0, stream>>>(x, dis, off, ew, W1, b1, W2, B, n);
    zagg_kernel<<<nbuck * ZSPLIT, 256, 0, stream>>>(B, dis, off, ew, npg, zsum, n);
    zred_kernel<<<16, 256, 0, stream>>>(zsum, b2, npg, Z, n);

    // decode
    dec1v3_kernel<<<(n + 31) / 32, 256, 0, stream>>>(Z, dis, off, ew, npg, W3, b3, W4, B, n);
    agg_kernel<16><<<(n + 63) / 64, 256, 0, stream>>>(B, dis, off, ew, b4, out, n);
}